// Round 1
// 580.339 us; speedup vs baseline: 2.1169x; 2.1169x over previous
//
#include <hip/hip_runtime.h>
#include <math.h>

#define BSZ 32
#define NI  128

typedef __attribute__((ext_vector_type(8))) _Float16 f16x8;
typedef __attribute__((ext_vector_type(4))) _Float16 f16x4;
typedef __attribute__((ext_vector_type(4))) float    f32x4;

// MFMA16(X, Y, C): C[row = quad*4+reg <- X's l15][col = l15 <- Y's l15]
// X,Y k-index = quad*8 + j.
// Tiled operand format: 1KB tiles [(r>>4)][(k>>5)], inner
//   ((r&15)*4 + ((k>>3)&3))*8 + (k&7)  == l15*32 + quad*8 + j for a fragment.
#define MFMA16(a, b, c) __builtin_amdgcn_mfma_f32_16x16x32_f16((a), (b), (c), 0, 0, 0)

// global -> LDS async DMA, 16B per lane, wave-linear dest
#define GLL(g, l) __builtin_amdgcn_global_load_lds(                          \
    (const __attribute__((address_space(1))) void*)(g),                      \
    (__attribute__((address_space(3))) void*)(l), 16, 0, 0)

__device__ inline float dot4f(float4 a, float4 b) {
    return a.x * b.x + a.y * b.y + a.z * b.z + a.w * b.w;
}

// ---------------------------------------------------------------------------
// tokens f32 -> f16 TILED. thread -> (row sg, 8-d group d8)
// ---------------------------------------------------------------------------
__global__ __launch_bounds__(256) void tok_convert(const float* __restrict__ in,
                                                   _Float16* __restrict__ tokT)
{
    int idx = blockIdx.x * 256 + threadIdx.x;       // 2M threads
    int sg = idx >> 5, d8 = idx & 31;
    const float* p = in + (size_t)sg * 256 + d8 * 8;
    float4 a = *(const float4*)p, b = *(const float4*)(p + 4);
    f16x8 h;
    h[0] = (_Float16)a.x; h[1] = (_Float16)a.y; h[2] = (_Float16)a.z; h[3] = (_Float16)a.w;
    h[4] = (_Float16)b.x; h[5] = (_Float16)b.y; h[6] = (_Float16)b.z; h[7] = (_Float16)b.w;
    *(f16x8*)(tokT + ((size_t)(sg >> 4) * 8 + (d8 >> 2)) * 512 + (sg & 15) * 32 + (d8 & 3) * 8) = h;
}

// ---------------------------------------------------------------------------
// 64x64 f32->f16 transpose tile -> TILED output (element (n,k) from src[k][n])
// ---------------------------------------------------------------------------
__device__ inline void tpose64(const float* __restrict__ src, int Csrc,
                               _Float16* __restrict__ dstT, int KT,
                               int r0, int c0, _Float16 (*tbuf)[72], int tid)
{
#pragma unroll
    for (int it = 0; it < 4; it++) {
        int idx = tid + it * 256;
        int rr = idx >> 4, c4 = idx & 15;
        float4 w = *(const float4*)(src + (size_t)(r0 + rr) * Csrc + c0 + c4 * 4);
        tbuf[c4 * 4 + 0][rr] = (_Float16)w.x;
        tbuf[c4 * 4 + 1][rr] = (_Float16)w.y;
        tbuf[c4 * 4 + 2][rr] = (_Float16)w.z;
        tbuf[c4 * 4 + 3][rr] = (_Float16)w.w;
    }
    __syncthreads();
#pragma unroll
    for (int it = 0; it < 2; it++) {
        int idx = tid + it * 256;
        int orr = idx >> 3, oc8 = idx & 7;
        int n = c0 + orr;
        size_t tile = (size_t)(n >> 4) * KT + (r0 >> 5) + (oc8 >> 2);
        *(f16x8*)(dstT + tile * 512 + (n & 15) * 32 + (oc8 & 3) * 8) = *(const f16x8*)&tbuf[orr][oc8 * 8];
    }
}

// ---------------------------------------------------------------------------
// prep: tiled f16 weights, qn, cls_n, qint2 = q@Wqi + bqi + bqs
// ---------------------------------------------------------------------------
__global__ __launch_bounds__(256) void prep(
    const float* __restrict__ Wk, const float* __restrict__ Wv,
    const float* __restrict__ Wqs, const float* __restrict__ Wf1,
    const float* __restrict__ Wf2,
    const float* __restrict__ intent_q, const float* __restrict__ Wqi,
    const float* __restrict__ bqi, const float* __restrict__ bqs,
    const float* __restrict__ cls_embed,
    _Float16* __restrict__ wkT, _Float16* __restrict__ wvT,
    _Float16* __restrict__ wqsT, _Float16* __restrict__ wf1T,
    _Float16* __restrict__ wf2T,
    float* __restrict__ qint2, float* __restrict__ qn, float* __restrict__ clsn)
{
    __shared__ _Float16 tbuf[64][72];
    __shared__ float buf[256];
    __shared__ float red[4];
    const int t = threadIdx.x, blk = blockIdx.x;
    const int lane = t & 63, w = t >> 6;

    if (blk < 112) {
        if (blk < 16)       tpose64(Wk, 256, wkT, 8, (blk >> 2) * 64, (blk & 3) * 64, tbuf, t);
        else if (blk < 32)  { int tt = blk - 16; tpose64(Wv, 256, wvT, 8, (tt >> 2) * 64, (tt & 3) * 64, tbuf, t); }
        else if (blk < 48)  { int tt = blk - 32; tpose64(Wqs, 256, wqsT, 8, (tt >> 2) * 64, (tt & 3) * 64, tbuf, t); }
        else if (blk < 80)  { int tt = blk - 48; tpose64(Wf1, 512, wf1T, 8, (tt & 3) * 64, (tt >> 2) * 64, tbuf, t); }
        else                { int tt = blk - 80; tpose64(Wf2, 256, wf2T, 16, (tt >> 2) * 64, (tt & 3) * 64, tbuf, t); }
    } else if (blk < 240) {
        int i = blk - 112;
        float x = intent_q[(size_t)i * 256 + t];
        buf[t] = x;
        float ss = x * x;
#pragma unroll
        for (int m = 1; m < 64; m <<= 1) ss += __shfl_xor(ss, m, 64);
        if (lane == 0) red[w] = ss;
        __syncthreads();
        float tot = red[0] + red[1] + red[2] + red[3];
        qn[(size_t)i * 256 + t] = x / fmaxf(sqrtf(tot), 1e-12f);
        float acc = bqi[t] + bqs[t];
        for (int e = 0; e < 256; e += 4) {
            const float4 q4 = *(const float4*)&buf[e];
            acc += q4.x * Wqi[(size_t)(e + 0) * 256 + t];
            acc += q4.y * Wqi[(size_t)(e + 1) * 256 + t];
            acc += q4.z * Wqi[(size_t)(e + 2) * 256 + t];
            acc += q4.w * Wqi[(size_t)(e + 3) * 256 + t];
        }
        qint2[(size_t)i * 256 + t] = acc;
    } else {
        int b = blk - 240;
        float x = cls_embed[(size_t)b * 256 + t];
        float ss = x * x;
#pragma unroll
        for (int m = 1; m < 64; m <<= 1) ss += __shfl_xor(ss, m, 64);
        if (lane == 0) red[w] = ss;
        __syncthreads();
        float tot = red[0] + red[1] + red[2] + red[3];
        clsn[(size_t)b * 256 + t] = x / fmaxf(sqrtf(tot), 1e-12f);
    }
}

// ---------------------------------------------------------------------------
// kv projection. All operands tiled. bx<2048 -> k path, else v path.
// k tiles: [(b*128 + s>>4)*8 + d>>5]; v tiles: [(b*16 + d>>4)*64 + s>>5]
// ---------------------------------------------------------------------------
__global__ __launch_bounds__(64) void kv_proj(
    const _Float16* __restrict__ tokT,
    const _Float16* __restrict__ wkT, const _Float16* __restrict__ wvT,
    const float* __restrict__ bk, const float* __restrict__ bv,
    _Float16* __restrict__ kT, _Float16* __restrict__ vT)
{
    const int lane = threadIdx.x, l15 = lane & 15, quad = lane >> 4;
    const int lofs = l15 * 32 + quad * 8;
    const int bx = blockIdx.x;
    if (bx < 2048) {
        const int b = bx >> 6, mp = (bx >> 3) & 7, se = bx & 7;
        f16x8 a0[8], a1[8];
#pragma unroll
        for (int ks = 0; ks < 8; ks++) {
            a0[ks] = *(const f16x8*)(wkT + ((size_t)(mp * 2) * 8 + ks) * 512 + lofs);
            a1[ks] = *(const f16x8*)(wkT + ((size_t)(mp * 2 + 1) * 8 + ks) * 512 + lofs);
        }
        f32x4 bi0 = *(const f32x4*)(bk + mp * 32 + quad * 4);
        f32x4 bi1 = *(const f32x4*)(bk + mp * 32 + 16 + quad * 4);
        for (int nt = 0; nt < 16; nt++) {
            int stg = se * 16 + nt;
            f32x4 c0 = {0.f, 0.f, 0.f, 0.f}, c1 = {0.f, 0.f, 0.f, 0.f};
#pragma unroll
            for (int ks = 0; ks < 8; ks++) {
                f16x8 bf = *(const f16x8*)(tokT + ((size_t)(b * 128 + stg) * 8 + ks) * 512 + lofs);
                c0 = MFMA16(a0[ks], bf, c0);
                c1 = MFMA16(a1[ks], bf, c1);
            }
            f16x4 p0, p1;
#pragma unroll
            for (int reg = 0; reg < 4; reg++) {
                p0[reg] = (_Float16)(c0[reg] + bi0[reg]);
                p1[reg] = (_Float16)(c1[reg] + bi1[reg]);
            }
            _Float16* tp = kT + ((size_t)(b * 128 + stg) * 8 + mp) * 512 + l15 * 32;
            *(f16x4*)(tp + (quad >> 1) * 8 + (quad & 1) * 4) = p0;
            *(f16x4*)(tp + (2 + (quad >> 1)) * 8 + (quad & 1) * 4) = p1;
        }
    } else {
        const int bb = bx - 2048;
        const int b = bb >> 6, sp = bb & 63;
        f16x8 a0[8], a1[8];
#pragma unroll
        for (int ks = 0; ks < 8; ks++) {
            a0[ks] = *(const f16x8*)(tokT + ((size_t)(b * 128 + sp * 2) * 8 + ks) * 512 + lofs);
            a1[ks] = *(const f16x8*)(tokT + ((size_t)(b * 128 + sp * 2 + 1) * 8 + ks) * 512 + lofs);
        }
        for (int nt = 0; nt < 16; nt++) {
            f32x4 c0 = {0.f, 0.f, 0.f, 0.f}, c1 = {0.f, 0.f, 0.f, 0.f};
#pragma unroll
            for (int ks = 0; ks < 8; ks++) {
                f16x8 bf = *(const f16x8*)(wvT + ((size_t)nt * 8 + ks) * 512 + lofs);
                c0 = MFMA16(a0[ks], bf, c0);
                c1 = MFMA16(a1[ks], bf, c1);
            }
            float bbv = bv[nt * 16 + l15];
            f16x4 p0, p1;
#pragma unroll
            for (int reg = 0; reg < 4; reg++) {
                p0[reg] = (_Float16)(c0[reg] + bbv);
                p1[reg] = (_Float16)(c1[reg] + bbv);
            }
            _Float16* tp = vT + ((size_t)(b * 16 + nt) * 64 + sp) * 512 + l15 * 32;
            *(f16x4*)(tp + (quad >> 1) * 8 + (quad & 1) * 4) = p0;
            *(f16x4*)(tp + (2 + (quad >> 1)) * 8 + (quad & 1) * 4) = p1;
        }
    }
}

// ---------------------------------------------------------------------------
// slots init: writes slots f32 row-major AND slots16 tiled
// ---------------------------------------------------------------------------
__global__ __launch_bounds__(256) void slots_init(
    const float* __restrict__ noise, const float* __restrict__ slot_mu,
    const float* __restrict__ slot_sigma, float* __restrict__ slots,
    _Float16* __restrict__ slotsT)
{
    int idx = blockIdx.x * 256 + threadIdx.x;    // 524288
    int row = idx >> 5, d8 = idx & 31;
    int b = row >> 9, i = (row >> 2) & 127, n = row & 3;
    int d = d8 * 8;
    const float* mp = slot_mu + n * 256 + d;
    const float* sp = slot_sigma + n * 256 + d;
    const float* np = noise + (((size_t)i * BSZ + b) * 4 + n) * 256 + d;
    float4 o0, o1;
    {
        float4 mu = *(const float4*)mp, sg = *(const float4*)sp, ns = *(const float4*)np;
        o0.x = mu.x + ns.x * sg.x; o0.y = mu.y + ns.y * sg.y;
        o0.z = mu.z + ns.z * sg.z; o0.w = mu.w + ns.w * sg.w;
    }
    {
        float4 mu = *(const float4*)(mp + 4), sg = *(const float4*)(sp + 4), ns = *(const float4*)(np + 4);
        o1.x = mu.x + ns.x * sg.x; o1.y = mu.y + ns.y * sg.y;
        o1.z = mu.z + ns.z * sg.z; o1.w = mu.w + ns.w * sg.w;
    }
    *(float4*)(slots + (size_t)row * 256 + d) = o0;
    *(float4*)(slots + (size_t)row * 256 + d + 4) = o1;
    f16x8 h;
    h[0] = (_Float16)o0.x; h[1] = (_Float16)o0.y; h[2] = (_Float16)o0.z; h[3] = (_Float16)o0.w;
    h[4] = (_Float16)o1.x; h[5] = (_Float16)o1.y; h[6] = (_Float16)o1.z; h[7] = (_Float16)o1.w;
    *(f16x8*)(slotsT + ((size_t)(row >> 4) * 8 + (d8 >> 2)) * 512 + (row & 15) * 32 + (d8 & 3) * 8) = h;
}

// ---------------------------------------------------------------------------
// qslot: qsT = (slots@Wqs + qint2)/16, tiled. grid 1024: rb=bx>>2, dq=bx&3
// ---------------------------------------------------------------------------
__global__ __launch_bounds__(256) void qslot_k(
    const _Float16* __restrict__ slotsT, const _Float16* __restrict__ wqsT,
    const float* __restrict__ qint2, _Float16* __restrict__ qsT)
{
    const int tid = threadIdx.x, lane = tid & 63, wv = tid >> 6;
    const int l15 = lane & 15, quad = lane >> 4;
    const int lofs = l15 * 32 + quad * 8;
    const int bx = blockIdx.x, rb = bx >> 2, dq = bx & 3;
    const int rt = rb * 4 + wv;
    const int gr0 = rt * 16;

    f16x8 bs[8];
#pragma unroll
    for (int ks = 0; ks < 8; ks++)
        bs[ks] = *(const f16x8*)(slotsT + ((size_t)rt * 8 + ks) * 512 + lofs);
    const int iq = ((gr0 + l15) & 511) >> 2;
#pragma unroll
    for (int dt = 0; dt < 4; dt++) {
        int dti = dq * 4 + dt;
        f32x4 c = {0.f, 0.f, 0.f, 0.f};
#pragma unroll
        for (int ks = 0; ks < 8; ks++)
            c = MFMA16(*(const f16x8*)(wqsT + ((size_t)dti * 8 + ks) * 512 + lofs), bs[ks], c);
        float4 qi = *(const float4*)(qint2 + (size_t)iq * 256 + dti * 16 + quad * 4);
        f16x4 o;
#pragma unroll
        for (int reg = 0; reg < 4; reg++) o[reg] = (_Float16)((c[reg] + qi[reg]) * 0.0625f);
        *(f16x4*)(qsT + ((size_t)rt * 8 + (dti >> 1)) * 512 + l15 * 32
                  + ((dti & 1) * 2 + (quad >> 1)) * 8 + (quad & 1) * 4) = o;
    }
}

// ---------------------------------------------------------------------------
// attn_k v2: LDS-staged, pipelined. grid 256: b=bx&31, rb=(bx>>5)&1, sk=bx>>6.
// 8 waves x 32 rows = 256 rows/block; 512-key chunk in 8 sub-chunks of 64.
// K double-buffered (global_load_lds), V single-buffered (staged under QK),
// raw s_barrier + counted vmcnt (never drained mid-loop except last iter).
// Accumulation order identical to v1 -> bitwise-same numerics.
// ---------------------------------------------------------------------------
__global__ __launch_bounds__(512, 2) void attn_k(
    const _Float16* __restrict__ qsT, const _Float16* __restrict__ kT,
    const _Float16* __restrict__ vT,
    _Float16* __restrict__ Opart, float* __restrict__ psum4)
{
    __shared__ __align__(16) _Float16 Kb[2][16384];   // 64 keys x 256 d, dbuf
    __shared__ __align__(16) _Float16 Vb[16384];      // 64 keys x 256 d (V^T tiles)
    __shared__ __align__(16) _Float16 pb[8][2304];    // per-wave P scratch, 32 x 72

    const int tid = threadIdx.x, lane = tid & 63, wv = tid >> 6;
    const int l15 = lane & 15, quad = lane >> 4;
    const int lofs = l15 * 32 + quad * 8;
    const int bx = blockIdx.x;
    const int b = bx & 31, rb = (bx >> 5) & 1, sk = bx >> 6;
    const int gr0 = b * 512 + rb * 256 + wv * 32;
    const int rt_q = gr0 >> 4;

    _Float16* pw = pb[wv];

    const _Float16* kSrc = kT + ((size_t)(b * 128 + sk * 32) * 8) * 512;

    // prologue: issue K(0) DMA, then load Q while it flies
    {
        const _Float16* src = kSrc + (size_t)(wv * 4) * 512 + lane * 8;
        _Float16* dst = &Kb[0][(wv * 4) * 512 + lane * 8];
#pragma unroll
        for (int j = 0; j < 4; j++) GLL(src + j * 512, dst + j * 512);
    }

    f16x8 q[2][8];
#pragma unroll
    for (int m = 0; m < 2; m++)
#pragma unroll
        for (int ks = 0; ks < 8; ks++)
            q[m][ks] = *(const f16x8*)(qsT + ((size_t)(rt_q + m) * 8 + ks) * 512 + lofs);

    f32x4 O[2][16];
#pragma unroll
    for (int m = 0; m < 2; m++)
#pragma unroll
        for (int dt = 0; dt < 16; dt++) O[m][dt] = (f32x4){0.f, 0.f, 0.f, 0.f};
    float ps[2][4] = {{0.f, 0.f, 0.f, 0.f}, {0.f, 0.f, 0.f, 0.f}};

    asm volatile("s_waitcnt vmcnt(0)" ::: "memory");
    __builtin_amdgcn_s_barrier();
    __builtin_amdgcn_sched_barrier(0);

    for (int s = 0; s < 8; s++) {
        const int cur = s & 1;

        // A: stage V(s) -> Vb (Vb free: post-PV barrier of s-1 passed)
        {
            const int seg0 = wv * 4;
#pragma unroll
            for (int j = 0; j < 4; j++) {
                const int seg = seg0 + j;
                const _Float16* src = vT
                    + ((size_t)(b * 16 + (seg >> 1)) * 64 + sk * 16 + s * 2 + (seg & 1)) * 512
                    + lane * 8;
                GLL(src, &Vb[seg * 512 + lane * 8]);
            }
        }
        // B: stage K(s+1) -> Kb[cur^1]
        if (s < 7) {
            const _Float16* src = kSrc + (size_t)(s + 1) * 16384 + (wv * 4) * 512 + lane * 8;
            _Float16* dst = &Kb[cur ^ 1][(wv * 4) * 512 + lane * 8];
#pragma unroll
            for (int j = 0; j < 4; j++) GLL(src + j * 512, dst + j * 512);
            // outstanding: [K(s)<=4][V(s)=4][K(s+1)=4] -> wait oldest, K(s) landed
            asm volatile("s_waitcnt vmcnt(8)" ::: "memory");
        } else {
            // outstanding: [K(7)<=4][V(7)=4] -> wait K(7)
            asm volatile("s_waitcnt vmcnt(4)" ::: "memory");
        }
        __builtin_amdgcn_s_barrier();           // all waves' K(s) parts visible
        __builtin_amdgcn_sched_barrier(0);

        // QK on Kb[cur] + exp + P->LDS (per-wave scratch, lgkm-ordered)
#pragma unroll
        for (int kt = 0; kt < 4; kt++) {
            const _Float16* kp = &Kb[cur][(kt * 8) * 512 + lofs];
            f32x4 c0 = {0.f, 0.f, 0.f, 0.f}, c1 = {0.f, 0.f, 0.f, 0.f};
#pragma unroll
            for (int ks = 0; ks < 8; ks++) {
                f16x8 kf = *(const f16x8*)(kp + ks * 512);
                c0 = MFMA16(q[0][ks], kf, c0);
                c1 = MFMA16(q[1][ks], kf, c1);
            }
            const int col = kt * 16 + l15;
#pragma unroll
            for (int reg = 0; reg < 4; reg++) {
                float p0 = __expf(fminf(c0[reg], 10.5f));
                float p1 = __expf(fminf(c1[reg], 10.5f));
                ps[0][reg] += p0;
                ps[1][reg] += p1;
                pw[(quad * 4 + reg) * 72 + col] = (_Float16)p0;
                pw[(16 + quad * 4 + reg) * 72 + col] = (_Float16)p1;
            }
        }

        __builtin_amdgcn_sched_barrier(0);
        if (s < 7) {
            // outstanding: [V(s)<=4][K(s+1)=4] -> wait V(s), leave K(s+1) flying
            asm volatile("s_waitcnt vmcnt(4)" ::: "memory");
        } else {
            asm volatile("s_waitcnt vmcnt(0)" ::: "memory");
        }
        __builtin_amdgcn_s_barrier();           // all waves' V(s) parts visible
        __builtin_amdgcn_sched_barrier(0);

        // PV on Vb
        f16x8 pa[2][2];
#pragma unroll
        for (int m = 0; m < 2; m++)
#pragma unroll
            for (int kg = 0; kg < 2; kg++)
                pa[m][kg] = *(const f16x8*)(pw + (m * 16 + l15) * 72 + kg * 32 + quad * 8);
#pragma unroll
        for (int dt = 0; dt < 16; dt++) {
            const _Float16* vp = &Vb[dt * 1024 + lofs];
            f16x8 v0 = *(const f16x8*)(vp);
            f16x8 v1 = *(const f16x8*)(vp + 512);
            O[0][dt] = MFMA16(pa[0][0], v0, O[0][dt]);
            O[0][dt] = MFMA16(pa[0][1], v1, O[0][dt]);
            O[1][dt] = MFMA16(pa[1][0], v0, O[1][dt]);
            O[1][dt] = MFMA16(pa[1][1], v1, O[1][dt]);
        }

        __builtin_amdgcn_sched_barrier(0);
        __builtin_amdgcn_s_barrier();           // Vb / Kb[cur] free for next iter DMA
        __builtin_amdgcn_sched_barrier(0);
    }

    // psum reduction over keys (l15 axis), identical to v1
#pragma unroll
    for (int m = 0; m < 2; m++) {
#pragma unroll
        for (int msk = 1; msk <= 8; msk <<= 1)
#pragma unroll
            for (int reg = 0; reg < 4; reg++) ps[m][reg] += __shfl_xor(ps[m][reg], msk, 64);
        if (l15 == 0) {
#pragma unroll
            for (int reg = 0; reg < 4; reg++)
                psum4[(size_t)sk * 16384 + gr0 + m * 16 + quad * 4 + reg] = ps[m][reg];
        }
    }

    // O transpose via per-wave LDS scratch (16 rows x 128 cols per pass),
    // coalesced row-major store to Opart
#pragma unroll
    for (int m = 0; m < 2; m++) {
#pragma unroll
        for (int hd = 0; hd < 2; hd++) {
#pragma unroll
            for (int dt = 0; dt < 8; dt++) {
                const int dti = hd * 8 + dt;
#pragma unroll
                for (int reg = 0; reg < 4; reg++)
                    pw[(quad * 4 + reg) * 136 + dt * 16 + l15] = (_Float16)O[m][dti][reg];
            }
#pragma unroll
            for (int p2 = 0; p2 < 4; p2++) {
                const int u = lane + p2 * 64;
                const int row = u >> 4, col8 = u & 15;
                *(f16x8*)(Opart + ((size_t)sk * 16384 + gr0 + m * 16 + row) * 256 + hd * 128 + col8 * 8) =
                    *(const f16x8*)(pw + row * 136 + col8 * 8);
            }
        }
    }
}

// ---------------------------------------------------------------------------
// LN: y = slots + (sum Opart)/(sum psum); x1=LN1 -> slots; LN2(x1) -> hT tiled
// ---------------------------------------------------------------------------
__global__ __launch_bounds__(256) void ln_k(
    const _Float16* __restrict__ Opart, const float* __restrict__ psum4,
    float* __restrict__ slots, _Float16* __restrict__ hT,
    const float* __restrict__ ln1_g, const float* __restrict__ ln1_b,
    const float* __restrict__ ln2_g, const float* __restrict__ ln2_b)
{
    const int tid = threadIdx.x, lane = tid & 63, wv = tid >> 6;
    const int row = blockIdx.x * 4 + wv;
    float l = 0.f;
#pragma unroll
    for (int j = 0; j < 4; j++) l += psum4[(size_t)j * 16384 + row];
    float invl = 1.f / l;
    float4 o4 = {0.f, 0.f, 0.f, 0.f};
#pragma unroll
    for (int j = 0; j < 4; j++) {
        f16x4 p = *(const f16x4*)(Opart + ((size_t)j * 16384 + row) * 256 + lane * 4);
        o4.x += (float)p[0]; o4.y += (float)p[1]; o4.z += (float)p[2]; o4.w += (float)p[3];
    }
    float4 s4 = *(const float4*)(slots + (size_t)row * 256 + lane * 4);
    float4 y;
    y.x = s4.x + o4.x * invl; y.y = s4.y + o4.y * invl;
    y.z = s4.z + o4.z * invl; y.w = s4.w + o4.w * invl;

    float sm = y.x + y.y + y.z + y.w, sq = dot4f(y, y);
#pragma unroll
    for (int m = 1; m < 64; m <<= 1) { sm += __shfl_xor(sm, m, 64); sq += __shfl_xor(sq, m, 64); }
    float mean = sm * (1.f / 256.f);
    float rstd = rsqrtf(sq * (1.f / 256.f) - mean * mean + 1e-5f);
    float4 g1 = *(const float4*)(ln1_g + lane * 4);
    float4 b1 = *(const float4*)(ln1_b + lane * 4);
    float4 x1;
    x1.x = (y.x - mean) * rstd * g1.x + b1.x;
    x1.y = (y.y - mean) * rstd * g1.y + b1.y;
    x1.z = (y.z - mean) * rstd * g1.z + b1.z;
    x1.w = (y.w - mean) * rstd * g1.w + b1.w;
    *(float4*)(slots + (size_t)row * 256 + lane * 4) = x1;

    float sm2 = x1.x + x1.y + x1.z + x1.w, sq2 = dot4f(x1, x1);
#pragma unroll
    for (int m = 1; m < 64; m <<= 1) { sm2 += __shfl_xor(sm2, m, 64); sq2 += __shfl_xor(sq2, m, 64); }
    float mean2 = sm2 * (1.f / 256.f);
    float rstd2 = rsqrtf(sq2 * (1.f / 256.f) - mean2 * mean2 + 1e-5f);
    float4 g2 = *(const float4*)(ln2_g + lane * 4);
    float4 b2 = *(const float4*)(ln2_b + lane * 4);
    f16x4 h;
    h[0] = (_Float16)((x1.x - mean2) * rstd2 * g2.x + b2.x);
    h[1] = (_Float16)((x1.y - mean2) * rstd2 * g2.y + b2.y);
    h[2] = (_Float16)((x1.z - mean2) * rstd2 * g2.z + b2.z);
    h[3] = (_Float16)((x1.w - mean2) * rstd2 * g2.w + b2.w);
    int d = lane * 4;
    *(f16x4*)(hT + ((size_t)(row >> 4) * 8 + (d >> 5)) * 512 + (row & 15) * 32
              + ((d >> 3) & 3) * 8 + (d & 7)) = h;
}

// ---------------------------------------------------------------------------
// FFN1: actT = gelu(h @ Wf1 + bf1), tiled. grid 1024: rb=bx>>2, hq=bx&3
// ---------------------------------------------------------------------------
__global__ __launch_bounds__(256) void ffn1_k(
    const _Float16* __restrict__ hT, const _Float16* __restrict__ wf1T,
    const float* __restrict__ bf1, _Float16* __restrict__ actT)
{
    const int tid = threadIdx.x, lane = tid & 63, wv = tid >> 6;
    const int l15 = lane & 15, quad = lane >> 4;
    const int lofs = l15 * 32 + quad * 8;
    const int bx = blockIdx.x, rb = bx >> 2, hq = bx & 3;
    const int rt = rb * 4 + wv;

    f16x8 bh[8];
#pragma unroll
    for (int ks = 0; ks < 8; ks++)
        bh[ks] = *(const f16x8*)(hT + ((size_t)rt * 8 + ks) * 512 + lofs);
#pragma unroll 2
    for (int ht = 0; ht < 8; ht++) {
        int hti = hq * 8 + ht;
        f32x4 c = {0.f, 0.f, 0.f, 0.f};
#pragma unroll
        for (int ks = 0; ks < 8; ks++)
            c = MFMA16(*(const f16x8*)(wf1T + ((size_t)hti * 8 + ks) * 512 + lofs), bh[ks], c);
        float4 bb = *(const float4*)(bf1 + hti * 16 + quad * 4);
        f16x4 o;
#pragma unroll
        for (int reg = 0; reg < 4; reg++) {
            float xg = c[reg] + bb[reg];
            o[reg] = (_Float16)(0.5f * xg * (1.f + erff(xg * 0.70710678118654752f)));
        }
        *(f16x4*)(actT + ((size_t)rt * 16 + (hti >> 1)) * 512 + l15 * 32
                  + ((hti & 1) * 2 + (quad >> 1)) * 8 + (quad & 1) * 4) = o;
    }
}

// ---------------------------------------------------------------------------
// FFN2: slots = x1 + act @ Wf2 + bf2 (f32 row-major via LDS transpose)
//       + slotsT tiled f16. grid 1024: rb=bx>>2, dq=bx&3
// ---------------------------------------------------------------------------
__global__ __launch_bounds__(256) void ffn2_k(
    const _Float16* __restrict__ actT, const _Float16* __restrict__ wf2T,
    const float* __restrict__ bf2, float* __restrict__ slots,
    _Float16* __restrict__ slotsT)
{
    __shared__ float xbuf[4][16][68];
    const int tid = threadIdx.x, lane = tid & 63, wv = tid >> 6;
    const int l15 = lane & 15, quad = lane >> 4;
    const int lofs = l15 * 32 + quad * 8;
    const int bx = blockIdx.x, rb = bx >> 2, dq = bx & 3;
    const int rt = rb * 4 + wv;
    const int gr0 = rt * 16;
    const int rr = lane >> 2, c4 = lane & 3;

    // stage x1 (16 rows x 64 d) coalesced -> LDS
#pragma unroll
    for (int j2 = 0; j2 < 4; j2++)
        *(float4*)&xbuf[wv][rr][j2 * 16 + c4 * 4] =
            *(const float4*)(slots + (size_t)(gr0 + rr) * 256 + dq * 64 + j2 * 16 + c4 * 4);

    f32x4 c[4];
#pragma unroll
    for (int dt = 0; dt < 4; dt++) {
        float4 x4 = *(const float4*)&xbuf[wv][l15][dt * 16 + quad * 4];
        float4 bb = *(const float4*)(bf2 + (dq * 4 + dt) * 16 + quad * 4);
        c[dt] = (f32x4){x4.x + bb.x, x4.y + bb.y, x4.z + bb.z, x4.w + bb.w};
    }
    const _Float16* ap = actT + ((size_t)rt * 16) * 512 + lofs;
    for (int ks = 0; ks < 16; ks++) {
        f16x8 bfrag = *(const f16x8*)(ap + (size_t)ks * 512);
#pragma unroll
        for (int dt = 0; dt < 4; dt++)
            c[dt] = MFMA16(*(const f16x8*)(wf2T + ((size_t)(dq * 4 + dt) * 16 + ks) * 512 + lofs), bfrag, c[dt]);
    }
    // tiled f16 slots
#pragma unroll
    for (int dt = 0; dt < 4; dt++) {
        int dti = dq * 4 + dt;
        f16x4 o;
#pragma unroll
        for (int reg = 0; reg < 4; reg++) o[reg] = (_Float16)c[dt][reg];
        *(f16x4*)(slotsT + ((size_t)rt * 8 + (dti >> 1)) * 512 + l15 * 32
                  + ((dti & 1) * 2 + (quad >> 1)) * 8 + (quad & 1) * 4) = o;
    }
    // f32 slots via LDS transpose (wave-local)
#pragma unroll
    for (int dt = 0; dt < 4; dt++) {
        float4 t = {c[dt][0], c[dt][1], c[dt][2], c[dt][3]};
        *(float4*)&xbuf[wv][l15][dt * 16 + quad * 4] = t;
    }
#pragma unroll
    for (int j2 = 0; j2 < 4; j2++)
        *(float4*)(slots + (size_t)(gr0 + rr) * 256 + dq * 64 + j2 * 16 + c4 * 4) =
            *(const float4*)&xbuf[wv][rr][j2 * 16 + c4 * 4];
}

// ---------------------------------------------------------------------------
// final scoring: wave per (b, i)
// ---------------------------------------------------------------------------
__global__ __launch_bounds__(256) void final_k(
    const float* __restrict__ slots, const float* __restrict__ qn,
    const float* __restrict__ clsn,
    const float* __restrict__ alphap, const float* __restrict__ tempp,
    float* __restrict__ out)
{
    const int tid = threadIdx.x, lane = tid & 63, wv = tid >> 6;
    const int bx = blockIdx.x;
    const int b = bx & 31, ig = bx >> 5;
    const int i = ig * 4 + wv;

    float4 qv = *(const float4*)(qn + (size_t)i * 256 + lane * 4);
    float4 xs[4];
    float st4[4];
#pragma unroll
    for (int n = 0; n < 4; n++) {
        xs[n] = *(const float4*)(slots + ((size_t)b * 512 + i * 4 + n) * 256 + lane * 4);
        float ss = dot4f(xs[n], xs[n]);
        float sq = dot4f(xs[n], qv);
#pragma unroll
        for (int m = 1; m < 64; m <<= 1) { ss += __shfl_xor(ss, m, 64); sq += __shfl_xor(sq, m, 64); }
        st4[n] = sq / fmaxf(sqrtf(ss), 1e-12f);
    }
    float mx = fmaxf(fmaxf(st4[0], st4[1]), fmaxf(st4[2], st4[3]));
    float e0 = __expf(st4[0] - mx), e1 = __expf(st4[1] - mx);
    float e2 = __expf(st4[2] - mx), e3 = __expf(st4[3] - mx);
    float inv = 1.f / (e0 + e1 + e2 + e3);
    float4 smv;
    smv.x = (e0 * xs[0].x + e1 * xs[1].x + e2 * xs[2].x + e3 * xs[3].x) * inv;
    smv.y = (e0 * xs[0].y + e1 * xs[1].y + e2 * xs[2].y + e3 * xs[3].y) * inv;
    smv.z = (e0 * xs[0].z + e1 * xs[1].z + e2 * xs[2].z + e3 * xs[3].z) * inv;
    smv.w = (e0 * xs[0].w + e1 * xs[1].w + e2 * xs[2].w + e3 * xs[3].w) * inv;
    float ssm = dot4f(smv, smv);
    float sqn = dot4f(smv, qv);
    float4 cv = *(const float4*)(clsn + (size_t)b * 256 + lane * 4);
    float cq = dot4f(cv, qv);
#pragma unroll
    for (int m = 1; m < 64; m <<= 1) {
        ssm += __shfl_xor(ssm, m, 64);
        sqn += __shfl_xor(sqn, m, 64);
        cq  += __shfl_xor(cq,  m, 64);
    }
    if (lane == 0) {
        float score = cq + alphap[0] * sqn / fmaxf(sqrtf(ssm), 1e-12f);
        out[(size_t)b * NI + i] = score / fmaxf(tempp[0], 1e-4f);
    }
}

// ---------------------------------------------------------------------------
extern "C" void kernel_launch(void* const* d_in, const int* in_sizes, int n_in,
                              void* d_out, int out_size, void* d_ws, size_t ws_size,
                              hipStream_t stream)
{
    const float* tokens     = (const float*)d_in[0];
    const float* cls_embed  = (const float*)d_in[1];
    const float* intent_q   = (const float*)d_in[2];
    const float* noise      = (const float*)d_in[3];
    const float* Wk  = (const float*)d_in[4];
    const float* bk  = (const float*)d_in[5];
    const float* Wv  = (const float*)d_in[6];
    const float* bv  = (const float*)d_in[7];
    const float* Wqs = (const float*)d_in[8];
    const float* bqs = (const float*)d_in[9];
    const float* Wqi = (const float*)d_in[10];
    const float* bqi = (const float*)d_in[11];
    const float* ln1g = (const float*)d_in[12];
    const float* ln1b = (const float*)d_in[13];
    const float* ln2g = (const float*)d_in[14];
    const float* ln2b = (const float*)d_in[15];
    const float* Wf1 = (const float*)d_in[16];
    const float* bf1 = (const float*)d_in[17];
    const float* Wf2 = (const float*)d_in[18];
    const float* bf2 = (const float*)d_in[19];
    const float* slot_mu    = (const float*)d_in[20];
    const float* slot_sigma = (const float*)d_in[21];
    const float* alphap = (const float*)d_in[22];
    const float* tempp  = (const float*)d_in[23];
    float* out = (float*)d_out;

    char* base = (char*)d_ws;
    // region A: tokT [0,33.5MB) during projection; then qsT | slotsT | hT
    _Float16* tokT  = (_Float16*)(base);
    _Float16* qsT   = (_Float16*)(base);                        //  8388608 B
    _Float16* slotsT= (_Float16*)(base + 8388608u);             //  8388608 B
    _Float16* hT    = (_Float16*)(base + 25165824u);            //  8388608 B
    _Float16* kT    = (_Float16*)(base + 33554432u);            // 33554432 B
    _Float16* vT    = (_Float16*)(base + 67108864u);            // 33554432 B
    _Float16* Opart = (_Float16*)(base + 100663296u);           // 33554432 B (aliases actT)
    _Float16* actT  = (_Float16*)(base + 100663296u);           // 16777216 B
    float* slots    = (float*)(base + 134217728u);              // 16777216 B
    _Float16* wkT   = (_Float16*)(base + 150994944u);           //   131072 B
    _Float16* wvT   = (_Float16*)(base + 151126016u);
    _Float16* wqsT  = (_Float16*)(base + 151257088u);
    _Float16* wf1T  = (_Float16*)(base + 151388160u);           //   262144 B
    _Float16* wf2T  = (_Float16*)(base + 151650304u);           //   262144 B
    float* qint2    = (float*)(base + 151912448u);              //   131072 B
    float* qnb      = (float*)(base + 152043520u);              //   131072 B
    float* clsn     = (float*)(base + 152174592u);              //    32768 B
    float* psum4    = (float*)(base + 152207360u);              //   262144 B

    tok_convert<<<8192, 256, 0, stream>>>(tokens, tokT);
    prep<<<272, 256, 0, stream>>>(Wk, Wv, Wqs, Wf1, Wf2, intent_q, Wqi, bqi, bqs,
                                  cls_embed, wkT, wvT, wqsT, wf1T, wf2T,
                                  qint2, qnb, clsn);
    kv_proj<<<4096, 64, 0, stream>>>(tokT, wkT, wvT, bk, bv, kT, vT);
    slots_init<<<2048, 256, 0, stream>>>(noise, slot_mu, slot_sigma, slots, slotsT);

    for (int it = 0; it < 3; it++) {
        qslot_k<<<1024, 256, 0, stream>>>(slotsT, wqsT, qint2, qsT);
        attn_k<<<256, 512, 0, stream>>>(qsT, kT, vT, Opart, psum4);
        ln_k<<<4096, 256, 0, stream>>>(Opart, psum4, slots, hT, ln1g, ln1b, ln2g, ln2b);
        ffn1_k<<<1024, 256, 0, stream>>>(hT, wf1T, bf1, actT);
        ffn2_k<<<1024, 256, 0, stream>>>(actT, wf2T, bf2, slots, slotsT);
    }
    final_k<<<1024, 256, 0, stream>>>(slots, qnb, clsn, alphap, tempp, out);
}

// Round 2
// 549.217 us; speedup vs baseline: 2.2368x; 1.0567x over previous
//
#include <hip/hip_runtime.h>
#include <math.h>

#define BSZ 32
#define NI  128

typedef __attribute__((ext_vector_type(8))) _Float16 f16x8;
typedef __attribute__((ext_vector_type(4))) _Float16 f16x4;
typedef __attribute__((ext_vector_type(4))) float    f32x4;

// MFMA16(X, Y, C): C[row = quad*4+reg <- X's l15][col = l15 <- Y's l15]
// X,Y k-index = quad*8 + j.
// Tiled operand format: 1KB tiles [(r>>4)][(k>>5)], inner
//   ((r&15)*4 + ((k>>3)&3))*8 + (k&7)  == l15*32 + quad*8 + j for a fragment.
#define MFMA16(a, b, c) __builtin_amdgcn_mfma_f32_16x16x32_f16((a), (b), (c), 0, 0, 0)

// global -> LDS async DMA, 16B per lane, wave-linear dest
#define GLL(g, l) __builtin_amdgcn_global_load_lds(                          \
    (const __attribute__((address_space(1))) void*)(g),                      \
    (__attribute__((address_space(3))) void*)(l), 16, 0, 0)

// barrier that waits LDS ops only (leaves global loads/stores in flight)
#define LGKM_BAR() do {                                                      \
    asm volatile("s_waitcnt lgkmcnt(0)" ::: "memory");                       \
    __builtin_amdgcn_sched_barrier(0);                                       \
    __builtin_amdgcn_s_barrier();                                            \
    __builtin_amdgcn_sched_barrier(0); } while (0)

__device__ inline float dot4f(float4 a, float4 b) {
    return a.x * b.x + a.y * b.y + a.z * b.z + a.w * b.w;
}

// ---------------------------------------------------------------------------
// 64x64 f32->f16 transpose tile -> TILED output (element (n,k) from src[k][n])
// ---------------------------------------------------------------------------
__device__ inline void tpose64(const float* __restrict__ src, int Csrc,
                               _Float16* __restrict__ dstT, int KT,
                               int r0, int c0, _Float16 (*tbuf)[72], int tid)
{
#pragma unroll
    for (int it = 0; it < 4; it++) {
        int idx = tid + it * 256;
        int rr = idx >> 4, c4 = idx & 15;
        float4 w = *(const float4*)(src + (size_t)(r0 + rr) * Csrc + c0 + c4 * 4);
        tbuf[c4 * 4 + 0][rr] = (_Float16)w.x;
        tbuf[c4 * 4 + 1][rr] = (_Float16)w.y;
        tbuf[c4 * 4 + 2][rr] = (_Float16)w.z;
        tbuf[c4 * 4 + 3][rr] = (_Float16)w.w;
    }
    __syncthreads();
#pragma unroll
    for (int it = 0; it < 2; it++) {
        int idx = tid + it * 256;
        int orr = idx >> 3, oc8 = idx & 7;
        int n = c0 + orr;
        size_t tile = (size_t)(n >> 4) * KT + (r0 >> 5) + (oc8 >> 2);
        *(f16x8*)(dstT + tile * 512 + (n & 15) * 32 + (oc8 & 3) * 8) = *(const f16x8*)&tbuf[orr][oc8 * 8];
    }
}

// ---------------------------------------------------------------------------
// prep: tiled f16 weights, qn, cls_n, qint2 = q@Wqi + bqi + bqs
// ---------------------------------------------------------------------------
__global__ __launch_bounds__(256) void prep(
    const float* __restrict__ Wk, const float* __restrict__ Wv,
    const float* __restrict__ Wqs, const float* __restrict__ Wf1,
    const float* __restrict__ Wf2,
    const float* __restrict__ intent_q, const float* __restrict__ Wqi,
    const float* __restrict__ bqi, const float* __restrict__ bqs,
    const float* __restrict__ cls_embed,
    _Float16* __restrict__ wkT, _Float16* __restrict__ wvT,
    _Float16* __restrict__ wqsT, _Float16* __restrict__ wf1T,
    _Float16* __restrict__ wf2T,
    float* __restrict__ qint2, float* __restrict__ qn, float* __restrict__ clsn)
{
    __shared__ _Float16 tbuf[64][72];
    __shared__ float buf[256];
    __shared__ float red[4];
    const int t = threadIdx.x, blk = blockIdx.x;
    const int lane = t & 63, w = t >> 6;

    if (blk < 112) {
        if (blk < 16)       tpose64(Wk, 256, wkT, 8, (blk >> 2) * 64, (blk & 3) * 64, tbuf, t);
        else if (blk < 32)  { int tt = blk - 16; tpose64(Wv, 256, wvT, 8, (tt >> 2) * 64, (tt & 3) * 64, tbuf, t); }
        else if (blk < 48)  { int tt = blk - 32; tpose64(Wqs, 256, wqsT, 8, (tt >> 2) * 64, (tt & 3) * 64, tbuf, t); }
        else if (blk < 80)  { int tt = blk - 48; tpose64(Wf1, 512, wf1T, 8, (tt & 3) * 64, (tt >> 2) * 64, tbuf, t); }
        else                { int tt = blk - 80; tpose64(Wf2, 256, wf2T, 16, (tt >> 2) * 64, (tt & 3) * 64, tbuf, t); }
    } else if (blk < 240) {
        int i = blk - 112;
        float x = intent_q[(size_t)i * 256 + t];
        buf[t] = x;
        float ss = x * x;
#pragma unroll
        for (int m = 1; m < 64; m <<= 1) ss += __shfl_xor(ss, m, 64);
        if (lane == 0) red[w] = ss;
        __syncthreads();
        float tot = red[0] + red[1] + red[2] + red[3];
        qn[(size_t)i * 256 + t] = x / fmaxf(sqrtf(tot), 1e-12f);
        float acc = bqi[t] + bqs[t];
        for (int e = 0; e < 256; e += 4) {
            const float4 q4 = *(const float4*)&buf[e];
            acc += q4.x * Wqi[(size_t)(e + 0) * 256 + t];
            acc += q4.y * Wqi[(size_t)(e + 1) * 256 + t];
            acc += q4.z * Wqi[(size_t)(e + 2) * 256 + t];
            acc += q4.w * Wqi[(size_t)(e + 3) * 256 + t];
        }
        qint2[(size_t)i * 256 + t] = acc;
    } else {
        int b = blk - 240;
        float x = cls_embed[(size_t)b * 256 + t];
        float ss = x * x;
#pragma unroll
        for (int m = 1; m < 64; m <<= 1) ss += __shfl_xor(ss, m, 64);
        if (lane == 0) red[w] = ss;
        __syncthreads();
        float tot = red[0] + red[1] + red[2] + red[3];
        clsn[(size_t)b * 256 + t] = x / fmaxf(sqrtf(tot), 1e-12f);
    }
}

// ---------------------------------------------------------------------------
// kvf_k: fused tokens->f16 + K-proj + V-proj. grid 256 x 512 threads.
// b = bx>>3, chunk = bx&7 (256 seq rows). 8 pairs of 32 rows, LDS dbuf.
// Wave w owns output dims [32w,32w+32) of BOTH K and V (weights in regs).
// Each staged token fragment feeds 4 MFMAs (2 K + 2 V), shared by 8 waves.
// MFMA order + f16 rounding identical to the old kv_proj -> bitwise-same K/V.
// ---------------------------------------------------------------------------
__global__ __launch_bounds__(512, 2) void kvf_k(
    const float* __restrict__ tokens,
    const _Float16* __restrict__ wkT, const _Float16* __restrict__ wvT,
    const float* __restrict__ bk, const float* __restrict__ bv,
    _Float16* __restrict__ kT, _Float16* __restrict__ vT)
{
    __shared__ __align__(16) _Float16 Sb[2][8192];   // 2 x 16KB: 32 rows x 256d tiled

    const int t = threadIdx.x, lane = t & 63, w = t >> 6;
    const int l15 = lane & 15, quad = lane >> 4;
    const int lofs = l15 * 32 + quad * 8;
    const int bx = blockIdx.x;
    const int b = bx >> 3, chunk = bx & 7;

    // weights for this wave's 32 output dims, in registers
    f16x8 wk[2][8], wv[2][8];
#pragma unroll
    for (int j = 0; j < 2; j++)
#pragma unroll
        for (int ks = 0; ks < 8; ks++) {
            wk[j][ks] = *(const f16x8*)(wkT + ((size_t)(2 * w + j) * 8 + ks) * 512 + lofs);
            wv[j][ks] = *(const f16x8*)(wvT + ((size_t)(2 * w + j) * 8 + ks) * 512 + lofs);
        }
    f32x4 bi0 = *(const f32x4*)(bk + w * 32 + quad * 4);
    f32x4 bi1 = *(const f32x4*)(bk + w * 32 + 16 + quad * 4);
    const float bv0 = bv[(2 * w) * 16 + l15];
    const float bv1 = bv[(2 * w + 1) * 16 + l15];

    // staging geometry: thread handles rows rr (st=0) and rr+16 (st=1), d8 group
    const int rr = t >> 5, d8 = t & 31;
    const float* tbase = tokens + ((size_t)b * 2048 + chunk * 256) * 256 + rr * 256 + d8 * 8;
    const int wofs0 = (d8 >> 2) * 512 + rr * 32 + (d8 & 3) * 8;
    const int wofs1 = (8 + (d8 >> 2)) * 512 + rr * 32 + (d8 & 3) * 8;

    float4 pa0, pa1, pb0, pb1;  // prefetch regs (pair in flight)

#define KVF_LOADS(P) do {                                                    \
        const float* sp_ = tbase + (size_t)(P) * 8192;                       \
        pa0 = *(const float4*)(sp_);                                         \
        pa1 = *(const float4*)(sp_ + 4);                                     \
        pb0 = *(const float4*)(sp_ + 4096);                                  \
        pb1 = *(const float4*)(sp_ + 4100);                                  \
    } while (0)

#define KVF_STAGE(BUF) do {                                                  \
        f16x8 h0, h1;                                                        \
        h0[0] = (_Float16)pa0.x; h0[1] = (_Float16)pa0.y;                    \
        h0[2] = (_Float16)pa0.z; h0[3] = (_Float16)pa0.w;                    \
        h0[4] = (_Float16)pa1.x; h0[5] = (_Float16)pa1.y;                    \
        h0[6] = (_Float16)pa1.z; h0[7] = (_Float16)pa1.w;                    \
        h1[0] = (_Float16)pb0.x; h1[1] = (_Float16)pb0.y;                    \
        h1[2] = (_Float16)pb0.z; h1[3] = (_Float16)pb0.w;                    \
        h1[4] = (_Float16)pb1.x; h1[5] = (_Float16)pb1.y;                    \
        h1[6] = (_Float16)pb1.z; h1[7] = (_Float16)pb1.w;                    \
        *(f16x8*)((BUF) + wofs0) = h0;                                       \
        *(f16x8*)((BUF) + wofs1) = h1;                                       \
    } while (0)

    KVF_LOADS(0);
    KVF_STAGE(&Sb[0][0]);
    LGKM_BAR();

    for (int p = 0; p < 8; p++) {
        if (p < 7) KVF_LOADS(p + 1);
        __builtin_amdgcn_sched_barrier(0);

        const _Float16* lb = &Sb[p & 1][0];
        const int stg0 = chunk * 16 + p * 2;
        const int sp = chunk * 8 + p;

        f16x8 a[2][8];
#pragma unroll
        for (int st = 0; st < 2; st++)
#pragma unroll
            for (int ks = 0; ks < 8; ks++)
                a[st][ks] = *(const f16x8*)(lb + (st * 8 + ks) * 512 + lofs);

        // K: c[row=dim][col=seq]
#pragma unroll
        for (int st = 0; st < 2; st++) {
            f32x4 c0 = {0.f, 0.f, 0.f, 0.f}, c1 = {0.f, 0.f, 0.f, 0.f};
#pragma unroll
            for (int ks = 0; ks < 8; ks++) {
                c0 = MFMA16(wk[0][ks], a[st][ks], c0);
                c1 = MFMA16(wk[1][ks], a[st][ks], c1);
            }
            f16x4 p0, p1;
#pragma unroll
            for (int reg = 0; reg < 4; reg++) {
                p0[reg] = (_Float16)(c0[reg] + bi0[reg]);
                p1[reg] = (_Float16)(c1[reg] + bi1[reg]);
            }
            _Float16* tp = kT + ((size_t)(b * 128 + stg0 + st) * 8 + w) * 512 + l15 * 32;
            *(f16x4*)(tp + (quad >> 1) * 8 + (quad & 1) * 4) = p0;
            *(f16x4*)(tp + (2 + (quad >> 1)) * 8 + (quad & 1) * 4) = p1;
        }

        // V: c[row=seq][col=dim]
#pragma unroll
        for (int j = 0; j < 2; j++) {
            f32x4 c0 = {0.f, 0.f, 0.f, 0.f}, c1 = {0.f, 0.f, 0.f, 0.f};
#pragma unroll
            for (int ks = 0; ks < 8; ks++) {
                c0 = MFMA16(a[0][ks], wv[j][ks], c0);
                c1 = MFMA16(a[1][ks], wv[j][ks], c1);
            }
            const float bb = j ? bv1 : bv0;
            f16x4 p0, p1;
#pragma unroll
            for (int reg = 0; reg < 4; reg++) {
                p0[reg] = (_Float16)(c0[reg] + bb);
                p1[reg] = (_Float16)(c1[reg] + bb);
            }
            _Float16* tp = vT + ((size_t)(b * 16 + 2 * w + j) * 64 + sp) * 512 + l15 * 32;
            *(f16x4*)(tp + (quad >> 1) * 8 + (quad & 1) * 4) = p0;
            *(f16x4*)(tp + (2 + (quad >> 1)) * 8 + (quad & 1) * 4) = p1;
        }

        if (p < 7) {
            KVF_STAGE(&Sb[(p + 1) & 1][0]);
            LGKM_BAR();
        }
    }
#undef KVF_LOADS
#undef KVF_STAGE
}

// ---------------------------------------------------------------------------
// slots init: writes slots f32 row-major AND slots16 tiled
// ---------------------------------------------------------------------------
__global__ __launch_bounds__(256) void slots_init(
    const float* __restrict__ noise, const float* __restrict__ slot_mu,
    const float* __restrict__ slot_sigma, float* __restrict__ slots,
    _Float16* __restrict__ slotsT)
{
    int idx = blockIdx.x * 256 + threadIdx.x;    // 524288
    int row = idx >> 5, d8 = idx & 31;
    int b = row >> 9, i = (row >> 2) & 127, n = row & 3;
    int d = d8 * 8;
    const float* mp = slot_mu + n * 256 + d;
    const float* sp = slot_sigma + n * 256 + d;
    const float* np = noise + (((size_t)i * BSZ + b) * 4 + n) * 256 + d;
    float4 o0, o1;
    {
        float4 mu = *(const float4*)mp, sg = *(const float4*)sp, ns = *(const float4*)np;
        o0.x = mu.x + ns.x * sg.x; o0.y = mu.y + ns.y * sg.y;
        o0.z = mu.z + ns.z * sg.z; o0.w = mu.w + ns.w * sg.w;
    }
    {
        float4 mu = *(const float4*)(mp + 4), sg = *(const float4*)(sp + 4), ns = *(const float4*)(np + 4);
        o1.x = mu.x + ns.x * sg.x; o1.y = mu.y + ns.y * sg.y;
        o1.z = mu.z + ns.z * sg.z; o1.w = mu.w + ns.w * sg.w;
    }
    *(float4*)(slots + (size_t)row * 256 + d) = o0;
    *(float4*)(slots + (size_t)row * 256 + d + 4) = o1;
    f16x8 h;
    h[0] = (_Float16)o0.x; h[1] = (_Float16)o0.y; h[2] = (_Float16)o0.z; h[3] = (_Float16)o0.w;
    h[4] = (_Float16)o1.x; h[5] = (_Float16)o1.y; h[6] = (_Float16)o1.z; h[7] = (_Float16)o1.w;
    *(f16x8*)(slotsT + ((size_t)(row >> 4) * 8 + (d8 >> 2)) * 512 + (row & 15) * 32 + (d8 & 3) * 8) = h;
}

// ---------------------------------------------------------------------------
// qslot: qsT = (slots@Wqs + qint2)/16, tiled. grid 1024: rb=bx>>2, dq=bx&3
// ---------------------------------------------------------------------------
__global__ __launch_bounds__(256) void qslot_k(
    const _Float16* __restrict__ slotsT, const _Float16* __restrict__ wqsT,
    const float* __restrict__ qint2, _Float16* __restrict__ qsT)
{
    const int tid = threadIdx.x, lane = tid & 63, wv = tid >> 6;
    const int l15 = lane & 15, quad = lane >> 4;
    const int lofs = l15 * 32 + quad * 8;
    const int bx = blockIdx.x, rb = bx >> 2, dq = bx & 3;
    const int rt = rb * 4 + wv;
    const int gr0 = rt * 16;

    f16x8 bs[8];
#pragma unroll
    for (int ks = 0; ks < 8; ks++)
        bs[ks] = *(const f16x8*)(slotsT + ((size_t)rt * 8 + ks) * 512 + lofs);
    const int iq = ((gr0 + l15) & 511) >> 2;
#pragma unroll
    for (int dt = 0; dt < 4; dt++) {
        int dti = dq * 4 + dt;
        f32x4 c = {0.f, 0.f, 0.f, 0.f};
#pragma unroll
        for (int ks = 0; ks < 8; ks++)
            c = MFMA16(*(const f16x8*)(wqsT + ((size_t)dti * 8 + ks) * 512 + lofs), bs[ks], c);
        float4 qi = *(const float4*)(qint2 + (size_t)iq * 256 + dti * 16 + quad * 4);
        f16x4 o;
#pragma unroll
        for (int reg = 0; reg < 4; reg++) o[reg] = (_Float16)((c[reg] + qi[reg]) * 0.0625f);
        *(f16x4*)(qsT + ((size_t)rt * 8 + (dti >> 1)) * 512 + l15 * 32
                  + ((dti & 1) * 2 + (quad >> 1)) * 8 + (quad & 1) * 4) = o;
    }
}

// ---------------------------------------------------------------------------
// attn_k v2: LDS-staged, pipelined. grid 256: b=bx&31, rb=(bx>>5)&1, sk=bx>>6.
// 8 waves x 32 rows = 256 rows/block; 512-key chunk in 8 sub-chunks of 64.
// K double-buffered (global_load_lds), V single-buffered (staged under QK),
// raw s_barrier + counted vmcnt (never drained mid-loop except last iter).
// ---------------------------------------------------------------------------
__global__ __launch_bounds__(512, 2) void attn_k(
    const _Float16* __restrict__ qsT, const _Float16* __restrict__ kT,
    const _Float16* __restrict__ vT,
    _Float16* __restrict__ Opart, float* __restrict__ psum4)
{
    __shared__ __align__(16) _Float16 Kb[2][16384];   // 64 keys x 256 d, dbuf
    __shared__ __align__(16) _Float16 Vb[16384];      // 64 keys x 256 d (V^T tiles)
    __shared__ __align__(16) _Float16 pb[8][2304];    // per-wave P scratch, 32 x 72

    const int tid = threadIdx.x, lane = tid & 63, wv = tid >> 6;
    const int l15 = lane & 15, quad = lane >> 4;
    const int lofs = l15 * 32 + quad * 8;
    const int bx = blockIdx.x;
    const int b = bx & 31, rb = (bx >> 5) & 1, sk = bx >> 6;
    const int gr0 = b * 512 + rb * 256 + wv * 32;
    const int rt_q = gr0 >> 4;

    _Float16* pw = pb[wv];

    const _Float16* kSrc = kT + ((size_t)(b * 128 + sk * 32) * 8) * 512;

    // prologue: issue K(0) DMA, then load Q while it flies
    {
        const _Float16* src = kSrc + (size_t)(wv * 4) * 512 + lane * 8;
        _Float16* dst = &Kb[0][(wv * 4) * 512 + lane * 8];
#pragma unroll
        for (int j = 0; j < 4; j++) GLL(src + j * 512, dst + j * 512);
    }

    f16x8 q[2][8];
#pragma unroll
    for (int m = 0; m < 2; m++)
#pragma unroll
        for (int ks = 0; ks < 8; ks++)
            q[m][ks] = *(const f16x8*)(qsT + ((size_t)(rt_q + m) * 8 + ks) * 512 + lofs);

    f32x4 O[2][16];
#pragma unroll
    for (int m = 0; m < 2; m++)
#pragma unroll
        for (int dt = 0; dt < 16; dt++) O[m][dt] = (f32x4){0.f, 0.f, 0.f, 0.f};
    float ps[2][4] = {{0.f, 0.f, 0.f, 0.f}, {0.f, 0.f, 0.f, 0.f}};

    asm volatile("s_waitcnt vmcnt(0)" ::: "memory");
    __builtin_amdgcn_s_barrier();
    __builtin_amdgcn_sched_barrier(0);

    for (int s = 0; s < 8; s++) {
        const int cur = s & 1;

        // A: stage V(s) -> Vb (Vb free: post-PV barrier of s-1 passed)
        {
            const int seg0 = wv * 4;
#pragma unroll
            for (int j = 0; j < 4; j++) {
                const int seg = seg0 + j;
                const _Float16* src = vT
                    + ((size_t)(b * 16 + (seg >> 1)) * 64 + sk * 16 + s * 2 + (seg & 1)) * 512
                    + lane * 8;
                GLL(src, &Vb[seg * 512 + lane * 8]);
            }
        }
        // B: stage K(s+1) -> Kb[cur^1]
        if (s < 7) {
            const _Float16* src = kSrc + (size_t)(s + 1) * 16384 + (wv * 4) * 512 + lane * 8;
            _Float16* dst = &Kb[cur ^ 1][(wv * 4) * 512 + lane * 8];
#pragma unroll
            for (int j = 0; j < 4; j++) GLL(src + j * 512, dst + j * 512);
            // outstanding: [K(s)<=4][V(s)=4][K(s+1)=4] -> wait oldest, K(s) landed
            asm volatile("s_waitcnt vmcnt(8)" ::: "memory");
        } else {
            // outstanding: [K(7)<=4][V(7)=4] -> wait K(7)
            asm volatile("s_waitcnt vmcnt(4)" ::: "memory");
        }
        __builtin_amdgcn_s_barrier();           // all waves' K(s) parts visible
        __builtin_amdgcn_sched_barrier(0);

        // QK on Kb[cur] + exp + P->LDS (per-wave scratch, lgkm-ordered)
#pragma unroll
        for (int kt = 0; kt < 4; kt++) {
            const _Float16* kp = &Kb[cur][(kt * 8) * 512 + lofs];
            f32x4 c0 = {0.f, 0.f, 0.f, 0.f}, c1 = {0.f, 0.f, 0.f, 0.f};
#pragma unroll
            for (int ks = 0; ks < 8; ks++) {
                f16x8 kf = *(const f16x8*)(kp + ks * 512);
                c0 = MFMA16(q[0][ks], kf, c0);
                c1 = MFMA16(q[1][ks], kf, c1);
            }
            const int col = kt * 16 + l15;
#pragma unroll
            for (int reg = 0; reg < 4; reg++) {
                float p0 = __expf(fminf(c0[reg], 10.5f));
                float p1 = __expf(fminf(c1[reg], 10.5f));
                ps[0][reg] += p0;
                ps[1][reg] += p1;
                pw[(quad * 4 + reg) * 72 + col] = (_Float16)p0;
                pw[(16 + quad * 4 + reg) * 72 + col] = (_Float16)p1;
            }
        }

        __builtin_amdgcn_sched_barrier(0);
        if (s < 7) {
            // outstanding: [V(s)<=4][K(s+1)=4] -> wait V(s), leave K(s+1) flying
            asm volatile("s_waitcnt vmcnt(4)" ::: "memory");
        } else {
            asm volatile("s_waitcnt vmcnt(0)" ::: "memory");
        }
        __builtin_amdgcn_s_barrier();           // all waves' V(s) parts visible
        __builtin_amdgcn_sched_barrier(0);

        // PV on Vb
        f16x8 pa[2][2];
#pragma unroll
        for (int m = 0; m < 2; m++)
#pragma unroll
            for (int kg = 0; kg < 2; kg++)
                pa[m][kg] = *(const f16x8*)(pw + (m * 16 + l15) * 72 + kg * 32 + quad * 8);
#pragma unroll
        for (int dt = 0; dt < 16; dt++) {
            const _Float16* vp = &Vb[dt * 1024 + lofs];
            f16x8 v0 = *(const f16x8*)(vp);
            f16x8 v1 = *(const f16x8*)(vp + 512);
            O[0][dt] = MFMA16(pa[0][0], v0, O[0][dt]);
            O[0][dt] = MFMA16(pa[0][1], v1, O[0][dt]);
            O[1][dt] = MFMA16(pa[1][0], v0, O[1][dt]);
            O[1][dt] = MFMA16(pa[1][1], v1, O[1][dt]);
        }

        __builtin_amdgcn_sched_barrier(0);
        __builtin_amdgcn_s_barrier();           // Vb / Kb[cur] free for next iter DMA
        __builtin_amdgcn_sched_barrier(0);
    }

    // psum reduction over keys (l15 axis)
#pragma unroll
    for (int m = 0; m < 2; m++) {
#pragma unroll
        for (int msk = 1; msk <= 8; msk <<= 1)
#pragma unroll
            for (int reg = 0; reg < 4; reg++) ps[m][reg] += __shfl_xor(ps[m][reg], msk, 64);
        if (l15 == 0) {
#pragma unroll
            for (int reg = 0; reg < 4; reg++)
                psum4[(size_t)sk * 16384 + gr0 + m * 16 + quad * 4 + reg] = ps[m][reg];
        }
    }

    // O transpose via per-wave LDS scratch (16 rows x 128 cols per pass),
    // coalesced row-major store to Opart
#pragma unroll
    for (int m = 0; m < 2; m++) {
#pragma unroll
        for (int hd = 0; hd < 2; hd++) {
#pragma unroll
            for (int dt = 0; dt < 8; dt++) {
                const int dti = hd * 8 + dt;
#pragma unroll
                for (int reg = 0; reg < 4; reg++)
                    pw[(quad * 4 + reg) * 136 + dt * 16 + l15] = (_Float16)O[m][dti][reg];
            }
#pragma unroll
            for (int p2 = 0; p2 < 4; p2++) {
                const int u = lane + p2 * 64;
                const int row = u >> 4, col8 = u & 15;
                *(f16x8*)(Opart + ((size_t)sk * 16384 + gr0 + m * 16 + row) * 256 + hd * 128 + col8 * 8) =
                    *(const f16x8*)(pw + row * 136 + col8 * 8);
            }
        }
    }
}

// ---------------------------------------------------------------------------
// LN: y = slots + (sum Opart)/(sum psum); x1=LN1 -> slots; LN2(x1) -> hT tiled
// ---------------------------------------------------------------------------
__global__ __launch_bounds__(256) void ln_k(
    const _Float16* __restrict__ Opart, const float* __restrict__ psum4,
    float* __restrict__ slots, _Float16* __restrict__ hT,
    const float* __restrict__ ln1_g, const float* __restrict__ ln1_b,
    const float* __restrict__ ln2_g, const float* __restrict__ ln2_b)
{
    const int tid = threadIdx.x, lane = tid & 63, wv = tid >> 6;
    const int row = blockIdx.x * 4 + wv;
    float l = 0.f;
#pragma unroll
    for (int j = 0; j < 4; j++) l += psum4[(size_t)j * 16384 + row];
    float invl = 1.f / l;
    float4 o4 = {0.f, 0.f, 0.f, 0.f};
#pragma unroll
    for (int j = 0; j < 4; j++) {
        f16x4 p = *(const f16x4*)(Opart + ((size_t)j * 16384 + row) * 256 + lane * 4);
        o4.x += (float)p[0]; o4.y += (float)p[1]; o4.z += (float)p[2]; o4.w += (float)p[3];
    }
    float4 s4 = *(const float4*)(slots + (size_t)row * 256 + lane * 4);
    float4 y;
    y.x = s4.x + o4.x * invl; y.y = s4.y + o4.y * invl;
    y.z = s4.z + o4.z * invl; y.w = s4.w + o4.w * invl;

    float sm = y.x + y.y + y.z + y.w, sq = dot4f(y, y);
#pragma unroll
    for (int m = 1; m < 64; m <<= 1) { sm += __shfl_xor(sm, m, 64); sq += __shfl_xor(sq, m, 64); }
    float mean = sm * (1.f / 256.f);
    float rstd = rsqrtf(sq * (1.f / 256.f) - mean * mean + 1e-5f);
    float4 g1 = *(const float4*)(ln1_g + lane * 4);
    float4 b1 = *(const float4*)(ln1_b + lane * 4);
    float4 x1;
    x1.x = (y.x - mean) * rstd * g1.x + b1.x;
    x1.y = (y.y - mean) * rstd * g1.y + b1.y;
    x1.z = (y.z - mean) * rstd * g1.z + b1.z;
    x1.w = (y.w - mean) * rstd * g1.w + b1.w;
    *(float4*)(slots + (size_t)row * 256 + lane * 4) = x1;

    float sm2 = x1.x + x1.y + x1.z + x1.w, sq2 = dot4f(x1, x1);
#pragma unroll
    for (int m = 1; m < 64; m <<= 1) { sm2 += __shfl_xor(sm2, m, 64); sq2 += __shfl_xor(sq2, m, 64); }
    float mean2 = sm2 * (1.f / 256.f);
    float rstd2 = rsqrtf(sq2 * (1.f / 256.f) - mean2 * mean2 + 1e-5f);
    float4 g2 = *(const float4*)(ln2_g + lane * 4);
    float4 b2 = *(const float4*)(ln2_b + lane * 4);
    f16x4 h;
    h[0] = (_Float16)((x1.x - mean2) * rstd2 * g2.x + b2.x);
    h[1] = (_Float16)((x1.y - mean2) * rstd2 * g2.y + b2.y);
    h[2] = (_Float16)((x1.z - mean2) * rstd2 * g2.z + b2.z);
    h[3] = (_Float16)((x1.w - mean2) * rstd2 * g2.w + b2.w);
    int d = lane * 4;
    *(f16x4*)(hT + ((size_t)(row >> 4) * 8 + (d >> 5)) * 512 + (row & 15) * 32
              + ((d >> 3) & 3) * 8 + (d & 7)) = h;
}

// ---------------------------------------------------------------------------
// FFN1: actT = gelu(h @ Wf1 + bf1), tiled. grid 1024: rb=bx>>2, hq=bx&3
// ---------------------------------------------------------------------------
__global__ __launch_bounds__(256) void ffn1_k(
    const _Float16* __restrict__ hT, const _Float16* __restrict__ wf1T,
    const float* __restrict__ bf1, _Float16* __restrict__ actT)
{
    const int tid = threadIdx.x, lane = tid & 63, wv = tid >> 6;
    const int l15 = lane & 15, quad = lane >> 4;
    const int lofs = l15 * 32 + quad * 8;
    const int bx = blockIdx.x, rb = bx >> 2, hq = bx & 3;
    const int rt = rb * 4 + wv;

    f16x8 bh[8];
#pragma unroll
    for (int ks = 0; ks < 8; ks++)
        bh[ks] = *(const f16x8*)(hT + ((size_t)rt * 8 + ks) * 512 + lofs);
#pragma unroll 2
    for (int ht = 0; ht < 8; ht++) {
        int hti = hq * 8 + ht;
        f32x4 c = {0.f, 0.f, 0.f, 0.f};
#pragma unroll
        for (int ks = 0; ks < 8; ks++)
            c = MFMA16(*(const f16x8*)(wf1T + ((size_t)hti * 8 + ks) * 512 + lofs), bh[ks], c);
        float4 bb = *(const float4*)(bf1 + hti * 16 + quad * 4);
        f16x4 o;
#pragma unroll
        for (int reg = 0; reg < 4; reg++) {
            float xg = c[reg] + bb[reg];
            o[reg] = (_Float16)(0.5f * xg * (1.f + erff(xg * 0.70710678118654752f)));
        }
        *(f16x4*)(actT + ((size_t)rt * 16 + (hti >> 1)) * 512 + l15 * 32
                  + ((hti & 1) * 2 + (quad >> 1)) * 8 + (quad & 1) * 4) = o;
    }
}

// ---------------------------------------------------------------------------
// FFN2: slots = x1 + act @ Wf2 + bf2 (f32 row-major via LDS transpose)
//       + slotsT tiled f16. grid 1024: rb=bx>>2, dq=bx&3
// ---------------------------------------------------------------------------
__global__ __launch_bounds__(256) void ffn2_k(
    const _Float16* __restrict__ actT, const _Float16* __restrict__ wf2T,
    const float* __restrict__ bf2, float* __restrict__ slots,
    _Float16* __restrict__ slotsT)
{
    __shared__ float xbuf[4][16][68];
    const int tid = threadIdx.x, lane = tid & 63, wv = tid >> 6;
    const int l15 = lane & 15, quad = lane >> 4;
    const int lofs = l15 * 32 + quad * 8;
    const int bx = blockIdx.x, rb = bx >> 2, dq = bx & 3;
    const int rt = rb * 4 + wv;
    const int gr0 = rt * 16;
    const int rr = lane >> 2, c4 = lane & 3;

    // stage x1 (16 rows x 64 d) coalesced -> LDS
#pragma unroll
    for (int j2 = 0; j2 < 4; j2++)
        *(float4*)&xbuf[wv][rr][j2 * 16 + c4 * 4] =
            *(const float4*)(slots + (size_t)(gr0 + rr) * 256 + dq * 64 + j2 * 16 + c4 * 4);

    f32x4 c[4];
#pragma unroll
    for (int dt = 0; dt < 4; dt++) {
        float4 x4 = *(const float4*)&xbuf[wv][l15][dt * 16 + quad * 4];
        float4 bb = *(const float4*)(bf2 + (dq * 4 + dt) * 16 + quad * 4);
        c[dt] = (f32x4){x4.x + bb.x, x4.y + bb.y, x4.z + bb.z, x4.w + bb.w};
    }
    const _Float16* ap = actT + ((size_t)rt * 16) * 512 + lofs;
    for (int ks = 0; ks < 16; ks++) {
        f16x8 bfrag = *(const f16x8*)(ap + (size_t)ks * 512);
#pragma unroll
        for (int dt = 0; dt < 4; dt++)
            c[dt] = MFMA16(*(const f16x8*)(wf2T + ((size_t)(dq * 4 + dt) * 16 + ks) * 512 + lofs), bfrag, c[dt]);
    }
    // tiled f16 slots
#pragma unroll
    for (int dt = 0; dt < 4; dt++) {
        int dti = dq * 4 + dt;
        f16x4 o;
#pragma unroll
        for (int reg = 0; reg < 4; reg++) o[reg] = (_Float16)c[dt][reg];
        *(f16x4*)(slotsT + ((size_t)rt * 8 + (dti >> 1)) * 512 + l15 * 32
                  + ((dti & 1) * 2 + (quad >> 1)) * 8 + (quad & 1) * 4) = o;
    }
    // f32 slots via LDS transpose (wave-local)
#pragma unroll
    for (int dt = 0; dt < 4; dt++) {
        float4 t = {c[dt][0], c[dt][1], c[dt][2], c[dt][3]};
        *(float4*)&xbuf[wv][l15][dt * 16 + quad * 4] = t;
    }
#pragma unroll
    for (int j2 = 0; j2 < 4; j2++)
        *(float4*)(slots + (size_t)(gr0 + rr) * 256 + dq * 64 + j2 * 16 + c4 * 4) =
            *(const float4*)&xbuf[wv][rr][j2 * 16 + c4 * 4];
}

// ---------------------------------------------------------------------------
// final scoring: wave per (b, i)
// ---------------------------------------------------------------------------
__global__ __launch_bounds__(256) void final_k(
    const float* __restrict__ slots, const float* __restrict__ qn,
    const float* __restrict__ clsn,
    const float* __restrict__ alphap, const float* __restrict__ tempp,
    float* __restrict__ out)
{
    const int tid = threadIdx.x, lane = tid & 63, wv = tid >> 6;
    const int bx = blockIdx.x;
    const int b = bx & 31, ig = bx >> 5;
    const int i = ig * 4 + wv;

    float4 qv = *(const float4*)(qn + (size_t)i * 256 + lane * 4);
    float4 xs[4];
    float st4[4];
#pragma unroll
    for (int n = 0; n < 4; n++) {
        xs[n] = *(const float4*)(slots + ((size_t)b * 512 + i * 4 + n) * 256 + lane * 4);
        float ss = dot4f(xs[n], xs[n]);
        float sq = dot4f(xs[n], qv);
#pragma unroll
        for (int m = 1; m < 64; m <<= 1) { ss += __shfl_xor(ss, m, 64); sq += __shfl_xor(sq, m, 64); }
        st4[n] = sq / fmaxf(sqrtf(ss), 1e-12f);
    }
    float mx = fmaxf(fmaxf(st4[0], st4[1]), fmaxf(st4[2], st4[3]));
    float e0 = __expf(st4[0] - mx), e1 = __expf(st4[1] - mx);
    float e2 = __expf(st4[2] - mx), e3 = __expf(st4[3] - mx);
    float inv = 1.f / (e0 + e1 + e2 + e3);
    float4 smv;
    smv.x = (e0 * xs[0].x + e1 * xs[1].x + e2 * xs[2].x + e3 * xs[3].x) * inv;
    smv.y = (e0 * xs[0].y + e1 * xs[1].y + e2 * xs[2].y + e3 * xs[3].y) * inv;
    smv.z = (e0 * xs[0].z + e1 * xs[1].z + e2 * xs[2].z + e3 * xs[3].z) * inv;
    smv.w = (e0 * xs[0].w + e1 * xs[1].w + e2 * xs[2].w + e3 * xs[3].w) * inv;
    float ssm = dot4f(smv, smv);
    float sqn = dot4f(smv, qv);
    float4 cv = *(const float4*)(clsn + (size_t)b * 256 + lane * 4);
    float cq = dot4f(cv, qv);
#pragma unroll
    for (int m = 1; m < 64; m <<= 1) {
        ssm += __shfl_xor(ssm, m, 64);
        sqn += __shfl_xor(sqn, m, 64);
        cq  += __shfl_xor(cq,  m, 64);
    }
    if (lane == 0) {
        float score = cq + alphap[0] * sqn / fmaxf(sqrtf(ssm), 1e-12f);
        out[(size_t)b * NI + i] = score / fmaxf(tempp[0], 1e-4f);
    }
}

// ---------------------------------------------------------------------------
extern "C" void kernel_launch(void* const* d_in, const int* in_sizes, int n_in,
                              void* d_out, int out_size, void* d_ws, size_t ws_size,
                              hipStream_t stream)
{
    const float* tokens     = (const float*)d_in[0];
    const float* cls_embed  = (const float*)d_in[1];
    const float* intent_q   = (const float*)d_in[2];
    const float* noise      = (const float*)d_in[3];
    const float* Wk  = (const float*)d_in[4];
    const float* bk  = (const float*)d_in[5];
    const float* Wv  = (const float*)d_in[6];
    const float* bv  = (const float*)d_in[7];
    const float* Wqs = (const float*)d_in[8];
    const float* bqs = (const float*)d_in[9];
    const float* Wqi = (const float*)d_in[10];
    const float* bqi = (const float*)d_in[11];
    const float* ln1g = (const float*)d_in[12];
    const float* ln1b = (const float*)d_in[13];
    const float* ln2g = (const float*)d_in[14];
    const float* ln2b = (const float*)d_in[15];
    const float* Wf1 = (const float*)d_in[16];
    const float* bf1 = (const float*)d_in[17];
    const float* Wf2 = (const float*)d_in[18];
    const float* bf2 = (const float*)d_in[19];
    const float* slot_mu    = (const float*)d_in[20];
    const float* slot_sigma = (const float*)d_in[21];
    const float* alphap = (const float*)d_in[22];
    const float* tempp  = (const float*)d_in[23];
    float* out = (float*)d_out;

    char* base = (char*)d_ws;
    // region A: qsT | slotsT | hT (tokT eliminated — kvf reads f32 tokens directly)
    _Float16* qsT   = (_Float16*)(base);                        //  8388608 B
    _Float16* slotsT= (_Float16*)(base + 8388608u);             //  8388608 B
    _Float16* hT    = (_Float16*)(base + 25165824u);            //  8388608 B
    _Float16* kT    = (_Float16*)(base + 33554432u);            // 33554432 B
    _Float16* vT    = (_Float16*)(base + 67108864u);            // 33554432 B
    _Float16* Opart = (_Float16*)(base + 100663296u);           // 33554432 B (aliases actT)
    _Float16* actT  = (_Float16*)(base + 100663296u);           // 16777216 B
    float* slots    = (float*)(base + 134217728u);              // 16777216 B
    _Float16* wkT   = (_Float16*)(base + 150994944u);           //   131072 B
    _Float16* wvT   = (_Float16*)(base + 151126016u);
    _Float16* wqsT  = (_Float16*)(base + 151257088u);
    _Float16* wf1T  = (_Float16*)(base + 151388160u);           //   262144 B
    _Float16* wf2T  = (_Float16*)(base + 151650304u);           //   262144 B
    float* qint2    = (float*)(base + 151912448u);              //   131072 B
    float* qnb      = (float*)(base + 152043520u);              //   131072 B
    float* clsn     = (float*)(base + 152174592u);              //    32768 B
    float* psum4    = (float*)(base + 152207360u);              //   262144 B

    prep<<<272, 256, 0, stream>>>(Wk, Wv, Wqs, Wf1, Wf2, intent_q, Wqi, bqi, bqs,
                                  cls_embed, wkT, wvT, wqsT, wf1T, wf2T,
                                  qint2, qnb, clsn);
    kvf_k<<<256, 512, 0, stream>>>(tokens, wkT, wvT, bk, bv, kT, vT);
    slots_init<<<2048, 256, 0, stream>>>(noise, slot_mu, slot_sigma, slots, slotsT);

    for (int it = 0; it < 3; it++) {
        qslot_k<<<1024, 256, 0, stream>>>(slotsT, wqsT, qint2, qsT);
        attn_k<<<256, 512, 0, stream>>>(qsT, kT, vT, Opart, psum4);
        ln_k<<<4096, 256, 0, stream>>>(Opart, psum4, slots, hT, ln1g, ln1b, ln2g, ln2b);
        ffn1_k<<<1024, 256, 0, stream>>>(hT, wf1T, bf1, actT);
        ffn2_k<<<1024, 256, 0, stream>>>(actT, wf2T, bf2, slots, slotsT);
    }
    final_k<<<1024, 256, 0, stream>>>(slots, qnb, clsn, alphap, tempp, out);
}

// Round 3
// 499.232 us; speedup vs baseline: 2.4608x; 1.1001x over previous
//
#include <hip/hip_runtime.h>
#include <math.h>

#define BSZ 32
#define NI  128

typedef __attribute__((ext_vector_type(8))) _Float16 f16x8;
typedef __attribute__((ext_vector_type(4))) _Float16 f16x4;
typedef __attribute__((ext_vector_type(4))) float    f32x4;

// MFMA16(X, Y, C): C[row = quad*4+reg <- X's l15][col = l15 <- Y's l15]
// X,Y k-index = quad*8 + j.
// Tiled operand format: 1KB tiles [(r>>4)][(k>>5)], inner
//   ((r&15)*4 + ((k>>3)&3))*8 + (k&7)  == l15*32 + quad*8 + j for a fragment.
#define MFMA16(a, b, c) __builtin_amdgcn_mfma_f32_16x16x32_f16((a), (b), (c), 0, 0, 0)

// global -> LDS async DMA, 16B per lane, wave-linear dest
#define GLL(g, l) __builtin_amdgcn_global_load_lds(                          \
    (const __attribute__((address_space(1))) void*)(g),                      \
    (__attribute__((address_space(3))) void*)(l), 16, 0, 0)

// barrier that waits LDS ops only (leaves global loads/stores in flight)
#define LGKM_BAR() do {                                                      \
    asm volatile("s_waitcnt lgkmcnt(0)" ::: "memory");                       \
    __builtin_amdgcn_sched_barrier(0);                                       \
    __builtin_amdgcn_s_barrier();                                            \
    __builtin_amdgcn_sched_barrier(0); } while (0)

__device__ inline float dot4f(float4 a, float4 b) {
    return a.x * b.x + a.y * b.y + a.z * b.z + a.w * b.w;
}

// swizzled pointer into slots LDS: row r (0..63), col c (multiple of 4).
// granule XOR spreads the 1KB row stride across banks (16B granules).
__device__ inline float4* slp(float* base, int r, int c) {
    return (float4*)(base + r * 256 + ((((c) >> 2) ^ (r & 7)) << 2));
}

// ---------------------------------------------------------------------------
// 64x64 f32->f16 transpose tile -> TILED output (element (n,k) from src[k][n])
// ---------------------------------------------------------------------------
__device__ inline void tpose64(const float* __restrict__ src, int Csrc,
                               _Float16* __restrict__ dstT, int KT,
                               int r0, int c0, _Float16 (*tbuf)[72], int tid)
{
#pragma unroll
    for (int it = 0; it < 4; it++) {
        int idx = tid + it * 256;
        int rr = idx >> 4, c4 = idx & 15;
        float4 w = *(const float4*)(src + (size_t)(r0 + rr) * Csrc + c0 + c4 * 4);
        tbuf[c4 * 4 + 0][rr] = (_Float16)w.x;
        tbuf[c4 * 4 + 1][rr] = (_Float16)w.y;
        tbuf[c4 * 4 + 2][rr] = (_Float16)w.z;
        tbuf[c4 * 4 + 3][rr] = (_Float16)w.w;
    }
    __syncthreads();
#pragma unroll
    for (int it = 0; it < 2; it++) {
        int idx = tid + it * 256;
        int orr = idx >> 3, oc8 = idx & 7;
        int n = c0 + orr;
        size_t tile = (size_t)(n >> 4) * KT + (r0 >> 5) + (oc8 >> 2);
        *(f16x8*)(dstT + tile * 512 + (n & 15) * 32 + (oc8 & 3) * 8) = *(const f16x8*)&tbuf[orr][oc8 * 8];
    }
}

// ---------------------------------------------------------------------------
// prep: tiled f16 weights, qn, cls_n, qint2 = q@Wqi + bqi + bqs
// ---------------------------------------------------------------------------
__global__ __launch_bounds__(256) void prep(
    const float* __restrict__ Wk, const float* __restrict__ Wv,
    const float* __restrict__ Wqs, const float* __restrict__ Wf1,
    const float* __restrict__ Wf2,
    const float* __restrict__ intent_q, const float* __restrict__ Wqi,
    const float* __restrict__ bqi, const float* __restrict__ bqs,
    const float* __restrict__ cls_embed,
    _Float16* __restrict__ wkT, _Float16* __restrict__ wvT,
    _Float16* __restrict__ wqsT, _Float16* __restrict__ wf1T,
    _Float16* __restrict__ wf2T,
    float* __restrict__ qint2, float* __restrict__ qn, float* __restrict__ clsn)
{
    __shared__ _Float16 tbuf[64][72];
    __shared__ float buf[256];
    __shared__ float red[4];
    const int t = threadIdx.x, blk = blockIdx.x;
    const int lane = t & 63, w = t >> 6;

    if (blk < 112) {
        if (blk < 16)       tpose64(Wk, 256, wkT, 8, (blk >> 2) * 64, (blk & 3) * 64, tbuf, t);
        else if (blk < 32)  { int tt = blk - 16; tpose64(Wv, 256, wvT, 8, (tt >> 2) * 64, (tt & 3) * 64, tbuf, t); }
        else if (blk < 48)  { int tt = blk - 32; tpose64(Wqs, 256, wqsT, 8, (tt >> 2) * 64, (tt & 3) * 64, tbuf, t); }
        else if (blk < 80)  { int tt = blk - 48; tpose64(Wf1, 512, wf1T, 8, (tt & 3) * 64, (tt >> 2) * 64, tbuf, t); }
        else                { int tt = blk - 80; tpose64(Wf2, 256, wf2T, 16, (tt >> 2) * 64, (tt & 3) * 64, tbuf, t); }
    } else if (blk < 240) {
        int i = blk - 112;
        float x = intent_q[(size_t)i * 256 + t];
        buf[t] = x;
        float ss = x * x;
#pragma unroll
        for (int m = 1; m < 64; m <<= 1) ss += __shfl_xor(ss, m, 64);
        if (lane == 0) red[w] = ss;
        __syncthreads();
        float tot = red[0] + red[1] + red[2] + red[3];
        qn[(size_t)i * 256 + t] = x / fmaxf(sqrtf(tot), 1e-12f);
        float acc = bqi[t] + bqs[t];
        for (int e = 0; e < 256; e += 4) {
            const float4 q4 = *(const float4*)&buf[e];
            acc += q4.x * Wqi[(size_t)(e + 0) * 256 + t];
            acc += q4.y * Wqi[(size_t)(e + 1) * 256 + t];
            acc += q4.z * Wqi[(size_t)(e + 2) * 256 + t];
            acc += q4.w * Wqi[(size_t)(e + 3) * 256 + t];
        }
        qint2[(size_t)i * 256 + t] = acc;
    } else {
        int b = blk - 240;
        float x = cls_embed[(size_t)b * 256 + t];
        float ss = x * x;
#pragma unroll
        for (int m = 1; m < 64; m <<= 1) ss += __shfl_xor(ss, m, 64);
        if (lane == 0) red[w] = ss;
        __syncthreads();
        float tot = red[0] + red[1] + red[2] + red[3];
        clsn[(size_t)b * 256 + t] = x / fmaxf(sqrtf(tot), 1e-12f);
    }
}

// ---------------------------------------------------------------------------
// kvf_k: fused tokens->f16 + K-proj + V-proj. grid 256 x 512 threads.
// XCD-swizzled: b = bx&31 so all chunks of batch b run on XCD b%8 — the
// same XCD attn_k's readers (b = bx&31) run on (dirty K/V lines stay local).
// ---------------------------------------------------------------------------
__global__ __launch_bounds__(512, 2) void kvf_k(
    const float* __restrict__ tokens,
    const _Float16* __restrict__ wkT, const _Float16* __restrict__ wvT,
    const float* __restrict__ bk, const float* __restrict__ bv,
    _Float16* __restrict__ kT, _Float16* __restrict__ vT)
{
    __shared__ __align__(16) _Float16 Sb[2][8192];   // 2 x 16KB: 32 rows x 256d tiled

    const int t = threadIdx.x, lane = t & 63, w = t >> 6;
    const int l15 = lane & 15, quad = lane >> 4;
    const int lofs = l15 * 32 + quad * 8;
    const int bx = blockIdx.x;
    const int b = bx & 31, chunk = bx >> 5;

    // weights for this wave's 32 output dims, in registers
    f16x8 wk[2][8], wv[2][8];
#pragma unroll
    for (int j = 0; j < 2; j++)
#pragma unroll
        for (int ks = 0; ks < 8; ks++) {
            wk[j][ks] = *(const f16x8*)(wkT + ((size_t)(2 * w + j) * 8 + ks) * 512 + lofs);
            wv[j][ks] = *(const f16x8*)(wvT + ((size_t)(2 * w + j) * 8 + ks) * 512 + lofs);
        }
    f32x4 bi0 = *(const f32x4*)(bk + w * 32 + quad * 4);
    f32x4 bi1 = *(const f32x4*)(bk + w * 32 + 16 + quad * 4);
    const float bv0 = bv[(2 * w) * 16 + l15];
    const float bv1 = bv[(2 * w + 1) * 16 + l15];

    const int rr = t >> 5, d8 = t & 31;
    const float* tbase = tokens + ((size_t)b * 2048 + chunk * 256) * 256 + rr * 256 + d8 * 8;
    const int wofs0 = (d8 >> 2) * 512 + rr * 32 + (d8 & 3) * 8;
    const int wofs1 = (8 + (d8 >> 2)) * 512 + rr * 32 + (d8 & 3) * 8;

    float4 pa0, pa1, pb0, pb1;

#define KVF_LOADS(P) do {                                                    \
        const float* sp_ = tbase + (size_t)(P) * 8192;                       \
        pa0 = *(const float4*)(sp_);                                         \
        pa1 = *(const float4*)(sp_ + 4);                                     \
        pb0 = *(const float4*)(sp_ + 4096);                                  \
        pb1 = *(const float4*)(sp_ + 4100);                                  \
    } while (0)

#define KVF_STAGE(BUF) do {                                                  \
        f16x8 h0, h1;                                                        \
        h0[0] = (_Float16)pa0.x; h0[1] = (_Float16)pa0.y;                    \
        h0[2] = (_Float16)pa0.z; h0[3] = (_Float16)pa0.w;                    \
        h0[4] = (_Float16)pa1.x; h0[5] = (_Float16)pa1.y;                    \
        h0[6] = (_Float16)pa1.z; h0[7] = (_Float16)pa1.w;                    \
        h1[0] = (_Float16)pb0.x; h1[1] = (_Float16)pb0.y;                    \
        h1[2] = (_Float16)pb0.z; h1[3] = (_Float16)pb0.w;                    \
        h1[4] = (_Float16)pb1.x; h1[5] = (_Float16)pb1.y;                    \
        h1[6] = (_Float16)pb1.z; h1[7] = (_Float16)pb1.w;                    \
        *(f16x8*)((BUF) + wofs0) = h0;                                       \
        *(f16x8*)((BUF) + wofs1) = h1;                                       \
    } while (0)

    KVF_LOADS(0);
    KVF_STAGE(&Sb[0][0]);
    LGKM_BAR();

    for (int p = 0; p < 8; p++) {
        if (p < 7) KVF_LOADS(p + 1);
        __builtin_amdgcn_sched_barrier(0);

        const _Float16* lb = &Sb[p & 1][0];
        const int stg0 = chunk * 16 + p * 2;
        const int sp = chunk * 8 + p;

        f16x8 a[2][8];
#pragma unroll
        for (int st = 0; st < 2; st++)
#pragma unroll
            for (int ks = 0; ks < 8; ks++)
                a[st][ks] = *(const f16x8*)(lb + (st * 8 + ks) * 512 + lofs);

        // K: c[row=dim][col=seq]
#pragma unroll
        for (int st = 0; st < 2; st++) {
            f32x4 c0 = {0.f, 0.f, 0.f, 0.f}, c1 = {0.f, 0.f, 0.f, 0.f};
#pragma unroll
            for (int ks = 0; ks < 8; ks++) {
                c0 = MFMA16(wk[0][ks], a[st][ks], c0);
                c1 = MFMA16(wk[1][ks], a[st][ks], c1);
            }
            f16x4 p0, p1;
#pragma unroll
            for (int reg = 0; reg < 4; reg++) {
                p0[reg] = (_Float16)(c0[reg] + bi0[reg]);
                p1[reg] = (_Float16)(c1[reg] + bi1[reg]);
            }
            _Float16* tp = kT + ((size_t)(b * 128 + stg0 + st) * 8 + w) * 512 + l15 * 32;
            *(f16x4*)(tp + (quad >> 1) * 8 + (quad & 1) * 4) = p0;
            *(f16x4*)(tp + (2 + (quad >> 1)) * 8 + (quad & 1) * 4) = p1;
        }

        // V: c[row=seq][col=dim]
#pragma unroll
        for (int j = 0; j < 2; j++) {
            f32x4 c0 = {0.f, 0.f, 0.f, 0.f}, c1 = {0.f, 0.f, 0.f, 0.f};
#pragma unroll
            for (int ks = 0; ks < 8; ks++) {
                c0 = MFMA16(a[0][ks], wv[j][ks], c0);
                c1 = MFMA16(a[1][ks], wv[j][ks], c1);
            }
            const float bb = j ? bv1 : bv0;
            f16x4 p0, p1;
#pragma unroll
            for (int reg = 0; reg < 4; reg++) {
                p0[reg] = (_Float16)(c0[reg] + bb);
                p1[reg] = (_Float16)(c1[reg] + bb);
            }
            _Float16* tp = vT + ((size_t)(b * 16 + 2 * w + j) * 64 + sp) * 512 + l15 * 32;
            *(f16x4*)(tp + (quad >> 1) * 8 + (quad & 1) * 4) = p0;
            *(f16x4*)(tp + (2 + (quad >> 1)) * 8 + (quad & 1) * 4) = p1;
        }

        if (p < 7) {
            KVF_STAGE(&Sb[(p + 1) & 1][0]);
            LGKM_BAR();
        }
    }
#undef KVF_LOADS
#undef KVF_STAGE
}

// ---------------------------------------------------------------------------
// slots init: writes slots f32 row-major AND slots16 tiled
// ---------------------------------------------------------------------------
__global__ __launch_bounds__(256) void slots_init(
    const float* __restrict__ noise, const float* __restrict__ slot_mu,
    const float* __restrict__ slot_sigma, float* __restrict__ slots,
    _Float16* __restrict__ slotsT)
{
    int idx = blockIdx.x * 256 + threadIdx.x;    // 524288
    int row = idx >> 5, d8 = idx & 31;
    int b = row >> 9, i = (row >> 2) & 127, n = row & 3;
    int d = d8 * 8;
    const float* mp = slot_mu + n * 256 + d;
    const float* sp = slot_sigma + n * 256 + d;
    const float* np = noise + (((size_t)i * BSZ + b) * 4 + n) * 256 + d;
    float4 o0, o1;
    {
        float4 mu = *(const float4*)mp, sg = *(const float4*)sp, ns = *(const float4*)np;
        o0.x = mu.x + ns.x * sg.x; o0.y = mu.y + ns.y * sg.y;
        o0.z = mu.z + ns.z * sg.z; o0.w = mu.w + ns.w * sg.w;
    }
    {
        float4 mu = *(const float4*)(mp + 4), sg = *(const float4*)(sp + 4), ns = *(const float4*)(np + 4);
        o1.x = mu.x + ns.x * sg.x; o1.y = mu.y + ns.y * sg.y;
        o1.z = mu.z + ns.z * sg.z; o1.w = mu.w + ns.w * sg.w;
    }
    *(float4*)(slots + (size_t)row * 256 + d) = o0;
    *(float4*)(slots + (size_t)row * 256 + d + 4) = o1;
    f16x8 h;
    h[0] = (_Float16)o0.x; h[1] = (_Float16)o0.y; h[2] = (_Float16)o0.z; h[3] = (_Float16)o0.w;
    h[4] = (_Float16)o1.x; h[5] = (_Float16)o1.y; h[6] = (_Float16)o1.z; h[7] = (_Float16)o1.w;
    *(f16x8*)(slotsT + ((size_t)(row >> 4) * 8 + (d8 >> 2)) * 512 + (row & 15) * 32 + (d8 & 3) * 8) = h;
}

// ---------------------------------------------------------------------------
// qslot: qsT = (slots@Wqs + qint2)/16, tiled. grid 1024 (iteration 0 only)
// ---------------------------------------------------------------------------
__global__ __launch_bounds__(256) void qslot_k(
    const _Float16* __restrict__ slotsT, const _Float16* __restrict__ wqsT,
    const float* __restrict__ qint2, _Float16* __restrict__ qsT)
{
    const int tid = threadIdx.x, lane = tid & 63, wv = tid >> 6;
    const int l15 = lane & 15, quad = lane >> 4;
    const int lofs = l15 * 32 + quad * 8;
    const int bx = blockIdx.x, rb = bx >> 2, dq = bx & 3;
    const int rt = rb * 4 + wv;
    const int gr0 = rt * 16;

    f16x8 bs[8];
#pragma unroll
    for (int ks = 0; ks < 8; ks++)
        bs[ks] = *(const f16x8*)(slotsT + ((size_t)rt * 8 + ks) * 512 + lofs);
    const int iq = ((gr0 + l15) & 511) >> 2;
#pragma unroll
    for (int dt = 0; dt < 4; dt++) {
        int dti = dq * 4 + dt;
        f32x4 c = {0.f, 0.f, 0.f, 0.f};
#pragma unroll
        for (int ks = 0; ks < 8; ks++)
            c = MFMA16(*(const f16x8*)(wqsT + ((size_t)dti * 8 + ks) * 512 + lofs), bs[ks], c);
        float4 qi = *(const float4*)(qint2 + (size_t)iq * 256 + dti * 16 + quad * 4);
        f16x4 o;
#pragma unroll
        for (int reg = 0; reg < 4; reg++) o[reg] = (_Float16)((c[reg] + qi[reg]) * 0.0625f);
        *(f16x4*)(qsT + ((size_t)rt * 8 + (dti >> 1)) * 512 + l15 * 32
                  + ((dti & 1) * 2 + (quad >> 1)) * 8 + (quad & 1) * 4) = o;
    }
}

// ---------------------------------------------------------------------------
// attn_k: LDS-staged, pipelined. grid 256: b=bx&31, rb=(bx>>5)&1, sk=bx>>6.
// ---------------------------------------------------------------------------
__global__ __launch_bounds__(512, 2) void attn_k(
    const _Float16* __restrict__ qsT, const _Float16* __restrict__ kT,
    const _Float16* __restrict__ vT,
    _Float16* __restrict__ Opart, float* __restrict__ psum4)
{
    __shared__ __align__(16) _Float16 Kb[2][16384];   // 64 keys x 256 d, dbuf
    __shared__ __align__(16) _Float16 Vb[16384];      // 64 keys x 256 d (V^T tiles)
    __shared__ __align__(16) _Float16 pb[8][2304];    // per-wave P scratch

    const int tid = threadIdx.x, lane = tid & 63, wv = tid >> 6;
    const int l15 = lane & 15, quad = lane >> 4;
    const int lofs = l15 * 32 + quad * 8;
    const int bx = blockIdx.x;
    const int b = bx & 31, rb = (bx >> 5) & 1, sk = bx >> 6;
    const int gr0 = b * 512 + rb * 256 + wv * 32;
    const int rt_q = gr0 >> 4;

    _Float16* pw = pb[wv];

    const _Float16* kSrc = kT + ((size_t)(b * 128 + sk * 32) * 8) * 512;

    {
        const _Float16* src = kSrc + (size_t)(wv * 4) * 512 + lane * 8;
        _Float16* dst = &Kb[0][(wv * 4) * 512 + lane * 8];
#pragma unroll
        for (int j = 0; j < 4; j++) GLL(src + j * 512, dst + j * 512);
    }

    f16x8 q[2][8];
#pragma unroll
    for (int m = 0; m < 2; m++)
#pragma unroll
        for (int ks = 0; ks < 8; ks++)
            q[m][ks] = *(const f16x8*)(qsT + ((size_t)(rt_q + m) * 8 + ks) * 512 + lofs);

    f32x4 O[2][16];
#pragma unroll
    for (int m = 0; m < 2; m++)
#pragma unroll
        for (int dt = 0; dt < 16; dt++) O[m][dt] = (f32x4){0.f, 0.f, 0.f, 0.f};
    float ps[2][4] = {{0.f, 0.f, 0.f, 0.f}, {0.f, 0.f, 0.f, 0.f}};

    asm volatile("s_waitcnt vmcnt(0)" ::: "memory");
    __builtin_amdgcn_s_barrier();
    __builtin_amdgcn_sched_barrier(0);

    for (int s = 0; s < 8; s++) {
        const int cur = s & 1;

        {
            const int seg0 = wv * 4;
#pragma unroll
            for (int j = 0; j < 4; j++) {
                const int seg = seg0 + j;
                const _Float16* src = vT
                    + ((size_t)(b * 16 + (seg >> 1)) * 64 + sk * 16 + s * 2 + (seg & 1)) * 512
                    + lane * 8;
                GLL(src, &Vb[seg * 512 + lane * 8]);
            }
        }
        if (s < 7) {
            const _Float16* src = kSrc + (size_t)(s + 1) * 16384 + (wv * 4) * 512 + lane * 8;
            _Float16* dst = &Kb[cur ^ 1][(wv * 4) * 512 + lane * 8];
#pragma unroll
            for (int j = 0; j < 4; j++) GLL(src + j * 512, dst + j * 512);
            asm volatile("s_waitcnt vmcnt(8)" ::: "memory");
        } else {
            asm volatile("s_waitcnt vmcnt(4)" ::: "memory");
        }
        __builtin_amdgcn_s_barrier();
        __builtin_amdgcn_sched_barrier(0);

#pragma unroll
        for (int kt = 0; kt < 4; kt++) {
            const _Float16* kp = &Kb[cur][(kt * 8) * 512 + lofs];
            f32x4 c0 = {0.f, 0.f, 0.f, 0.f}, c1 = {0.f, 0.f, 0.f, 0.f};
#pragma unroll
            for (int ks = 0; ks < 8; ks++) {
                f16x8 kf = *(const f16x8*)(kp + ks * 512);
                c0 = MFMA16(q[0][ks], kf, c0);
                c1 = MFMA16(q[1][ks], kf, c1);
            }
            const int col = kt * 16 + l15;
#pragma unroll
            for (int reg = 0; reg < 4; reg++) {
                float p0 = __expf(fminf(c0[reg], 10.5f));
                float p1 = __expf(fminf(c1[reg], 10.5f));
                ps[0][reg] += p0;
                ps[1][reg] += p1;
                pw[(quad * 4 + reg) * 72 + col] = (_Float16)p0;
                pw[(16 + quad * 4 + reg) * 72 + col] = (_Float16)p1;
            }
        }

        __builtin_amdgcn_sched_barrier(0);
        if (s < 7) {
            asm volatile("s_waitcnt vmcnt(4)" ::: "memory");
        } else {
            asm volatile("s_waitcnt vmcnt(0)" ::: "memory");
        }
        __builtin_amdgcn_s_barrier();
        __builtin_amdgcn_sched_barrier(0);

        f16x8 pa[2][2];
#pragma unroll
        for (int m = 0; m < 2; m++)
#pragma unroll
            for (int kg = 0; kg < 2; kg++)
                pa[m][kg] = *(const f16x8*)(pw + (m * 16 + l15) * 72 + kg * 32 + quad * 8);
#pragma unroll
        for (int dt = 0; dt < 16; dt++) {
            const _Float16* vp = &Vb[dt * 1024 + lofs];
            f16x8 v0 = *(const f16x8*)(vp);
            f16x8 v1 = *(const f16x8*)(vp + 512);
            O[0][dt] = MFMA16(pa[0][0], v0, O[0][dt]);
            O[0][dt] = MFMA16(pa[0][1], v1, O[0][dt]);
            O[1][dt] = MFMA16(pa[1][0], v0, O[1][dt]);
            O[1][dt] = MFMA16(pa[1][1], v1, O[1][dt]);
        }

        __builtin_amdgcn_sched_barrier(0);
        __builtin_amdgcn_s_barrier();
        __builtin_amdgcn_sched_barrier(0);
    }

#pragma unroll
    for (int m = 0; m < 2; m++) {
#pragma unroll
        for (int msk = 1; msk <= 8; msk <<= 1)
#pragma unroll
            for (int reg = 0; reg < 4; reg++) ps[m][reg] += __shfl_xor(ps[m][reg], msk, 64);
        if (l15 == 0) {
#pragma unroll
            for (int reg = 0; reg < 4; reg++)
                psum4[(size_t)sk * 16384 + gr0 + m * 16 + quad * 4 + reg] = ps[m][reg];
        }
    }

#pragma unroll
    for (int m = 0; m < 2; m++) {
#pragma unroll
        for (int hd = 0; hd < 2; hd++) {
#pragma unroll
            for (int dt = 0; dt < 8; dt++) {
                const int dti = hd * 8 + dt;
#pragma unroll
                for (int reg = 0; reg < 4; reg++)
                    pw[(quad * 4 + reg) * 136 + dt * 16 + l15] = (_Float16)O[m][dti][reg];
            }
#pragma unroll
            for (int p2 = 0; p2 < 4; p2++) {
                const int u = lane + p2 * 64;
                const int row = u >> 4, col8 = u & 15;
                *(f16x8*)(Opart + ((size_t)sk * 16384 + gr0 + m * 16 + row) * 256 + hd * 128 + col8 * 8) =
                    *(const f16x8*)(pw + row * 136 + col8 * 8);
            }
        }
    }
}

// ---------------------------------------------------------------------------
// mlp_k: fused LN1+LN2+FFN1+FFN2 (+qslot for next iter | final scoring).
// grid 256 x 512 threads. Block owns 64 rows: b = bx&31 (XCD b%8 matches
// attn/kvf), rg = bx>>5. Wave-pair pairW owns rowtile pairW (16 rows);
// halves split the output-dim loops. slots held in XOR-swizzled LDS f32.
// Per-element arithmetic identical to ln_k/ffn1_k/ffn2_k/qslot_k/final_k.
// ---------------------------------------------------------------------------
__global__ __launch_bounds__(512, 1) void mlp_k(
    const _Float16* __restrict__ Opart, const float* __restrict__ psum4,
    float* __restrict__ slots,
    const float* __restrict__ ln1_g, const float* __restrict__ ln1_b,
    const float* __restrict__ ln2_g, const float* __restrict__ ln2_b,
    const _Float16* __restrict__ wf1T, const float* __restrict__ bf1,
    const _Float16* __restrict__ wf2T, const float* __restrict__ bf2,
    const _Float16* __restrict__ wqsT, const float* __restrict__ qint2,
    _Float16* __restrict__ qsT,
    const float* __restrict__ qn, const float* __restrict__ clsn,
    const float* __restrict__ alphap, const float* __restrict__ tempp,
    float* __restrict__ out, int it)
{
    __shared__ float sl[64 * 256];                 // 64KB swizzled x1/slots
    __shared__ float2 st2[64];                     // LN2 stats per row
    __shared__ __align__(16) _Float16 actL[32768]; // 64KB act tiled

    const int tid = threadIdx.x, lane = tid & 63, w8 = tid >> 6;
    const int l15 = lane & 15, quad = lane >> 4;
    const int lofs = l15 * 32 + quad * 8;
    const int pairW = w8 >> 1, half = w8 & 1;
    const int bx = blockIdx.x;
    const int b = bx & 31, rg = bx >> 5;
    const int R0 = b * 512 + rg * 64;

    // ---- phase 1: y = slots + O/psum; x1 = LN1(y) -> sl; LN2 stats -> st2
#pragma unroll
    for (int r2 = 0; r2 < 2; r2++) {
        const int lr = w8 * 8 + r2 * 4 + quad;
        const int gr = R0 + lr;
        float l = 0.f;
#pragma unroll
        for (int j = 0; j < 4; j++) l += psum4[(size_t)j * 16384 + gr];
        const float invl = 1.f / l;
        float4 y[4];
        float sm = 0.f, sq = 0.f;
#pragma unroll
        for (int k = 0; k < 4; k++) {
            const int c = k * 64 + l15 * 4;
            float4 o4 = {0.f, 0.f, 0.f, 0.f};
#pragma unroll
            for (int j = 0; j < 4; j++) {
                f16x4 p = *(const f16x4*)(Opart + ((size_t)j * 16384 + gr) * 256 + c);
                o4.x += (float)p[0]; o4.y += (float)p[1];
                o4.z += (float)p[2]; o4.w += (float)p[3];
            }
            float4 s4 = *(const float4*)(slots + (size_t)gr * 256 + c);
            y[k].x = s4.x + o4.x * invl; y[k].y = s4.y + o4.y * invl;
            y[k].z = s4.z + o4.z * invl; y[k].w = s4.w + o4.w * invl;
            sm += y[k].x + y[k].y + y[k].z + y[k].w;
            sq += dot4f(y[k], y[k]);
        }
#pragma unroll
        for (int m = 1; m <= 8; m <<= 1) { sm += __shfl_xor(sm, m, 64); sq += __shfl_xor(sq, m, 64); }
        const float mean = sm * (1.f / 256.f);
        const float rstd = rsqrtf(sq * (1.f / 256.f) - mean * mean + 1e-5f);
        float sm2 = 0.f, sq2 = 0.f;
#pragma unroll
        for (int k = 0; k < 4; k++) {
            const int c = k * 64 + l15 * 4;
            float4 g1 = *(const float4*)(ln1_g + c);
            float4 b1 = *(const float4*)(ln1_b + c);
            float4 x1;
            x1.x = (y[k].x - mean) * rstd * g1.x + b1.x;
            x1.y = (y[k].y - mean) * rstd * g1.y + b1.y;
            x1.z = (y[k].z - mean) * rstd * g1.z + b1.z;
            x1.w = (y[k].w - mean) * rstd * g1.w + b1.w;
            *slp(sl, lr, c) = x1;
            sm2 += x1.x + x1.y + x1.z + x1.w;
            sq2 += dot4f(x1, x1);
        }
#pragma unroll
        for (int m = 1; m <= 8; m <<= 1) { sm2 += __shfl_xor(sm2, m, 64); sq2 += __shfl_xor(sq2, m, 64); }
        const float mean2 = sm2 * (1.f / 256.f);
        const float rstd2 = rsqrtf(sq2 * (1.f / 256.f) - mean2 * mean2 + 1e-5f);
        if (l15 == 0) st2[lr] = make_float2(mean2, rstd2);
    }
    __syncthreads();

    // ---- phase 2: h = LN2(x1) on the fly -> bh frags; act = gelu(h@Wf1+bf1)
    const int lrf = pairW * 16 + l15;
    {
        const float2 s2 = st2[lrf];
        f16x8 bh[8];
#pragma unroll
        for (int ks = 0; ks < 8; ks++) {
            const int c0 = ks * 32 + quad * 8;
            float4 xa = *slp(sl, lrf, c0);
            float4 xb = *slp(sl, lrf, c0 + 4);
            float4 ga = *(const float4*)(ln2_g + c0);
            float4 gb = *(const float4*)(ln2_g + c0 + 4);
            float4 ba = *(const float4*)(ln2_b + c0);
            float4 bb2 = *(const float4*)(ln2_b + c0 + 4);
            bh[ks][0] = (_Float16)((xa.x - s2.x) * s2.y * ga.x + ba.x);
            bh[ks][1] = (_Float16)((xa.y - s2.x) * s2.y * ga.y + ba.y);
            bh[ks][2] = (_Float16)((xa.z - s2.x) * s2.y * ga.z + ba.z);
            bh[ks][3] = (_Float16)((xa.w - s2.x) * s2.y * ga.w + ba.w);
            bh[ks][4] = (_Float16)((xb.x - s2.x) * s2.y * gb.x + bb2.x);
            bh[ks][5] = (_Float16)((xb.y - s2.x) * s2.y * gb.y + bb2.y);
            bh[ks][6] = (_Float16)((xb.z - s2.x) * s2.y * gb.z + bb2.z);
            bh[ks][7] = (_Float16)((xb.w - s2.x) * s2.y * gb.w + bb2.w);
        }
#pragma unroll 2
        for (int t16 = 0; t16 < 16; t16++) {
            const int hti = half * 16 + t16;
            f32x4 c = {0.f, 0.f, 0.f, 0.f};
#pragma unroll
            for (int ks = 0; ks < 8; ks++)
                c = MFMA16(*(const f16x8*)(wf1T + ((size_t)hti * 8 + ks) * 512 + lofs), bh[ks], c);
            float4 bb = *(const float4*)(bf1 + hti * 16 + quad * 4);
            f16x4 o;
#pragma unroll
            for (int reg = 0; reg < 4; reg++) {
                float xg = c[reg] + bb[reg];
                o[reg] = (_Float16)(0.5f * xg * (1.f + erff(xg * 0.70710678118654752f)));
            }
            *(f16x4*)(actL + ((size_t)(pairW * 16 + (hti >> 1))) * 512 + l15 * 32
                      + ((hti & 1) * 2 + (quad >> 1)) * 8 + (quad & 1) * 4) = o;
        }
    }
    __syncthreads();

    // ---- phase 3: slots_new = x1 + act@Wf2 + bf2 -> sl (in place)
    {
        f32x4 c[8];
#pragma unroll
        for (int d = 0; d < 8; d++) {
            const int dti = half * 8 + d;
            float4 x4 = *slp(sl, lrf, dti * 16 + quad * 4);
            float4 bb = *(const float4*)(bf2 + dti * 16 + quad * 4);
            c[d] = (f32x4){x4.x + bb.x, x4.y + bb.y, x4.z + bb.z, x4.w + bb.w};
        }
        const _Float16* ap = actL + ((size_t)pairW * 16) * 512 + lofs;
        for (int ks = 0; ks < 16; ks++) {
            f16x8 afrag = *(const f16x8*)(ap + (size_t)ks * 512);
#pragma unroll
            for (int d = 0; d < 8; d++)
                c[d] = MFMA16(*(const f16x8*)(wf2T + ((size_t)(half * 8 + d) * 16 + ks) * 512 + lofs),
                              afrag, c[d]);
        }
#pragma unroll
        for (int d = 0; d < 8; d++) {
            const int dti = half * 8 + d;
            float4 v = {c[d][0], c[d][1], c[d][2], c[d][3]};
            *slp(sl, lrf, dti * 16 + quad * 4) = v;
        }
    }
    __syncthreads();

    if (it < 2) {
        // ---- phase 4a: qsT for next iteration
        f16x8 bs[8];
#pragma unroll
        for (int ks = 0; ks < 8; ks++) {
            const int c0 = ks * 32 + quad * 8;
            float4 xa = *slp(sl, lrf, c0);
            float4 xb = *slp(sl, lrf, c0 + 4);
            bs[ks][0] = (_Float16)xa.x; bs[ks][1] = (_Float16)xa.y;
            bs[ks][2] = (_Float16)xa.z; bs[ks][3] = (_Float16)xa.w;
            bs[ks][4] = (_Float16)xb.x; bs[ks][5] = (_Float16)xb.y;
            bs[ks][6] = (_Float16)xb.z; bs[ks][7] = (_Float16)xb.w;
        }
        const int iq = (rg * 64 + pairW * 16 + l15) >> 2;
        const int rtg = b * 32 + rg * 4 + pairW;
#pragma unroll
        for (int d = 0; d < 8; d++) {
            const int dti = half * 8 + d;
            f32x4 c = {0.f, 0.f, 0.f, 0.f};
#pragma unroll
            for (int ks = 0; ks < 8; ks++)
                c = MFMA16(*(const f16x8*)(wqsT + ((size_t)dti * 8 + ks) * 512 + lofs), bs[ks], c);
            float4 qi = *(const float4*)(qint2 + (size_t)iq * 256 + dti * 16 + quad * 4);
            f16x4 o;
#pragma unroll
            for (int reg = 0; reg < 4; reg++) o[reg] = (_Float16)((c[reg] + qi[reg]) * 0.0625f);
            *(f16x4*)(qsT + ((size_t)rtg * 8 + (dti >> 1)) * 512 + l15 * 32
                      + ((dti & 1) * 2 + (quad >> 1)) * 8 + (quad & 1) * 4) = o;
        }
        // ---- phase 4b: slots_new -> global (coalesced)
        {
            const int lr2 = tid >> 3, k8 = tid & 7;
#pragma unroll
            for (int q4 = 0; q4 < 8; q4++) {
                float4 v = *slp(sl, lr2, k8 * 32 + q4 * 4);
                *(float4*)(slots + (size_t)(R0 + lr2) * 256 + k8 * 32 + q4 * 4) = v;
            }
        }
    } else {
        // ---- phase 4c: final scoring (2 intents per wave)
#pragma unroll
        for (int ii = 0; ii < 2; ii++) {
            const int i_loc = w8 * 2 + ii;
            const int i = rg * 16 + i_loc;
            float4 qv = *(const float4*)(qn + (size_t)i * 256 + lane * 4);
            float4 xs[4];
            float st4[4];
#pragma unroll
            for (int n = 0; n < 4; n++) {
                xs[n] = *slp(sl, i_loc * 4 + n, lane * 4);
                float ss = dot4f(xs[n], xs[n]);
                float sq = dot4f(xs[n], qv);
#pragma unroll
                for (int m = 1; m < 64; m <<= 1) { ss += __shfl_xor(ss, m, 64); sq += __shfl_xor(sq, m, 64); }
                st4[n] = sq / fmaxf(sqrtf(ss), 1e-12f);
            }
            float mx = fmaxf(fmaxf(st4[0], st4[1]), fmaxf(st4[2], st4[3]));
            float e0 = __expf(st4[0] - mx), e1 = __expf(st4[1] - mx);
            float e2 = __expf(st4[2] - mx), e3 = __expf(st4[3] - mx);
            float inv = 1.f / (e0 + e1 + e2 + e3);
            float4 smv;
            smv.x = (e0 * xs[0].x + e1 * xs[1].x + e2 * xs[2].x + e3 * xs[3].x) * inv;
            smv.y = (e0 * xs[0].y + e1 * xs[1].y + e2 * xs[2].y + e3 * xs[3].y) * inv;
            smv.z = (e0 * xs[0].z + e1 * xs[1].z + e2 * xs[2].z + e3 * xs[3].z) * inv;
            smv.w = (e0 * xs[0].w + e1 * xs[1].w + e2 * xs[2].w + e3 * xs[3].w) * inv;
            float ssm = dot4f(smv, smv);
            float sqn = dot4f(smv, qv);
            float4 cv = *(const float4*)(clsn + (size_t)b * 256 + lane * 4);
            float cq = dot4f(cv, qv);
#pragma unroll
            for (int m = 1; m < 64; m <<= 1) {
                ssm += __shfl_xor(ssm, m, 64);
                sqn += __shfl_xor(sqn, m, 64);
                cq  += __shfl_xor(cq,  m, 64);
            }
            if (lane == 0) {
                float score = cq + alphap[0] * sqn / fmaxf(sqrtf(ssm), 1e-12f);
                out[(size_t)b * NI + i] = score / fmaxf(tempp[0], 1e-4f);
            }
        }
    }
}

// ---------------------------------------------------------------------------
extern "C" void kernel_launch(void* const* d_in, const int* in_sizes, int n_in,
                              void* d_out, int out_size, void* d_ws, size_t ws_size,
                              hipStream_t stream)
{
    const float* tokens     = (const float*)d_in[0];
    const float* cls_embed  = (const float*)d_in[1];
    const float* intent_q   = (const float*)d_in[2];
    const float* noise      = (const float*)d_in[3];
    const float* Wk  = (const float*)d_in[4];
    const float* bk  = (const float*)d_in[5];
    const float* Wv  = (const float*)d_in[6];
    const float* bv  = (const float*)d_in[7];
    const float* Wqs = (const float*)d_in[8];
    const float* bqs = (const float*)d_in[9];
    const float* Wqi = (const float*)d_in[10];
    const float* bqi = (const float*)d_in[11];
    const float* ln1g = (const float*)d_in[12];
    const float* ln1b = (const float*)d_in[13];
    const float* ln2g = (const float*)d_in[14];
    const float* ln2b = (const float*)d_in[15];
    const float* Wf1 = (const float*)d_in[16];
    const float* bf1 = (const float*)d_in[17];
    const float* Wf2 = (const float*)d_in[18];
    const float* bf2 = (const float*)d_in[19];
    const float* slot_mu    = (const float*)d_in[20];
    const float* slot_sigma = (const float*)d_in[21];
    const float* alphap = (const float*)d_in[22];
    const float* tempp  = (const float*)d_in[23];
    float* out = (float*)d_out;

    char* base = (char*)d_ws;
    _Float16* qsT   = (_Float16*)(base);                        //  8388608 B
    _Float16* slotsT= (_Float16*)(base + 8388608u);             //  8388608 B
    _Float16* kT    = (_Float16*)(base + 33554432u);            // 33554432 B
    _Float16* vT    = (_Float16*)(base + 67108864u);            // 33554432 B
    _Float16* Opart = (_Float16*)(base + 100663296u);           // 33554432 B
    float* slots    = (float*)(base + 134217728u);              // 16777216 B
    _Float16* wkT   = (_Float16*)(base + 150994944u);           //   131072 B
    _Float16* wvT   = (_Float16*)(base + 151126016u);
    _Float16* wqsT  = (_Float16*)(base + 151257088u);
    _Float16* wf1T  = (_Float16*)(base + 151388160u);           //   262144 B
    _Float16* wf2T  = (_Float16*)(base + 151650304u);           //   262144 B
    float* qint2    = (float*)(base + 151912448u);              //   131072 B
    float* qnb      = (float*)(base + 152043520u);              //   131072 B
    float* clsn     = (float*)(base + 152174592u);              //    32768 B
    float* psum4    = (float*)(base + 152207360u);              //   262144 B

    prep<<<272, 256, 0, stream>>>(Wk, Wv, Wqs, Wf1, Wf2, intent_q, Wqi, bqi, bqs,
                                  cls_embed, wkT, wvT, wqsT, wf1T, wf2T,
                                  qint2, qnb, clsn);
    kvf_k<<<256, 512, 0, stream>>>(tokens, wkT, wvT, bk, bv, kT, vT);
    slots_init<<<2048, 256, 0, stream>>>(noise, slot_mu, slot_sigma, slots, slotsT);
    qslot_k<<<1024, 256, 0, stream>>>(slotsT, wqsT, qint2, qsT);

    for (int it = 0; it < 3; it++) {
        attn_k<<<256, 512, 0, stream>>>(qsT, kT, vT, Opart, psum4);
        mlp_k<<<256, 512, 0, stream>>>(Opart, psum4, slots,
                                       ln1g, ln1b, ln2g, ln2b,
                                       wf1T, bf1, wf2T, bf2,
                                       wqsT, qint2, qsT,
                                       qnb, clsn, alphap, tempp, out, it);
    }
}

// Round 4
// 489.966 us; speedup vs baseline: 2.5073x; 1.0189x over previous
//
#include <hip/hip_runtime.h>
#include <math.h>

#define BSZ 32
#define NI  128

typedef __attribute__((ext_vector_type(8))) _Float16 f16x8;
typedef __attribute__((ext_vector_type(4))) _Float16 f16x4;
typedef __attribute__((ext_vector_type(4))) float    f32x4;

// MFMA16(X, Y, C): C[row = quad*4+reg <- X's l15][col = l15 <- Y's l15]
// X,Y k-index = quad*8 + j.
// Tiled operand format: 1KB tiles [(r>>4)][(k>>5)], inner
//   ((r&15)*4 + ((k>>3)&3))*8 + (k&7)  == l15*32 + quad*8 + j for a fragment.
#define MFMA16(a, b, c) __builtin_amdgcn_mfma_f32_16x16x32_f16((a), (b), (c), 0, 0, 0)

// global -> LDS async DMA, 16B per lane, wave-linear dest
#define GLL(g, l) __builtin_amdgcn_global_load_lds(                          \
    (const __attribute__((address_space(1))) void*)(g),                      \
    (__attribute__((address_space(3))) void*)(l), 16, 0, 0)

// barrier that waits LDS ops only (leaves global loads/stores in flight)
#define LGKM_BAR() do {                                                      \
    asm volatile("s_waitcnt lgkmcnt(0)" ::: "memory");                       \
    __builtin_amdgcn_sched_barrier(0);                                       \
    __builtin_amdgcn_s_barrier();                                            \
    __builtin_amdgcn_sched_barrier(0); } while (0)

__device__ inline float dot4f(float4 a, float4 b) {
    return a.x * b.x + a.y * b.y + a.z * b.z + a.w * b.w;
}

// swizzled pointer into slots LDS: row r, col c (multiple of 4).
__device__ inline float4* slp(float* base, int r, int c) {
    return (float4*)(base + r * 256 + ((((c) >> 2) ^ (r & 7)) << 2));
}

// ---------------------------------------------------------------------------
// 64x64 f32->f16 transpose tile -> TILED output (element (n,k) from src[k][n])
// ---------------------------------------------------------------------------
__device__ inline void tpose64(const float* __restrict__ src, int Csrc,
                               _Float16* __restrict__ dstT, int KT,
                               int r0, int c0, _Float16 (*tbuf)[72], int tid)
{
#pragma unroll
    for (int it = 0; it < 4; it++) {
        int idx = tid + it * 256;
        int rr = idx >> 4, c4 = idx & 15;
        float4 w = *(const float4*)(src + (size_t)(r0 + rr) * Csrc + c0 + c4 * 4);
        tbuf[c4 * 4 + 0][rr] = (_Float16)w.x;
        tbuf[c4 * 4 + 1][rr] = (_Float16)w.y;
        tbuf[c4 * 4 + 2][rr] = (_Float16)w.z;
        tbuf[c4 * 4 + 3][rr] = (_Float16)w.w;
    }
    __syncthreads();
#pragma unroll
    for (int it = 0; it < 2; it++) {
        int idx = tid + it * 256;
        int orr = idx >> 3, oc8 = idx & 7;
        int n = c0 + orr;
        size_t tile = (size_t)(n >> 4) * KT + (r0 >> 5) + (oc8 >> 2);
        *(f16x8*)(dstT + tile * 512 + (n & 15) * 32 + (oc8 & 3) * 8) = *(const f16x8*)&tbuf[orr][oc8 * 8];
    }
}

// ---------------------------------------------------------------------------
// prep: tiled f16 weights, qn, cls_n, qint2 = q@Wqi + bqi + bqs
// ---------------------------------------------------------------------------
__global__ __launch_bounds__(256) void prep(
    const float* __restrict__ Wk, const float* __restrict__ Wv,
    const float* __restrict__ Wqs, const float* __restrict__ Wf1,
    const float* __restrict__ Wf2,
    const float* __restrict__ intent_q, const float* __restrict__ Wqi,
    const float* __restrict__ bqi, const float* __restrict__ bqs,
    const float* __restrict__ cls_embed,
    _Float16* __restrict__ wkT, _Float16* __restrict__ wvT,
    _Float16* __restrict__ wqsT, _Float16* __restrict__ wf1T,
    _Float16* __restrict__ wf2T,
    float* __restrict__ qint2, float* __restrict__ qn, float* __restrict__ clsn)
{
    __shared__ _Float16 tbuf[64][72];
    __shared__ float buf[256];
    __shared__ float red[4];
    const int t = threadIdx.x, blk = blockIdx.x;
    const int lane = t & 63, w = t >> 6;

    if (blk < 112) {
        if (blk < 16)       tpose64(Wk, 256, wkT, 8, (blk >> 2) * 64, (blk & 3) * 64, tbuf, t);
        else if (blk < 32)  { int tt = blk - 16; tpose64(Wv, 256, wvT, 8, (tt >> 2) * 64, (tt & 3) * 64, tbuf, t); }
        else if (blk < 48)  { int tt = blk - 32; tpose64(Wqs, 256, wqsT, 8, (tt >> 2) * 64, (tt & 3) * 64, tbuf, t); }
        else if (blk < 80)  { int tt = blk - 48; tpose64(Wf1, 512, wf1T, 8, (tt & 3) * 64, (tt >> 2) * 64, tbuf, t); }
        else                { int tt = blk - 80; tpose64(Wf2, 256, wf2T, 16, (tt >> 2) * 64, (tt & 3) * 64, tbuf, t); }
    } else if (blk < 240) {
        int i = blk - 112;
        float x = intent_q[(size_t)i * 256 + t];
        buf[t] = x;
        float ss = x * x;
#pragma unroll
        for (int m = 1; m < 64; m <<= 1) ss += __shfl_xor(ss, m, 64);
        if (lane == 0) red[w] = ss;
        __syncthreads();
        float tot = red[0] + red[1] + red[2] + red[3];
        qn[(size_t)i * 256 + t] = x / fmaxf(sqrtf(tot), 1e-12f);
        float acc = bqi[t] + bqs[t];
        for (int e = 0; e < 256; e += 4) {
            const float4 q4 = *(const float4*)&buf[e];
            acc += q4.x * Wqi[(size_t)(e + 0) * 256 + t];
            acc += q4.y * Wqi[(size_t)(e + 1) * 256 + t];
            acc += q4.z * Wqi[(size_t)(e + 2) * 256 + t];
            acc += q4.w * Wqi[(size_t)(e + 3) * 256 + t];
        }
        qint2[(size_t)i * 256 + t] = acc;
    } else {
        int b = blk - 240;
        float x = cls_embed[(size_t)b * 256 + t];
        float ss = x * x;
#pragma unroll
        for (int m = 1; m < 64; m <<= 1) ss += __shfl_xor(ss, m, 64);
        if (lane == 0) red[w] = ss;
        __syncthreads();
        float tot = red[0] + red[1] + red[2] + red[3];
        clsn[(size_t)b * 256 + t] = x / fmaxf(sqrtf(tot), 1e-12f);
    }
}

// ---------------------------------------------------------------------------
// kvf_k: fused tokens->f16 + K-proj + V-proj. grid 256 x 512 threads.
// Sb uses tile-dependent granule XOR swizzle (writes vary tile within phase).
// ---------------------------------------------------------------------------
__global__ __launch_bounds__(512, 2) void kvf_k(
    const float* __restrict__ tokens,
    const _Float16* __restrict__ wkT, const _Float16* __restrict__ wvT,
    const float* __restrict__ bk, const float* __restrict__ bv,
    _Float16* __restrict__ kT, _Float16* __restrict__ vT)
{
    __shared__ __align__(16) _Float16 Sb[2][8192];   // 2 x 16KB: 32 rows x 256d tiled

    const int t = threadIdx.x, lane = t & 63, w = t >> 6;
    const int l15 = lane & 15, quad = lane >> 4;
    const int lofs = l15 * 32 + quad * 8;
    // swizzled within-tile read offset (granule g = l15*4+quad), tile term ^(ks&3)*16
    const int lofsA = ((l15 * 4 + quad) ^ ((l15 >> 1) & 7)) * 8;
    const int bx = blockIdx.x;
    const int b = bx & 31, chunk = bx >> 5;

    f16x8 wk[2][8], wv[2][8];
#pragma unroll
    for (int j = 0; j < 2; j++)
#pragma unroll
        for (int ks = 0; ks < 8; ks++) {
            wk[j][ks] = *(const f16x8*)(wkT + ((size_t)(2 * w + j) * 8 + ks) * 512 + lofs);
            wv[j][ks] = *(const f16x8*)(wvT + ((size_t)(2 * w + j) * 8 + ks) * 512 + lofs);
        }
    f32x4 bi0 = *(const f32x4*)(bk + w * 32 + quad * 4);
    f32x4 bi1 = *(const f32x4*)(bk + w * 32 + 16 + quad * 4);
    const float bv0 = bv[(2 * w) * 16 + l15];
    const float bv1 = bv[(2 * w + 1) * 16 + l15];

    const int rr = t >> 5, d8 = t & 31;
    const float* tbase = tokens + ((size_t)b * 2048 + chunk * 256) * 256 + rr * 256 + d8 * 8;
    // swizzled write offsets: tile T = d8>>2 (+8), granule g = rr*4+(d8&3)
    const int mskW = ((rr >> 1) & 7) ^ (((d8 >> 2) & 3) << 1);
    const int wofs0 = (d8 >> 2) * 512 + (((rr * 4 + (d8 & 3)) ^ mskW) * 8);
    const int wofs1 = wofs0 + 8 * 512;

    float4 pa0, pa1, pb0, pb1;

#define KVF_LOADS(P) do {                                                    \
        const float* sp_ = tbase + (size_t)(P) * 8192;                       \
        pa0 = *(const float4*)(sp_);                                         \
        pa1 = *(const float4*)(sp_ + 4);                                     \
        pb0 = *(const float4*)(sp_ + 4096);                                  \
        pb1 = *(const float4*)(sp_ + 4100);                                  \
    } while (0)

#define KVF_STAGE(BUF) do {                                                  \
        f16x8 h0, h1;                                                        \
        h0[0] = (_Float16)pa0.x; h0[1] = (_Float16)pa0.y;                    \
        h0[2] = (_Float16)pa0.z; h0[3] = (_Float16)pa0.w;                    \
        h0[4] = (_Float16)pa1.x; h0[5] = (_Float16)pa1.y;                    \
        h0[6] = (_Float16)pa1.z; h0[7] = (_Float16)pa1.w;                    \
        h1[0] = (_Float16)pb0.x; h1[1] = (_Float16)pb0.y;                    \
        h1[2] = (_Float16)pb0.z; h1[3] = (_Float16)pb0.w;                    \
        h1[4] = (_Float16)pb1.x; h1[5] = (_Float16)pb1.y;                    \
        h1[6] = (_Float16)pb1.z; h1[7] = (_Float16)pb1.w;                    \
        *(f16x8*)((BUF) + wofs0) = h0;                                       \
        *(f16x8*)((BUF) + wofs1) = h1;                                       \
    } while (0)

    KVF_LOADS(0);
    KVF_STAGE(&Sb[0][0]);
    LGKM_BAR();

    for (int p = 0; p < 8; p++) {
        if (p < 7) KVF_LOADS(p + 1);
        __builtin_amdgcn_sched_barrier(0);

        const _Float16* lb = &Sb[p & 1][0];
        const int stg0 = chunk * 16 + p * 2;
        const int sp = chunk * 8 + p;

        f16x8 a[2][8];
#pragma unroll
        for (int st = 0; st < 2; st++)
#pragma unroll
            for (int ks = 0; ks < 8; ks++)
                a[st][ks] = *(const f16x8*)(lb + (st * 8 + ks) * 512 + (lofsA ^ ((ks & 3) * 16)));

        // K: c[row=dim][col=seq]
#pragma unroll
        for (int st = 0; st < 2; st++) {
            f32x4 c0 = {0.f, 0.f, 0.f, 0.f}, c1 = {0.f, 0.f, 0.f, 0.f};
#pragma unroll
            for (int ks = 0; ks < 8; ks++) {
                c0 = MFMA16(wk[0][ks], a[st][ks], c0);
                c1 = MFMA16(wk[1][ks], a[st][ks], c1);
            }
            f16x4 p0, p1;
#pragma unroll
            for (int reg = 0; reg < 4; reg++) {
                p0[reg] = (_Float16)(c0[reg] + bi0[reg]);
                p1[reg] = (_Float16)(c1[reg] + bi1[reg]);
            }
            _Float16* tp = kT + ((size_t)(b * 128 + stg0 + st) * 8 + w) * 512 + l15 * 32;
            *(f16x4*)(tp + (quad >> 1) * 8 + (quad & 1) * 4) = p0;
            *(f16x4*)(tp + (2 + (quad >> 1)) * 8 + (quad & 1) * 4) = p1;
        }

        // V: c[row=seq][col=dim]
#pragma unroll
        for (int j = 0; j < 2; j++) {
            f32x4 c0 = {0.f, 0.f, 0.f, 0.f}, c1 = {0.f, 0.f, 0.f, 0.f};
#pragma unroll
            for (int ks = 0; ks < 8; ks++) {
                c0 = MFMA16(a[0][ks], wv[j][ks], c0);
                c1 = MFMA16(a[1][ks], wv[j][ks], c1);
            }
            const float bb = j ? bv1 : bv0;
            f16x4 p0, p1;
#pragma unroll
            for (int reg = 0; reg < 4; reg++) {
                p0[reg] = (_Float16)(c0[reg] + bb);
                p1[reg] = (_Float16)(c1[reg] + bb);
            }
            _Float16* tp = vT + ((size_t)(b * 16 + 2 * w + j) * 64 + sp) * 512 + l15 * 32;
            *(f16x4*)(tp + (quad >> 1) * 8 + (quad & 1) * 4) = p0;
            *(f16x4*)(tp + (2 + (quad >> 1)) * 8 + (quad & 1) * 4) = p1;
        }

        if (p < 7) {
            KVF_STAGE(&Sb[(p + 1) & 1][0]);
            LGKM_BAR();
        }
    }
#undef KVF_LOADS
#undef KVF_STAGE
}

// ---------------------------------------------------------------------------
// slots init: writes slots f32 row-major AND slots16 tiled
// ---------------------------------------------------------------------------
__global__ __launch_bounds__(256) void slots_init(
    const float* __restrict__ noise, const float* __restrict__ slot_mu,
    const float* __restrict__ slot_sigma, float* __restrict__ slots,
    _Float16* __restrict__ slotsT)
{
    int idx = blockIdx.x * 256 + threadIdx.x;    // 524288
    int row = idx >> 5, d8 = idx & 31;
    int b = row >> 9, i = (row >> 2) & 127, n = row & 3;
    int d = d8 * 8;
    const float* mp = slot_mu + n * 256 + d;
    const float* sp = slot_sigma + n * 256 + d;
    const float* np = noise + (((size_t)i * BSZ + b) * 4 + n) * 256 + d;
    float4 o0, o1;
    {
        float4 mu = *(const float4*)mp, sg = *(const float4*)sp, ns = *(const float4*)np;
        o0.x = mu.x + ns.x * sg.x; o0.y = mu.y + ns.y * sg.y;
        o0.z = mu.z + ns.z * sg.z; o0.w = mu.w + ns.w * sg.w;
    }
    {
        float4 mu = *(const float4*)(mp + 4), sg = *(const float4*)(sp + 4), ns = *(const float4*)(np + 4);
        o1.x = mu.x + ns.x * sg.x; o1.y = mu.y + ns.y * sg.y;
        o1.z = mu.z + ns.z * sg.z; o1.w = mu.w + ns.w * sg.w;
    }
    *(float4*)(slots + (size_t)row * 256 + d) = o0;
    *(float4*)(slots + (size_t)row * 256 + d + 4) = o1;
    f16x8 h;
    h[0] = (_Float16)o0.x; h[1] = (_Float16)o0.y; h[2] = (_Float16)o0.z; h[3] = (_Float16)o0.w;
    h[4] = (_Float16)o1.x; h[5] = (_Float16)o1.y; h[6] = (_Float16)o1.z; h[7] = (_Float16)o1.w;
    *(f16x8*)(slotsT + ((size_t)(row >> 4) * 8 + (d8 >> 2)) * 512 + (row & 15) * 32 + (d8 & 3) * 8) = h;
}

// ---------------------------------------------------------------------------
// qslot: qsT = (slots@Wqs + qint2)/16, tiled. grid 1024 (iteration 0 only)
// ---------------------------------------------------------------------------
__global__ __launch_bounds__(256) void qslot_k(
    const _Float16* __restrict__ slotsT, const _Float16* __restrict__ wqsT,
    const float* __restrict__ qint2, _Float16* __restrict__ qsT)
{
    const int tid = threadIdx.x, lane = tid & 63, wv = tid >> 6;
    const int l15 = lane & 15, quad = lane >> 4;
    const int lofs = l15 * 32 + quad * 8;
    const int bx = blockIdx.x, rb = bx >> 2, dq = bx & 3;
    const int rt = rb * 4 + wv;
    const int gr0 = rt * 16;

    f16x8 bs[8];
#pragma unroll
    for (int ks = 0; ks < 8; ks++)
        bs[ks] = *(const f16x8*)(slotsT + ((size_t)rt * 8 + ks) * 512 + lofs);
    const int iq = ((gr0 + l15) & 511) >> 2;
#pragma unroll
    for (int dt = 0; dt < 4; dt++) {
        int dti = dq * 4 + dt;
        f32x4 c = {0.f, 0.f, 0.f, 0.f};
#pragma unroll
        for (int ks = 0; ks < 8; ks++)
            c = MFMA16(*(const f16x8*)(wqsT + ((size_t)dti * 8 + ks) * 512 + lofs), bs[ks], c);
        float4 qi = *(const float4*)(qint2 + (size_t)iq * 256 + dti * 16 + quad * 4);
        f16x4 o;
#pragma unroll
        for (int reg = 0; reg < 4; reg++) o[reg] = (_Float16)((c[reg] + qi[reg]) * 0.0625f);
        *(f16x4*)(qsT + ((size_t)rt * 8 + (dti >> 1)) * 512 + l15 * 32
                  + ((dti & 1) * 2 + (quad >> 1)) * 8 + (quad & 1) * 4) = o;
    }
}

// ---------------------------------------------------------------------------
// attn_k: LDS-staged, pipelined. grid 256: b=bx&31, rb=(bx>>5)&1, sk=bx>>6.
// Kb/Vb granule-swizzled: GLL sources pre-swizzled (lane^((lane>>3)&7)),
// fragment reads use swizzled within-tile offset lofsA -> 2-way (free) banks.
// ---------------------------------------------------------------------------
__global__ __launch_bounds__(512, 2) void attn_k(
    const _Float16* __restrict__ qsT, const _Float16* __restrict__ kT,
    const _Float16* __restrict__ vT,
    _Float16* __restrict__ Opart, float* __restrict__ psum4)
{
    __shared__ __align__(16) _Float16 Kb[2][16384];   // 64 keys x 256 d, dbuf
    __shared__ __align__(16) _Float16 Vb[16384];      // 64 keys x 256 d (V^T tiles)
    __shared__ __align__(16) _Float16 pb[8][2304];    // per-wave P scratch

    const int tid = threadIdx.x, lane = tid & 63, wv = tid >> 6;
    const int l15 = lane & 15, quad = lane >> 4;
    const int lofs = l15 * 32 + quad * 8;
    const int lofsA = ((l15 * 4 + quad) ^ ((l15 >> 1) & 7)) * 8;
    const int lnsw = (lane ^ ((lane >> 3) & 7)) * 8;  // pre-swizzled GLL src offset
    const int bx = blockIdx.x;
    const int b = bx & 31, rb = (bx >> 5) & 1, sk = bx >> 6;
    const int gr0 = b * 512 + rb * 256 + wv * 32;
    const int rt_q = gr0 >> 4;

    _Float16* pw = pb[wv];

    const _Float16* kSrc = kT + ((size_t)(b * 128 + sk * 32) * 8) * 512;

    {
        const _Float16* src = kSrc + (size_t)(wv * 4) * 512 + lnsw;
        _Float16* dst = &Kb[0][(wv * 4) * 512 + lane * 8];
#pragma unroll
        for (int j = 0; j < 4; j++) GLL(src + j * 512, dst + j * 512);
    }

    f16x8 q[2][8];
#pragma unroll
    for (int m = 0; m < 2; m++)
#pragma unroll
        for (int ks = 0; ks < 8; ks++)
            q[m][ks] = *(const f16x8*)(qsT + ((size_t)(rt_q + m) * 8 + ks) * 512 + lofs);

    f32x4 O[2][16];
#pragma unroll
    for (int m = 0; m < 2; m++)
#pragma unroll
        for (int dt = 0; dt < 16; dt++) O[m][dt] = (f32x4){0.f, 0.f, 0.f, 0.f};
    float ps[2][4] = {{0.f, 0.f, 0.f, 0.f}, {0.f, 0.f, 0.f, 0.f}};

    asm volatile("s_waitcnt vmcnt(0)" ::: "memory");
    __builtin_amdgcn_s_barrier();
    __builtin_amdgcn_sched_barrier(0);

    for (int s = 0; s < 8; s++) {
        const int cur = s & 1;

        {
            const int seg0 = wv * 4;
#pragma unroll
            for (int j = 0; j < 4; j++) {
                const int seg = seg0 + j;
                const _Float16* src = vT
                    + ((size_t)(b * 16 + (seg >> 1)) * 64 + sk * 16 + s * 2 + (seg & 1)) * 512
                    + lnsw;
                GLL(src, &Vb[seg * 512 + lane * 8]);
            }
        }
        if (s < 7) {
            const _Float16* src = kSrc + (size_t)(s + 1) * 16384 + (wv * 4) * 512 + lnsw;
            _Float16* dst = &Kb[cur ^ 1][(wv * 4) * 512 + lane * 8];
#pragma unroll
            for (int j = 0; j < 4; j++) GLL(src + j * 512, dst + j * 512);
            asm volatile("s_waitcnt vmcnt(8)" ::: "memory");
        } else {
            asm volatile("s_waitcnt vmcnt(4)" ::: "memory");
        }
        __builtin_amdgcn_s_barrier();
        __builtin_amdgcn_sched_barrier(0);

#pragma unroll
        for (int kt = 0; kt < 4; kt++) {
            const _Float16* kp = &Kb[cur][(kt * 8) * 512];
            f32x4 c0 = {0.f, 0.f, 0.f, 0.f}, c1 = {0.f, 0.f, 0.f, 0.f};
#pragma unroll
            for (int ks = 0; ks < 8; ks++) {
                f16x8 kf = *(const f16x8*)(kp + ks * 512 + lofsA);
                c0 = MFMA16(q[0][ks], kf, c0);
                c1 = MFMA16(q[1][ks], kf, c1);
            }
            const int col = kt * 16 + l15;
#pragma unroll
            for (int reg = 0; reg < 4; reg++) {
                float p0 = __expf(fminf(c0[reg], 10.5f));
                float p1 = __expf(fminf(c1[reg], 10.5f));
                ps[0][reg] += p0;
                ps[1][reg] += p1;
                pw[(quad * 4 + reg) * 72 + col] = (_Float16)p0;
                pw[(16 + quad * 4 + reg) * 72 + col] = (_Float16)p1;
            }
        }

        __builtin_amdgcn_sched_barrier(0);
        if (s < 7) {
            asm volatile("s_waitcnt vmcnt(4)" ::: "memory");
        } else {
            asm volatile("s_waitcnt vmcnt(0)" ::: "memory");
        }
        __builtin_amdgcn_s_barrier();
        __builtin_amdgcn_sched_barrier(0);

        f16x8 pa[2][2];
#pragma unroll
        for (int m = 0; m < 2; m++)
#pragma unroll
            for (int kg = 0; kg < 2; kg++)
                pa[m][kg] = *(const f16x8*)(pw + (m * 16 + l15) * 72 + kg * 32 + quad * 8);
#pragma unroll
        for (int dt = 0; dt < 16; dt++) {
            const _Float16* vp = &Vb[dt * 1024];
            f16x8 v0 = *(const f16x8*)(vp + lofsA);
            f16x8 v1 = *(const f16x8*)(vp + 512 + lofsA);
            O[0][dt] = MFMA16(pa[0][0], v0, O[0][dt]);
            O[0][dt] = MFMA16(pa[0][1], v1, O[0][dt]);
            O[1][dt] = MFMA16(pa[1][0], v0, O[1][dt]);
            O[1][dt] = MFMA16(pa[1][1], v1, O[1][dt]);
        }

        __builtin_amdgcn_sched_barrier(0);
        __builtin_amdgcn_s_barrier();
        __builtin_amdgcn_sched_barrier(0);
    }

#pragma unroll
    for (int m = 0; m < 2; m++) {
#pragma unroll
        for (int msk = 1; msk <= 8; msk <<= 1)
#pragma unroll
            for (int reg = 0; reg < 4; reg++) ps[m][reg] += __shfl_xor(ps[m][reg], msk, 64);
        if (l15 == 0) {
#pragma unroll
            for (int reg = 0; reg < 4; reg++)
                psum4[(size_t)sk * 16384 + gr0 + m * 16 + quad * 4 + reg] = ps[m][reg];
        }
    }

#pragma unroll
    for (int m = 0; m < 2; m++) {
#pragma unroll
        for (int hd = 0; hd < 2; hd++) {
#pragma unroll
            for (int dt = 0; dt < 8; dt++) {
                const int dti = hd * 8 + dt;
#pragma unroll
                for (int reg = 0; reg < 4; reg++)
                    pw[(quad * 4 + reg) * 136 + dt * 16 + l15] = (_Float16)O[m][dti][reg];
            }
#pragma unroll
            for (int p2 = 0; p2 < 4; p2++) {
                const int u = lane + p2 * 64;
                const int row = u >> 4, col8 = u & 15;
                *(f16x8*)(Opart + ((size_t)sk * 16384 + gr0 + m * 16 + row) * 256 + hd * 128 + col8 * 8) =
                    *(const f16x8*)(pw + row * 136 + col8 * 8);
            }
        }
    }
}

// ---------------------------------------------------------------------------
// mlp_k: fused LN1+LN2+FFN1+FFN2 (+qslot | final). grid 512 x 256 threads.
// Block owns 32 rows: b = bx&31 (XCD b%8 matches attn), rg = bx>>5 (0..15).
// LDS 64.3KB -> 2 blocks/CU (two barrier domains overlap latency).
// actL granule-swizzled. Per-element arithmetic identical to prior mlp_k.
// ---------------------------------------------------------------------------
__global__ __launch_bounds__(256, 2) void mlp_k(
    const _Float16* __restrict__ Opart, const float* __restrict__ psum4,
    float* __restrict__ slots,
    const float* __restrict__ ln1_g, const float* __restrict__ ln1_b,
    const float* __restrict__ ln2_g, const float* __restrict__ ln2_b,
    const _Float16* __restrict__ wf1T, const float* __restrict__ bf1,
    const _Float16* __restrict__ wf2T, const float* __restrict__ bf2,
    const _Float16* __restrict__ wqsT, const float* __restrict__ qint2,
    _Float16* __restrict__ qsT,
    const float* __restrict__ qn, const float* __restrict__ clsn,
    const float* __restrict__ alphap, const float* __restrict__ tempp,
    float* __restrict__ out, int it)
{
    __shared__ float sl[32 * 256];                 // 32KB swizzled x1/slots
    __shared__ float2 st2[32];                     // LN2 stats per row
    __shared__ __align__(16) _Float16 actL[16384]; // 32KB act tiled (swizzled)

    const int tid = threadIdx.x, lane = tid & 63, w4 = tid >> 6;
    const int l15 = lane & 15, quad = lane >> 4;
    const int lofs = l15 * 32 + quad * 8;
    const int lofsA = ((l15 * 4 + quad) ^ ((l15 >> 1) & 7)) * 8;
    const int pairW = w4 >> 1, half = w4 & 1;
    const int bx = blockIdx.x;
    const int b = bx & 31, rg = bx >> 5;
    const int R0 = b * 512 + rg * 32;

    // ---- phase 1: y = slots + O/psum; x1 = LN1(y) -> sl; LN2 stats -> st2
#pragma unroll
    for (int r2 = 0; r2 < 2; r2++) {
        const int lr = w4 * 8 + r2 * 4 + quad;
        const int gr = R0 + lr;
        float l = 0.f;
#pragma unroll
        for (int j = 0; j < 4; j++) l += psum4[(size_t)j * 16384 + gr];
        const float invl = 1.f / l;
        float4 y[4];
        float sm = 0.f, sq = 0.f;
#pragma unroll
        for (int k = 0; k < 4; k++) {
            const int c = k * 64 + l15 * 4;
            float4 o4 = {0.f, 0.f, 0.f, 0.f};
#pragma unroll
            for (int j = 0; j < 4; j++) {
                f16x4 p = *(const f16x4*)(Opart + ((size_t)j * 16384 + gr) * 256 + c);
                o4.x += (float)p[0]; o4.y += (float)p[1];
                o4.z += (float)p[2]; o4.w += (float)p[3];
            }
            float4 s4 = *(const float4*)(slots + (size_t)gr * 256 + c);
            y[k].x = s4.x + o4.x * invl; y[k].y = s4.y + o4.y * invl;
            y[k].z = s4.z + o4.z * invl; y[k].w = s4.w + o4.w * invl;
            sm += y[k].x + y[k].y + y[k].z + y[k].w;
            sq += dot4f(y[k], y[k]);
        }
#pragma unroll
        for (int m = 1; m <= 8; m <<= 1) { sm += __shfl_xor(sm, m, 64); sq += __shfl_xor(sq, m, 64); }
        const float mean = sm * (1.f / 256.f);
        const float rstd = rsqrtf(sq * (1.f / 256.f) - mean * mean + 1e-5f);
        float sm2 = 0.f, sq2 = 0.f;
#pragma unroll
        for (int k = 0; k < 4; k++) {
            const int c = k * 64 + l15 * 4;
            float4 g1 = *(const float4*)(ln1_g + c);
            float4 b1 = *(const float4*)(ln1_b + c);
            float4 x1;
            x1.x = (y[k].x - mean) * rstd * g1.x + b1.x;
            x1.y = (y[k].y - mean) * rstd * g1.y + b1.y;
            x1.z = (y[k].z - mean) * rstd * g1.z + b1.z;
            x1.w = (y[k].w - mean) * rstd * g1.w + b1.w;
            *slp(sl, lr, c) = x1;
            sm2 += x1.x + x1.y + x1.z + x1.w;
            sq2 += dot4f(x1, x1);
        }
#pragma unroll
        for (int m = 1; m <= 8; m <<= 1) { sm2 += __shfl_xor(sm2, m, 64); sq2 += __shfl_xor(sq2, m, 64); }
        const float mean2 = sm2 * (1.f / 256.f);
        const float rstd2 = rsqrtf(sq2 * (1.f / 256.f) - mean2 * mean2 + 1e-5f);
        if (l15 == 0) st2[lr] = make_float2(mean2, rstd2);
    }
    __syncthreads();

    // ---- phase 2: h = LN2(x1) on the fly -> bh frags; act = gelu(h@Wf1+bf1)
    const int lrf = pairW * 16 + l15;
    {
        const float2 s2 = st2[lrf];
        f16x8 bh[8];
#pragma unroll
        for (int ks = 0; ks < 8; ks++) {
            const int c0 = ks * 32 + quad * 8;
            float4 xa = *slp(sl, lrf, c0);
            float4 xb = *slp(sl, lrf, c0 + 4);
            float4 ga = *(const float4*)(ln2_g + c0);
            float4 gb = *(const float4*)(ln2_g + c0 + 4);
            float4 ba = *(const float4*)(ln2_b + c0);
            float4 bb2 = *(const float4*)(ln2_b + c0 + 4);
            bh[ks][0] = (_Float16)((xa.x - s2.x) * s2.y * ga.x + ba.x);
            bh[ks][1] = (_Float16)((xa.y - s2.x) * s2.y * ga.y + ba.y);
            bh[ks][2] = (_Float16)((xa.z - s2.x) * s2.y * ga.z + ba.z);
            bh[ks][3] = (_Float16)((xa.w - s2.x) * s2.y * ga.w + ba.w);
            bh[ks][4] = (_Float16)((xb.x - s2.x) * s2.y * gb.x + bb2.x);
            bh[ks][5] = (_Float16)((xb.y - s2.x) * s2.y * gb.y + bb2.y);
            bh[ks][6] = (_Float16)((xb.z - s2.x) * s2.y * gb.z + bb2.z);
            bh[ks][7] = (_Float16)((xb.w - s2.x) * s2.y * gb.w + bb2.w);
        }
#pragma unroll 2
        for (int t16 = 0; t16 < 16; t16++) {
            const int hti = half * 16 + t16;
            f32x4 c = {0.f, 0.f, 0.f, 0.f};
#pragma unroll
            for (int ks = 0; ks < 8; ks++)
                c = MFMA16(*(const f16x8*)(wf1T + ((size_t)hti * 8 + ks) * 512 + lofs), bh[ks], c);
            float4 bb = *(const float4*)(bf1 + hti * 16 + quad * 4);
            f16x4 o;
#pragma unroll
            for (int reg = 0; reg < 4; reg++) {
                float xg = c[reg] + bb[reg];
                o[reg] = (_Float16)(0.5f * xg * (1.f + erff(xg * 0.70710678118654752f)));
            }
            // swizzled actL store: tile = pairW*16 + (hti>>1), g = l15*4 + (hti&1)*2 + (quad>>1)
            const int gA = l15 * 4 + (hti & 1) * 2 + (quad >> 1);
            *(f16x4*)(actL + ((size_t)(pairW * 16 + (hti >> 1))) * 512
                      + ((gA ^ ((l15 >> 1) & 7)) * 8) + (quad & 1) * 4) = o;
        }
    }
    __syncthreads();

    // ---- phase 3: slots_new = x1 + act@Wf2 + bf2 -> sl (in place)
    {
        f32x4 c[8];
#pragma unroll
        for (int d = 0; d < 8; d++) {
            const int dti = half * 8 + d;
            float4 x4 = *slp(sl, lrf, dti * 16 + quad * 4);
            float4 bb = *(const float4*)(bf2 + dti * 16 + quad * 4);
            c[d] = (f32x4){x4.x + bb.x, x4.y + bb.y, x4.z + bb.z, x4.w + bb.w};
        }
        const _Float16* ap = actL + ((size_t)pairW * 16) * 512;
        for (int ks = 0; ks < 16; ks++) {
            f16x8 afrag = *(const f16x8*)(ap + (size_t)ks * 512 + lofsA);
#pragma unroll
            for (int d = 0; d < 8; d++)
                c[d] = MFMA16(*(const f16x8*)(wf2T + ((size_t)(half * 8 + d) * 16 + ks) * 512 + lofs),
                              afrag, c[d]);
        }
#pragma unroll
        for (int d = 0; d < 8; d++) {
            const int dti = half * 8 + d;
            float4 v = {c[d][0], c[d][1], c[d][2], c[d][3]};
            *slp(sl, lrf, dti * 16 + quad * 4) = v;
        }
    }
    __syncthreads();

    if (it < 2) {
        // ---- phase 4a: qsT for next iteration
        f16x8 bs[8];
#pragma unroll
        for (int ks = 0; ks < 8; ks++) {
            const int c0 = ks * 32 + quad * 8;
            float4 xa = *slp(sl, lrf, c0);
            float4 xb = *slp(sl, lrf, c0 + 4);
            bs[ks][0] = (_Float16)xa.x; bs[ks][1] = (_Float16)xa.y;
            bs[ks][2] = (_Float16)xa.z; bs[ks][3] = (_Float16)xa.w;
            bs[ks][4] = (_Float16)xb.x; bs[ks][5] = (_Float16)xb.y;
            bs[ks][6] = (_Float16)xb.z; bs[ks][7] = (_Float16)xb.w;
        }
        const int iq = (rg * 32 + pairW * 16 + l15) >> 2;
        const int rtg = b * 32 + rg * 2 + pairW;
#pragma unroll
        for (int d = 0; d < 8; d++) {
            const int dti = half * 8 + d;
            f32x4 c = {0.f, 0.f, 0.f, 0.f};
#pragma unroll
            for (int ks = 0; ks < 8; ks++)
                c = MFMA16(*(const f16x8*)(wqsT + ((size_t)dti * 8 + ks) * 512 + lofs), bs[ks], c);
            float4 qi = *(const float4*)(qint2 + (size_t)iq * 256 + dti * 16 + quad * 4);
            f16x4 o;
#pragma unroll
            for (int reg = 0; reg < 4; reg++) o[reg] = (_Float16)((c[reg] + qi[reg]) * 0.0625f);
            *(f16x4*)(qsT + ((size_t)rtg * 8 + (dti >> 1)) * 512 + l15 * 32
                      + ((dti & 1) * 2 + (quad >> 1)) * 8 + (quad & 1) * 4) = o;
        }
        // ---- phase 4b: slots_new -> global (coalesced)
        {
            const int lr2 = tid >> 3, k8 = tid & 7;
#pragma unroll
            for (int q4 = 0; q4 < 8; q4++) {
                float4 v = *slp(sl, lr2, k8 * 32 + q4 * 4);
                *(float4*)(slots + (size_t)(R0 + lr2) * 256 + k8 * 32 + q4 * 4) = v;
            }
        }
    } else {
        // ---- phase 4c: final scoring (2 intents per wave, 8 per block)
#pragma unroll
        for (int ii = 0; ii < 2; ii++) {
            const int i_loc = w4 * 2 + ii;
            const int i = rg * 8 + i_loc;
            float4 qv = *(const float4*)(qn + (size_t)i * 256 + lane * 4);
            float4 xs[4];
            float st4[4];
#pragma unroll
            for (int n = 0; n < 4; n++) {
                xs[n] = *slp(sl, i_loc * 4 + n, lane * 4);
                float ss = dot4f(xs[n], xs[n]);
                float sq = dot4f(xs[n], qv);
#pragma unroll
                for (int m = 1; m < 64; m <<= 1) { ss += __shfl_xor(ss, m, 64); sq += __shfl_xor(sq, m, 64); }
                st4[n] = sq / fmaxf(sqrtf(ss), 1e-12f);
            }
            float mx = fmaxf(fmaxf(st4[0], st4[1]), fmaxf(st4[2], st4[3]));
            float e0 = __expf(st4[0] - mx), e1 = __expf(st4[1] - mx);
            float e2 = __expf(st4[2] - mx), e3 = __expf(st4[3] - mx);
            float inv = 1.f / (e0 + e1 + e2 + e3);
            float4 smv;
            smv.x = (e0 * xs[0].x + e1 * xs[1].x + e2 * xs[2].x + e3 * xs[3].x) * inv;
            smv.y = (e0 * xs[0].y + e1 * xs[1].y + e2 * xs[2].y + e3 * xs[3].y) * inv;
            smv.z = (e0 * xs[0].z + e1 * xs[1].z + e2 * xs[2].z + e3 * xs[3].z) * inv;
            smv.w = (e0 * xs[0].w + e1 * xs[1].w + e2 * xs[2].w + e3 * xs[3].w) * inv;
            float ssm = dot4f(smv, smv);
            float sqn = dot4f(smv, qv);
            float4 cv = *(const float4*)(clsn + (size_t)b * 256 + lane * 4);
            float cq = dot4f(cv, qv);
#pragma unroll
            for (int m = 1; m < 64; m <<= 1) {
                ssm += __shfl_xor(ssm, m, 64);
                sqn += __shfl_xor(sqn, m, 64);
                cq  += __shfl_xor(cq,  m, 64);
            }
            if (lane == 0) {
                float score = cq + alphap[0] * sqn / fmaxf(sqrtf(ssm), 1e-12f);
                out[(size_t)b * NI + i] = score / fmaxf(tempp[0], 1e-4f);
            }
        }
    }
}

// ---------------------------------------------------------------------------
extern "C" void kernel_launch(void* const* d_in, const int* in_sizes, int n_in,
                              void* d_out, int out_size, void* d_ws, size_t ws_size,
                              hipStream_t stream)
{
    const float* tokens     = (const float*)d_in[0];
    const float* cls_embed  = (const float*)d_in[1];
    const float* intent_q   = (const float*)d_in[2];
    const float* noise      = (const float*)d_in[3];
    const float* Wk  = (const float*)d_in[4];
    const float* bk  = (const float*)d_in[5];
    const float* Wv  = (const float*)d_in[6];
    const float* bv  = (const float*)d_in[7];
    const float* Wqs = (const float*)d_in[8];
    const float* bqs = (const float*)d_in[9];
    const float* Wqi = (const float*)d_in[10];
    const float* bqi = (const float*)d_in[11];
    const float* ln1g = (const float*)d_in[12];
    const float* ln1b = (const float*)d_in[13];
    const float* ln2g = (const float*)d_in[14];
    const float* ln2b = (const float*)d_in[15];
    const float* Wf1 = (const float*)d_in[16];
    const float* bf1 = (const float*)d_in[17];
    const float* Wf2 = (const float*)d_in[18];
    const float* bf2 = (const float*)d_in[19];
    const float* slot_mu    = (const float*)d_in[20];
    const float* slot_sigma = (const float*)d_in[21];
    const float* alphap = (const float*)d_in[22];
    const float* tempp  = (const float*)d_in[23];
    float* out = (float*)d_out;

    char* base = (char*)d_ws;
    _Float16* qsT   = (_Float16*)(base);                        //  8388608 B
    _Float16* slotsT= (_Float16*)(base + 8388608u);             //  8388608 B
    _Float16* kT    = (_Float16*)(base + 33554432u);            // 33554432 B
    _Float16* vT    = (_Float16*)(base + 67108864u);            // 33554432 B
    _Float16* Opart = (_Float16*)(base + 100663296u);           // 33554432 B
    float* slots    = (float*)(base + 134217728u);              // 16777216 B
    _Float16* wkT   = (_Float16*)(base + 150994944u);           //   131072 B
    _Float16* wvT   = (_Float16*)(base + 151126016u);
    _Float16* wqsT  = (_Float16*)(base + 151257088u);
    _Float16* wf1T  = (_Float16*)(base + 151388160u);           //   262144 B
    _Float16* wf2T  = (_Float16*)(base + 151650304u);           //   262144 B
    float* qint2    = (float*)(base + 151912448u);              //   131072 B
    float* qnb      = (float*)(base + 152043520u);              //   131072 B
    float* clsn     = (float*)(base + 152174592u);              //    32768 B
    float* psum4    = (float*)(base + 152207360u);              //   262144 B

    prep<<<272, 256, 0, stream>>>(Wk, Wv, Wqs, Wf1, Wf2, intent_q, Wqi, bqi, bqs,
                                  cls_embed, wkT, wvT, wqsT, wf1T, wf2T,
                                  qint2, qnb, clsn);
    kvf_k<<<256, 512, 0, stream>>>(tokens, wkT, wvT, bk, bv, kT, vT);
    slots_init<<<2048, 256, 0, stream>>>(noise, slot_mu, slot_sigma, slots, slotsT);
    qslot_k<<<1024, 256, 0, stream>>>(slotsT, wqsT, qint2, qsT);

    for (int it = 0; it < 3; it++) {
        attn_k<<<256, 512, 0, stream>>>(qsT, kT, vT, Opart, psum4);
        mlp_k<<<512, 256, 0, stream>>>(Opart, psum4, slots,
                                       ln1g, ln1b, ln2g, ln2b,
                                       wf1T, bf1, wf2T, bf2,
                                       wqsT, qint2, qsT,
                                       qnb, clsn, alphap, tempp, out, it);
    }
}

// Round 5
// 473.631 us; speedup vs baseline: 2.5938x; 1.0345x over previous
//
#include <hip/hip_runtime.h>
#include <math.h>

#define BSZ 32
#define NI  128

typedef __attribute__((ext_vector_type(8))) _Float16 f16x8;
typedef __attribute__((ext_vector_type(4))) _Float16 f16x4;
typedef __attribute__((ext_vector_type(4))) float    f32x4;

// MFMA16(X, Y, C): C[row = quad*4+reg <- X's l15][col = l15 <- Y's l15]
// X,Y k-index = quad*8 + j.
// Tiled operand format: 1KB tiles [(r>>4)][(k>>5)], inner
//   ((r&15)*4 + ((k>>3)&3))*8 + (k&7)  == l15*32 + quad*8 + j for a fragment.
#define MFMA16(a, b, c) __builtin_amdgcn_mfma_f32_16x16x32_f16((a), (b), (c), 0, 0, 0)

// global -> LDS async DMA, 16B per lane, wave-linear dest
#define GLL(g, l) __builtin_amdgcn_global_load_lds(                          \
    (const __attribute__((address_space(1))) void*)(g),                      \
    (__attribute__((address_space(3))) void*)(l), 16, 0, 0)

// barrier that waits LDS ops only (leaves global loads/stores in flight)
#define LGKM_BAR() do {                                                      \
    asm volatile("s_waitcnt lgkmcnt(0)" ::: "memory");                       \
    __builtin_amdgcn_sched_barrier(0);                                       \
    __builtin_amdgcn_s_barrier();                                            \
    __builtin_amdgcn_sched_barrier(0); } while (0)

__device__ inline float dot4f(float4 a, float4 b) {
    return a.x * b.x + a.y * b.y + a.z * b.z + a.w * b.w;
}

// swizzled pointer into row-major f32 LDS: row r, col c (multiple of 4).
__device__ inline float4* slp(float* base, int r, int c) {
    return (float4*)(base + r * 256 + ((((c) >> 2) ^ (r & 7)) << 2));
}

// ---------------------------------------------------------------------------
// 64x64 f32->f16 transpose tile -> TILED output (element (n,k) from src[k][n])
// ---------------------------------------------------------------------------
__device__ inline void tpose64(const float* __restrict__ src, int Csrc,
                               _Float16* __restrict__ dstT, int KT,
                               int r0, int c0, _Float16 (*tbuf)[72], int tid)
{
#pragma unroll
    for (int it = 0; it < 4; it++) {
        int idx = tid + it * 256;
        int rr = idx >> 4, c4 = idx & 15;
        float4 w = *(const float4*)(src + (size_t)(r0 + rr) * Csrc + c0 + c4 * 4);
        tbuf[c4 * 4 + 0][rr] = (_Float16)w.x;
        tbuf[c4 * 4 + 1][rr] = (_Float16)w.y;
        tbuf[c4 * 4 + 2][rr] = (_Float16)w.z;
        tbuf[c4 * 4 + 3][rr] = (_Float16)w.w;
    }
    __syncthreads();
#pragma unroll
    for (int it = 0; it < 2; it++) {
        int idx = tid + it * 256;
        int orr = idx >> 3, oc8 = idx & 7;
        int n = c0 + orr;
        size_t tile = (size_t)(n >> 4) * KT + (r0 >> 5) + (oc8 >> 2);
        *(f16x8*)(dstT + tile * 512 + (n & 15) * 32 + (oc8 & 3) * 8) = *(const f16x8*)&tbuf[orr][oc8 * 8];
    }
}

// ---------------------------------------------------------------------------
// prep: tiled f16 weights, qn, cls_n, qint2 = q@Wqi + bqi + bqs
// ---------------------------------------------------------------------------
__global__ __launch_bounds__(256) void prep(
    const float* __restrict__ Wk, const float* __restrict__ Wv,
    const float* __restrict__ Wqs, const float* __restrict__ Wf1,
    const float* __restrict__ Wf2,
    const float* __restrict__ intent_q, const float* __restrict__ Wqi,
    const float* __restrict__ bqi, const float* __restrict__ bqs,
    const float* __restrict__ cls_embed,
    _Float16* __restrict__ wkT, _Float16* __restrict__ wvT,
    _Float16* __restrict__ wqsT, _Float16* __restrict__ wf1T,
    _Float16* __restrict__ wf2T,
    float* __restrict__ qint2, float* __restrict__ qn, float* __restrict__ clsn)
{
    __shared__ _Float16 tbuf[64][72];
    __shared__ float buf[256];
    __shared__ float red[4];
    const int t = threadIdx.x, blk = blockIdx.x;
    const int lane = t & 63, w = t >> 6;

    if (blk < 112) {
        if (blk < 16)       tpose64(Wk, 256, wkT, 8, (blk >> 2) * 64, (blk & 3) * 64, tbuf, t);
        else if (blk < 32)  { int tt = blk - 16; tpose64(Wv, 256, wvT, 8, (tt >> 2) * 64, (tt & 3) * 64, tbuf, t); }
        else if (blk < 48)  { int tt = blk - 32; tpose64(Wqs, 256, wqsT, 8, (tt >> 2) * 64, (tt & 3) * 64, tbuf, t); }
        else if (blk < 80)  { int tt = blk - 48; tpose64(Wf1, 512, wf1T, 8, (tt & 3) * 64, (tt >> 2) * 64, tbuf, t); }
        else                { int tt = blk - 80; tpose64(Wf2, 256, wf2T, 16, (tt >> 2) * 64, (tt & 3) * 64, tbuf, t); }
    } else if (blk < 240) {
        int i = blk - 112;
        float x = intent_q[(size_t)i * 256 + t];
        buf[t] = x;
        float ss = x * x;
#pragma unroll
        for (int m = 1; m < 64; m <<= 1) ss += __shfl_xor(ss, m, 64);
        if (lane == 0) red[w] = ss;
        __syncthreads();
        float tot = red[0] + red[1] + red[2] + red[3];
        qn[(size_t)i * 256 + t] = x / fmaxf(sqrtf(tot), 1e-12f);
        float acc = bqi[t] + bqs[t];
        for (int e = 0; e < 256; e += 4) {
            const float4 q4 = *(const float4*)&buf[e];
            acc += q4.x * Wqi[(size_t)(e + 0) * 256 + t];
            acc += q4.y * Wqi[(size_t)(e + 1) * 256 + t];
            acc += q4.z * Wqi[(size_t)(e + 2) * 256 + t];
            acc += q4.w * Wqi[(size_t)(e + 3) * 256 + t];
        }
        qint2[(size_t)i * 256 + t] = acc;
    } else {
        int b = blk - 240;
        float x = cls_embed[(size_t)b * 256 + t];
        float ss = x * x;
#pragma unroll
        for (int m = 1; m < 64; m <<= 1) ss += __shfl_xor(ss, m, 64);
        if (lane == 0) red[w] = ss;
        __syncthreads();
        float tot = red[0] + red[1] + red[2] + red[3];
        clsn[(size_t)b * 256 + t] = x / fmaxf(sqrtf(tot), 1e-12f);
    }
}

// ---------------------------------------------------------------------------
// kvf_k: fused tokens->f16 + K-proj + V-proj. grid 256 x 512 threads.
// ---------------------------------------------------------------------------
__global__ __launch_bounds__(512, 2) void kvf_k(
    const float* __restrict__ tokens,
    const _Float16* __restrict__ wkT, const _Float16* __restrict__ wvT,
    const float* __restrict__ bk, const float* __restrict__ bv,
    _Float16* __restrict__ kT, _Float16* __restrict__ vT)
{
    __shared__ __align__(16) _Float16 Sb[2][8192];   // 2 x 16KB: 32 rows x 256d tiled

    const int t = threadIdx.x, lane = t & 63, w = t >> 6;
    const int l15 = lane & 15, quad = lane >> 4;
    const int lofs = l15 * 32 + quad * 8;
    const int lofsA = ((l15 * 4 + quad) ^ ((l15 >> 1) & 7)) * 8;
    const int bx = blockIdx.x;
    const int b = bx & 31, chunk = bx >> 5;

    f16x8 wk[2][8], wv[2][8];
#pragma unroll
    for (int j = 0; j < 2; j++)
#pragma unroll
        for (int ks = 0; ks < 8; ks++) {
            wk[j][ks] = *(const f16x8*)(wkT + ((size_t)(2 * w + j) * 8 + ks) * 512 + lofs);
            wv[j][ks] = *(const f16x8*)(wvT + ((size_t)(2 * w + j) * 8 + ks) * 512 + lofs);
        }
    f32x4 bi0 = *(const f32x4*)(bk + w * 32 + quad * 4);
    f32x4 bi1 = *(const f32x4*)(bk + w * 32 + 16 + quad * 4);
    const float bv0 = bv[(2 * w) * 16 + l15];
    const float bv1 = bv[(2 * w + 1) * 16 + l15];

    const int rr = t >> 5, d8 = t & 31;
    const float* tbase = tokens + ((size_t)b * 2048 + chunk * 256) * 256 + rr * 256 + d8 * 8;
    const int mskW = ((rr >> 1) & 7) ^ (((d8 >> 2) & 3) << 1);
    const int wofs0 = (d8 >> 2) * 512 + (((rr * 4 + (d8 & 3)) ^ mskW) * 8);
    const int wofs1 = wofs0 + 8 * 512;

    float4 pa0, pa1, pb0, pb1;

#define KVF_LOADS(P) do {                                                    \
        const float* sp_ = tbase + (size_t)(P) * 8192;                       \
        pa0 = *(const float4*)(sp_);                                         \
        pa1 = *(const float4*)(sp_ + 4);                                     \
        pb0 = *(const float4*)(sp_ + 4096);                                  \
        pb1 = *(const float4*)(sp_ + 4100);                                  \
    } while (0)

#define KVF_STAGE(BUF) do {                                                  \
        f16x8 h0, h1;                                                        \
        h0[0] = (_Float16)pa0.x; h0[1] = (_Float16)pa0.y;                    \
        h0[2] = (_Float16)pa0.z; h0[3] = (_Float16)pa0.w;                    \
        h0[4] = (_Float16)pa1.x; h0[5] = (_Float16)pa1.y;                    \
        h0[6] = (_Float16)pa1.z; h0[7] = (_Float16)pa1.w;                    \
        h1[0] = (_Float16)pb0.x; h1[1] = (_Float16)pb0.y;                    \
        h1[2] = (_Float16)pb0.z; h1[3] = (_Float16)pb0.w;                    \
        h1[4] = (_Float16)pb1.x; h1[5] = (_Float16)pb1.y;                    \
        h1[6] = (_Float16)pb1.z; h1[7] = (_Float16)pb1.w;                    \
        *(f16x8*)((BUF) + wofs0) = h0;                                       \
        *(f16x8*)((BUF) + wofs1) = h1;                                       \
    } while (0)

    KVF_LOADS(0);
    KVF_STAGE(&Sb[0][0]);
    LGKM_BAR();

    for (int p = 0; p < 8; p++) {
        if (p < 7) KVF_LOADS(p + 1);
        __builtin_amdgcn_sched_barrier(0);

        const _Float16* lb = &Sb[p & 1][0];
        const int stg0 = chunk * 16 + p * 2;
        const int sp = chunk * 8 + p;

        f16x8 a[2][8];
#pragma unroll
        for (int st = 0; st < 2; st++)
#pragma unroll
            for (int ks = 0; ks < 8; ks++)
                a[st][ks] = *(const f16x8*)(lb + (st * 8 + ks) * 512 + (lofsA ^ ((ks & 3) * 16)));

        // K: c[row=dim][col=seq]
#pragma unroll
        for (int st = 0; st < 2; st++) {
            f32x4 c0 = {0.f, 0.f, 0.f, 0.f}, c1 = {0.f, 0.f, 0.f, 0.f};
#pragma unroll
            for (int ks = 0; ks < 8; ks++) {
                c0 = MFMA16(wk[0][ks], a[st][ks], c0);
                c1 = MFMA16(wk[1][ks], a[st][ks], c1);
            }
            f16x4 p0, p1;
#pragma unroll
            for (int reg = 0; reg < 4; reg++) {
                p0[reg] = (_Float16)(c0[reg] + bi0[reg]);
                p1[reg] = (_Float16)(c1[reg] + bi1[reg]);
            }
            _Float16* tp = kT + ((size_t)(b * 128 + stg0 + st) * 8 + w) * 512 + l15 * 32;
            *(f16x4*)(tp + (quad >> 1) * 8 + (quad & 1) * 4) = p0;
            *(f16x4*)(tp + (2 + (quad >> 1)) * 8 + (quad & 1) * 4) = p1;
        }

        // V: c[row=seq][col=dim]
#pragma unroll
        for (int j = 0; j < 2; j++) {
            f32x4 c0 = {0.f, 0.f, 0.f, 0.f}, c1 = {0.f, 0.f, 0.f, 0.f};
#pragma unroll
            for (int ks = 0; ks < 8; ks++) {
                c0 = MFMA16(a[0][ks], wv[j][ks], c0);
                c1 = MFMA16(a[1][ks], wv[j][ks], c1);
            }
            const float bb = j ? bv1 : bv0;
            f16x4 p0, p1;
#pragma unroll
            for (int reg = 0; reg < 4; reg++) {
                p0[reg] = (_Float16)(c0[reg] + bb);
                p1[reg] = (_Float16)(c1[reg] + bb);
            }
            _Float16* tp = vT + ((size_t)(b * 16 + 2 * w + j) * 64 + sp) * 512 + l15 * 32;
            *(f16x4*)(tp + (quad >> 1) * 8 + (quad & 1) * 4) = p0;
            *(f16x4*)(tp + (2 + (quad >> 1)) * 8 + (quad & 1) * 4) = p1;
        }

        if (p < 7) {
            KVF_STAGE(&Sb[(p + 1) & 1][0]);
            LGKM_BAR();
        }
    }
#undef KVF_LOADS
#undef KVF_STAGE
}

// ---------------------------------------------------------------------------
// slotq_k: fused slots-init + qslot. grid 1024 x 256: block = one row-tile
// (16 rows). slots = mu + eps*sigma -> LDS(swz) + f32 global; then
// qsT = (slots@Wqs + qint2)/16 tiled. f16 conversion order identical to the
// old slots_init->slotsT->qslot path -> bitwise-same qsT.
// ---------------------------------------------------------------------------
__global__ __launch_bounds__(256, 4) void slotq_k(
    const float* __restrict__ noise, const float* __restrict__ slot_mu,
    const float* __restrict__ slot_sigma,
    const _Float16* __restrict__ wqsT, const float* __restrict__ qint2,
    float* __restrict__ slots, _Float16* __restrict__ qsT)
{
    __shared__ float sb[16 * 256];
    const int tid = threadIdx.x, lane = tid & 63, w4 = tid >> 6;
    const int l15 = lane & 15, quad = lane >> 4;
    const int lofs = l15 * 32 + quad * 8;
    const int rt = blockIdx.x;
    const int gr0 = rt * 16;

    {
        const int lr = w4 * 4 + quad;
        const int gr = gr0 + lr;
        const int b = gr >> 9, i = (gr >> 2) & 127, n = gr & 3;
        const float* np = noise + (((size_t)i * BSZ + b) * 4 + n) * 256;
#pragma unroll
        for (int k = 0; k < 4; k++) {
            const int c = k * 64 + l15 * 4;
            float4 mu = *(const float4*)(slot_mu + n * 256 + c);
            float4 sg = *(const float4*)(slot_sigma + n * 256 + c);
            float4 ns = *(const float4*)(np + c);
            float4 o;
            o.x = mu.x + ns.x * sg.x; o.y = mu.y + ns.y * sg.y;
            o.z = mu.z + ns.z * sg.z; o.w = mu.w + ns.w * sg.w;
            *slp(sb, lr, c) = o;
            *(float4*)(slots + (size_t)gr * 256 + c) = o;
        }
    }
    __syncthreads();

    f16x8 bs[8];
#pragma unroll
    for (int ks = 0; ks < 8; ks++) {
        const int c0 = ks * 32 + quad * 8;
        float4 xa = *slp(sb, l15, c0);
        float4 xb = *slp(sb, l15, c0 + 4);
        bs[ks][0] = (_Float16)xa.x; bs[ks][1] = (_Float16)xa.y;
        bs[ks][2] = (_Float16)xa.z; bs[ks][3] = (_Float16)xa.w;
        bs[ks][4] = (_Float16)xb.x; bs[ks][5] = (_Float16)xb.y;
        bs[ks][6] = (_Float16)xb.z; bs[ks][7] = (_Float16)xb.w;
    }
    const int iq = ((gr0 + l15) & 511) >> 2;
#pragma unroll
    for (int d = 0; d < 4; d++) {
        const int dti = w4 * 4 + d;
        f32x4 c = {0.f, 0.f, 0.f, 0.f};
#pragma unroll
        for (int ks = 0; ks < 8; ks++)
            c = MFMA16(*(const f16x8*)(wqsT + ((size_t)dti * 8 + ks) * 512 + lofs), bs[ks], c);
        float4 qi = *(const float4*)(qint2 + (size_t)iq * 256 + dti * 16 + quad * 4);
        f16x4 o;
#pragma unroll
        for (int reg = 0; reg < 4; reg++) o[reg] = (_Float16)((c[reg] + qi[reg]) * 0.0625f);
        *(f16x4*)(qsT + ((size_t)rt * 8 + (dti >> 1)) * 512 + l15 * 32
                  + ((dti & 1) * 2 + (quad >> 1)) * 8 + (quad & 1) * 4) = o;
    }
}

// ---------------------------------------------------------------------------
// attn_k: LDS-staged, pipelined. grid 256: b=bx&31, rb=(bx>>5)&1, sk=bx>>6.
// Kb/Vb granule-swizzled (pre-swizzled GLL source, swizzled fragment reads).
// ---------------------------------------------------------------------------
__global__ __launch_bounds__(512, 2) void attn_k(
    const _Float16* __restrict__ qsT, const _Float16* __restrict__ kT,
    const _Float16* __restrict__ vT,
    _Float16* __restrict__ Opart, float* __restrict__ psum4)
{
    __shared__ __align__(16) _Float16 Kb[2][16384];   // 64 keys x 256 d, dbuf
    __shared__ __align__(16) _Float16 Vb[16384];      // 64 keys x 256 d (V^T tiles)
    __shared__ __align__(16) _Float16 pb[8][2304];    // per-wave P scratch

    const int tid = threadIdx.x, lane = tid & 63, wv = tid >> 6;
    const int l15 = lane & 15, quad = lane >> 4;
    const int lofs = l15 * 32 + quad * 8;
    const int lofsA = ((l15 * 4 + quad) ^ ((l15 >> 1) & 7)) * 8;
    const int lnsw = (lane ^ ((lane >> 3) & 7)) * 8;
    const int bx = blockIdx.x;
    const int b = bx & 31, rb = (bx >> 5) & 1, sk = bx >> 6;
    const int gr0 = b * 512 + rb * 256 + wv * 32;
    const int rt_q = gr0 >> 4;

    _Float16* pw = pb[wv];

    const _Float16* kSrc = kT + ((size_t)(b * 128 + sk * 32) * 8) * 512;

    {
        const _Float16* src = kSrc + (size_t)(wv * 4) * 512 + lnsw;
        _Float16* dst = &Kb[0][(wv * 4) * 512 + lane * 8];
#pragma unroll
        for (int j = 0; j < 4; j++) GLL(src + j * 512, dst + j * 512);
    }

    f16x8 q[2][8];
#pragma unroll
    for (int m = 0; m < 2; m++)
#pragma unroll
        for (int ks = 0; ks < 8; ks++)
            q[m][ks] = *(const f16x8*)(qsT + ((size_t)(rt_q + m) * 8 + ks) * 512 + lofs);

    f32x4 O[2][16];
#pragma unroll
    for (int m = 0; m < 2; m++)
#pragma unroll
        for (int dt = 0; dt < 16; dt++) O[m][dt] = (f32x4){0.f, 0.f, 0.f, 0.f};
    float ps[2][4] = {{0.f, 0.f, 0.f, 0.f}, {0.f, 0.f, 0.f, 0.f}};

    asm volatile("s_waitcnt vmcnt(0)" ::: "memory");
    __builtin_amdgcn_s_barrier();
    __builtin_amdgcn_sched_barrier(0);

    for (int s = 0; s < 8; s++) {
        const int cur = s & 1;

        {
            const int seg0 = wv * 4;
#pragma unroll
            for (int j = 0; j < 4; j++) {
                const int seg = seg0 + j;
                const _Float16* src = vT
                    + ((size_t)(b * 16 + (seg >> 1)) * 64 + sk * 16 + s * 2 + (seg & 1)) * 512
                    + lnsw;
                GLL(src, &Vb[seg * 512 + lane * 8]);
            }
        }
        if (s < 7) {
            const _Float16* src = kSrc + (size_t)(s + 1) * 16384 + (wv * 4) * 512 + lnsw;
            _Float16* dst = &Kb[cur ^ 1][(wv * 4) * 512 + lane * 8];
#pragma unroll
            for (int j = 0; j < 4; j++) GLL(src + j * 512, dst + j * 512);
            asm volatile("s_waitcnt vmcnt(8)" ::: "memory");
        } else {
            asm volatile("s_waitcnt vmcnt(4)" ::: "memory");
        }
        __builtin_amdgcn_s_barrier();
        __builtin_amdgcn_sched_barrier(0);

#pragma unroll
        for (int kt = 0; kt < 4; kt++) {
            const _Float16* kp = &Kb[cur][(kt * 8) * 512];
            f32x4 c0 = {0.f, 0.f, 0.f, 0.f}, c1 = {0.f, 0.f, 0.f, 0.f};
#pragma unroll
            for (int ks = 0; ks < 8; ks++) {
                f16x8 kf = *(const f16x8*)(kp + ks * 512 + lofsA);
                c0 = MFMA16(q[0][ks], kf, c0);
                c1 = MFMA16(q[1][ks], kf, c1);
            }
            const int col = kt * 16 + l15;
#pragma unroll
            for (int reg = 0; reg < 4; reg++) {
                float p0 = __expf(fminf(c0[reg], 10.5f));
                float p1 = __expf(fminf(c1[reg], 10.5f));
                ps[0][reg] += p0;
                ps[1][reg] += p1;
                pw[(quad * 4 + reg) * 72 + col] = (_Float16)p0;
                pw[(16 + quad * 4 + reg) * 72 + col] = (_Float16)p1;
            }
        }

        __builtin_amdgcn_sched_barrier(0);
        if (s < 7) {
            asm volatile("s_waitcnt vmcnt(4)" ::: "memory");
        } else {
            asm volatile("s_waitcnt vmcnt(0)" ::: "memory");
        }
        __builtin_amdgcn_s_barrier();
        __builtin_amdgcn_sched_barrier(0);

        f16x8 pa[2][2];
#pragma unroll
        for (int m = 0; m < 2; m++)
#pragma unroll
            for (int kg = 0; kg < 2; kg++)
                pa[m][kg] = *(const f16x8*)(pw + (m * 16 + l15) * 72 + kg * 32 + quad * 8);
#pragma unroll
        for (int dt = 0; dt < 16; dt++) {
            const _Float16* vp = &Vb[dt * 1024];
            f16x8 v0 = *(const f16x8*)(vp + lofsA);
            f16x8 v1 = *(const f16x8*)(vp + 512 + lofsA);
            O[0][dt] = MFMA16(pa[0][0], v0, O[0][dt]);
            O[0][dt] = MFMA16(pa[0][1], v1, O[0][dt]);
            O[1][dt] = MFMA16(pa[1][0], v0, O[1][dt]);
            O[1][dt] = MFMA16(pa[1][1], v1, O[1][dt]);
        }

        __builtin_amdgcn_sched_barrier(0);
        __builtin_amdgcn_s_barrier();
        __builtin_amdgcn_sched_barrier(0);
    }

#pragma unroll
    for (int m = 0; m < 2; m++) {
#pragma unroll
        for (int msk = 1; msk <= 8; msk <<= 1)
#pragma unroll
            for (int reg = 0; reg < 4; reg++) ps[m][reg] += __shfl_xor(ps[m][reg], msk, 64);
        if (l15 == 0) {
#pragma unroll
            for (int reg = 0; reg < 4; reg++)
                psum4[(size_t)sk * 16384 + gr0 + m * 16 + quad * 4 + reg] = ps[m][reg];
        }
    }

#pragma unroll
    for (int m = 0; m < 2; m++) {
#pragma unroll
        for (int hd = 0; hd < 2; hd++) {
#pragma unroll
            for (int dt = 0; dt < 8; dt++) {
                const int dti = hd * 8 + dt;
#pragma unroll
                for (int reg = 0; reg < 4; reg++)
                    pw[(quad * 4 + reg) * 136 + dt * 16 + l15] = (_Float16)O[m][dti][reg];
            }
#pragma unroll
            for (int p2 = 0; p2 < 4; p2++) {
                const int u = lane + p2 * 64;
                const int row = u >> 4, col8 = u & 15;
                *(f16x8*)(Opart + ((size_t)sk * 16384 + gr0 + m * 16 + row) * 256 + hd * 128 + col8 * 8) =
                    *(const f16x8*)(pw + row * 136 + col8 * 8);
            }
        }
    }
}

// ---------------------------------------------------------------------------
// mlp_k: fused LN1+LN2+FFN1+FFN2 (+qslot | final). grid 1024 x 256 threads.
// Block owns 16 rows (one row-tile): b = bx&31, rg = bx>>5 (0..31).
// LDS ~32.3KB -> 4 blocks/CU (16 waves) for latency hiding.
// Per-element arithmetic identical to prior mlp_k.
// ---------------------------------------------------------------------------
__global__ __launch_bounds__(256, 4) void mlp_k(
    const _Float16* __restrict__ Opart, const float* __restrict__ psum4,
    float* __restrict__ slots,
    const float* __restrict__ ln1_g, const float* __restrict__ ln1_b,
    const float* __restrict__ ln2_g, const float* __restrict__ ln2_b,
    const _Float16* __restrict__ wf1T, const float* __restrict__ bf1,
    const _Float16* __restrict__ wf2T, const float* __restrict__ bf2,
    const _Float16* __restrict__ wqsT, const float* __restrict__ qint2,
    _Float16* __restrict__ qsT,
    const float* __restrict__ qn, const float* __restrict__ clsn,
    const float* __restrict__ alphap, const float* __restrict__ tempp,
    float* __restrict__ out, int it)
{
    __shared__ float sl[16 * 256];                 // 16KB swizzled x1/slots
    __shared__ float2 st2[16];                     // LN2 stats per row
    __shared__ __align__(16) _Float16 actL[8192];  // 16KB act tiled (swizzled)

    const int tid = threadIdx.x, lane = tid & 63, w4 = tid >> 6;
    const int l15 = lane & 15, quad = lane >> 4;
    const int lofs = l15 * 32 + quad * 8;
    const int lofsA = ((l15 * 4 + quad) ^ ((l15 >> 1) & 7)) * 8;
    const int bx = blockIdx.x;
    const int b = bx & 31, rg = bx >> 5;
    const int R0 = b * 512 + rg * 16;

    // ---- phase 1: y = slots + O/psum; x1 = LN1(y) -> sl; LN2 stats -> st2
    {
        const int lr = w4 * 4 + quad;
        const int gr = R0 + lr;
        float l = 0.f;
#pragma unroll
        for (int j = 0; j < 4; j++) l += psum4[(size_t)j * 16384 + gr];
        const float invl = 1.f / l;
        float4 y[4];
        float sm = 0.f, sq = 0.f;
#pragma unroll
        for (int k = 0; k < 4; k++) {
            const int c = k * 64 + l15 * 4;
            float4 o4 = {0.f, 0.f, 0.f, 0.f};
#pragma unroll
            for (int j = 0; j < 4; j++) {
                f16x4 p = *(const f16x4*)(Opart + ((size_t)j * 16384 + gr) * 256 + c);
                o4.x += (float)p[0]; o4.y += (float)p[1];
                o4.z += (float)p[2]; o4.w += (float)p[3];
            }
            float4 s4 = *(const float4*)(slots + (size_t)gr * 256 + c);
            y[k].x = s4.x + o4.x * invl; y[k].y = s4.y + o4.y * invl;
            y[k].z = s4.z + o4.z * invl; y[k].w = s4.w + o4.w * invl;
            sm += y[k].x + y[k].y + y[k].z + y[k].w;
            sq += dot4f(y[k], y[k]);
        }
#pragma unroll
        for (int m = 1; m <= 8; m <<= 1) { sm += __shfl_xor(sm, m, 64); sq += __shfl_xor(sq, m, 64); }
        const float mean = sm * (1.f / 256.f);
        const float rstd = rsqrtf(sq * (1.f / 256.f) - mean * mean + 1e-5f);
        float sm2 = 0.f, sq2 = 0.f;
#pragma unroll
        for (int k = 0; k < 4; k++) {
            const int c = k * 64 + l15 * 4;
            float4 g1 = *(const float4*)(ln1_g + c);
            float4 b1 = *(const float4*)(ln1_b + c);
            float4 x1;
            x1.x = (y[k].x - mean) * rstd * g1.x + b1.x;
            x1.y = (y[k].y - mean) * rstd * g1.y + b1.y;
            x1.z = (y[k].z - mean) * rstd * g1.z + b1.z;
            x1.w = (y[k].w - mean) * rstd * g1.w + b1.w;
            *slp(sl, lr, c) = x1;
            sm2 += x1.x + x1.y + x1.z + x1.w;
            sq2 += dot4f(x1, x1);
        }
#pragma unroll
        for (int m = 1; m <= 8; m <<= 1) { sm2 += __shfl_xor(sm2, m, 64); sq2 += __shfl_xor(sq2, m, 64); }
        const float mean2 = sm2 * (1.f / 256.f);
        const float rstd2 = rsqrtf(sq2 * (1.f / 256.f) - mean2 * mean2 + 1e-5f);
        if (l15 == 0) st2[lr] = make_float2(mean2, rstd2);
    }
    __syncthreads();

    // ---- phase 2: h = LN2(x1) on the fly; act = gelu(h@Wf1+bf1); wave w4
    // owns htis w4*8..w4*8+7
    {
        const float2 s2 = st2[l15];
        f16x8 bh[8];
#pragma unroll
        for (int ks = 0; ks < 8; ks++) {
            const int c0 = ks * 32 + quad * 8;
            float4 xa = *slp(sl, l15, c0);
            float4 xb = *slp(sl, l15, c0 + 4);
            float4 ga = *(const float4*)(ln2_g + c0);
            float4 gb = *(const float4*)(ln2_g + c0 + 4);
            float4 ba = *(const float4*)(ln2_b + c0);
            float4 bb2 = *(const float4*)(ln2_b + c0 + 4);
            bh[ks][0] = (_Float16)((xa.x - s2.x) * s2.y * ga.x + ba.x);
            bh[ks][1] = (_Float16)((xa.y - s2.x) * s2.y * ga.y + ba.y);
            bh[ks][2] = (_Float16)((xa.z - s2.x) * s2.y * ga.z + ba.z);
            bh[ks][3] = (_Float16)((xa.w - s2.x) * s2.y * ga.w + ba.w);
            bh[ks][4] = (_Float16)((xb.x - s2.x) * s2.y * gb.x + bb2.x);
            bh[ks][5] = (_Float16)((xb.y - s2.x) * s2.y * gb.y + bb2.y);
            bh[ks][6] = (_Float16)((xb.z - s2.x) * s2.y * gb.z + bb2.z);
            bh[ks][7] = (_Float16)((xb.w - s2.x) * s2.y * gb.w + bb2.w);
        }
#pragma unroll 2
        for (int t8 = 0; t8 < 8; t8++) {
            const int hti = w4 * 8 + t8;
            f32x4 c = {0.f, 0.f, 0.f, 0.f};
#pragma unroll
            for (int ks = 0; ks < 8; ks++)
                c = MFMA16(*(const f16x8*)(wf1T + ((size_t)hti * 8 + ks) * 512 + lofs), bh[ks], c);
            float4 bb = *(const float4*)(bf1 + hti * 16 + quad * 4);
            f16x4 o;
#pragma unroll
            for (int reg = 0; reg < 4; reg++) {
                float xg = c[reg] + bb[reg];
                o[reg] = (_Float16)(0.5f * xg * (1.f + erff(xg * 0.70710678118654752f)));
            }
            const int gA = l15 * 4 + (hti & 1) * 2 + (quad >> 1);
            *(f16x4*)(actL + ((size_t)(hti >> 1)) * 512
                      + ((gA ^ ((l15 >> 1) & 7)) * 8) + (quad & 1) * 4) = o;
        }
    }
    __syncthreads();

    // ---- phase 3: slots_new = x1 + act@Wf2 + bf2 -> sl; wave w4 owns
    // d-tiles w4*4..w4*4+3
    {
        f32x4 c[4];
#pragma unroll
        for (int d = 0; d < 4; d++) {
            const int dti = w4 * 4 + d;
            float4 x4 = *slp(sl, l15, dti * 16 + quad * 4);
            float4 bb = *(const float4*)(bf2 + dti * 16 + quad * 4);
            c[d] = (f32x4){x4.x + bb.x, x4.y + bb.y, x4.z + bb.z, x4.w + bb.w};
        }
        for (int ks = 0; ks < 16; ks++) {
            f16x8 afrag = *(const f16x8*)(actL + (size_t)ks * 512 + lofsA);
#pragma unroll
            for (int d = 0; d < 4; d++)
                c[d] = MFMA16(*(const f16x8*)(wf2T + ((size_t)(w4 * 4 + d) * 16 + ks) * 512 + lofs),
                              afrag, c[d]);
        }
        __syncthreads();   // all phase-3 reads of sl done before overwrite
#pragma unroll
        for (int d = 0; d < 4; d++) {
            const int dti = w4 * 4 + d;
            float4 v = {c[d][0], c[d][1], c[d][2], c[d][3]};
            *slp(sl, l15, dti * 16 + quad * 4) = v;
        }
    }
    __syncthreads();

    if (it < 2) {
        // ---- phase 4a: qsT for next iteration
        f16x8 bs[8];
#pragma unroll
        for (int ks = 0; ks < 8; ks++) {
            const int c0 = ks * 32 + quad * 8;
            float4 xa = *slp(sl, l15, c0);
            float4 xb = *slp(sl, l15, c0 + 4);
            bs[ks][0] = (_Float16)xa.x; bs[ks][1] = (_Float16)xa.y;
            bs[ks][2] = (_Float16)xa.z; bs[ks][3] = (_Float16)xa.w;
            bs[ks][4] = (_Float16)xb.x; bs[ks][5] = (_Float16)xb.y;
            bs[ks][6] = (_Float16)xb.z; bs[ks][7] = (_Float16)xb.w;
        }
        const int iq = rg * 4 + (l15 >> 2);
        const int rtg = b * 32 + rg;
#pragma unroll
        for (int d = 0; d < 4; d++) {
            const int dti = w4 * 4 + d;
            f32x4 c = {0.f, 0.f, 0.f, 0.f};
#pragma unroll
            for (int ks = 0; ks < 8; ks++)
                c = MFMA16(*(const f16x8*)(wqsT + ((size_t)dti * 8 + ks) * 512 + lofs), bs[ks], c);
            float4 qi = *(const float4*)(qint2 + (size_t)iq * 256 + dti * 16 + quad * 4);
            f16x4 o;
#pragma unroll
            for (int reg = 0; reg < 4; reg++) o[reg] = (_Float16)((c[reg] + qi[reg]) * 0.0625f);
            *(f16x4*)(qsT + ((size_t)rtg * 8 + (dti >> 1)) * 512 + l15 * 32
                      + ((dti & 1) * 2 + (quad >> 1)) * 8 + (quad & 1) * 4) = o;
        }
        // ---- phase 4b: slots_new -> global (coalesced)
        {
            const int lr2 = tid >> 4, c16 = tid & 15;
#pragma unroll
            for (int q4 = 0; q4 < 4; q4++) {
                float4 v = *slp(sl, lr2, c16 * 16 + q4 * 4);
                *(float4*)(slots + (size_t)(R0 + lr2) * 256 + c16 * 16 + q4 * 4) = v;
            }
        }
    } else {
        // ---- phase 4c: final scoring (1 intent per wave, 4 per block)
        const int i = rg * 4 + w4;
        float4 qv = *(const float4*)(qn + (size_t)i * 256 + lane * 4);
        float4 xs[4];
        float st4[4];
#pragma unroll
        for (int n = 0; n < 4; n++) {
            xs[n] = *slp(sl, w4 * 4 + n, lane * 4);
            float ss = dot4f(xs[n], xs[n]);
            float sq = dot4f(xs[n], qv);
#pragma unroll
            for (int m = 1; m < 64; m <<= 1) { ss += __shfl_xor(ss, m, 64); sq += __shfl_xor(sq, m, 64); }
            st4[n] = sq / fmaxf(sqrtf(ss), 1e-12f);
        }
        float mx = fmaxf(fmaxf(st4[0], st4[1]), fmaxf(st4[2], st4[3]));
        float e0 = __expf(st4[0] - mx), e1 = __expf(st4[1] - mx);
        float e2 = __expf(st4[2] - mx), e3 = __expf(st4[3] - mx);
        float inv = 1.f / (e0 + e1 + e2 + e3);
        float4 smv;
        smv.x = (e0 * xs[0].x + e1 * xs[1].x + e2 * xs[2].x + e3 * xs[3].x) * inv;
        smv.y = (e0 * xs[0].y + e1 * xs[1].y + e2 * xs[2].y + e3 * xs[3].y) * inv;
        smv.z = (e0 * xs[0].z + e1 * xs[1].z + e2 * xs[2].z + e3 * xs[3].z) * inv;
        smv.w = (e0 * xs[0].w + e1 * xs[1].w + e2 * xs[2].w + e3 * xs[3].w) * inv;
        float ssm = dot4f(smv, smv);
        float sqn = dot4f(smv, qv);
        float4 cv = *(const float4*)(clsn + (size_t)b * 256 + lane * 4);
        float cq = dot4f(cv, qv);
#pragma unroll
        for (int m = 1; m < 64; m <<= 1) {
            ssm += __shfl_xor(ssm, m, 64);
            sqn += __shfl_xor(sqn, m, 64);
            cq  += __shfl_xor(cq,  m, 64);
        }
        if (lane == 0) {
            float score = cq + alphap[0] * sqn / fmaxf(sqrtf(ssm), 1e-12f);
            out[(size_t)b * NI + i] = score / fmaxf(tempp[0], 1e-4f);
        }
    }
}

// ---------------------------------------------------------------------------
extern "C" void kernel_launch(void* const* d_in, const int* in_sizes, int n_in,
                              void* d_out, int out_size, void* d_ws, size_t ws_size,
                              hipStream_t stream)
{
    const float* tokens     = (const float*)d_in[0];
    const float* cls_embed  = (const float*)d_in[1];
    const float* intent_q   = (const float*)d_in[2];
    const float* noise      = (const float*)d_in[3];
    const float* Wk  = (const float*)d_in[4];
    const float* bk  = (const float*)d_in[5];
    const float* Wv  = (const float*)d_in[6];
    const float* bv  = (const float*)d_in[7];
    const float* Wqs = (const float*)d_in[8];
    const float* bqs = (const float*)d_in[9];
    const float* Wqi = (const float*)d_in[10];
    const float* bqi = (const float*)d_in[11];
    const float* ln1g = (const float*)d_in[12];
    const float* ln1b = (const float*)d_in[13];
    const float* ln2g = (const float*)d_in[14];
    const float* ln2b = (const float*)d_in[15];
    const float* Wf1 = (const float*)d_in[16];
    const float* bf1 = (const float*)d_in[17];
    const float* Wf2 = (const float*)d_in[18];
    const float* bf2 = (const float*)d_in[19];
    const float* slot_mu    = (const float*)d_in[20];
    const float* slot_sigma = (const float*)d_in[21];
    const float* alphap = (const float*)d_in[22];
    const float* tempp  = (const float*)d_in[23];
    float* out = (float*)d_out;

    char* base = (char*)d_ws;
    _Float16* qsT   = (_Float16*)(base);                        //  8388608 B
    _Float16* kT    = (_Float16*)(base + 33554432u);            // 33554432 B
    _Float16* vT    = (_Float16*)(base + 67108864u);            // 33554432 B
    _Float16* Opart = (_Float16*)(base + 100663296u);           // 33554432 B
    float* slots    = (float*)(base + 134217728u);              // 16777216 B
    _Float16* wkT   = (_Float16*)(base + 150994944u);           //   131072 B
    _Float16* wvT   = (_Float16*)(base + 151126016u);
    _Float16* wqsT  = (_Float16*)(base + 151257088u);
    _Float16* wf1T  = (_Float16*)(base + 151388160u);           //   262144 B
    _Float16* wf2T  = (_Float16*)(base + 151650304u);           //   262144 B
    float* qint2    = (float*)(base + 151912448u);              //   131072 B
    float* qnb      = (float*)(base + 152043520u);              //   131072 B
    float* clsn     = (float*)(base + 152174592u);              //    32768 B
    float* psum4    = (float*)(base + 152207360u);              //   262144 B

    prep<<<272, 256, 0, stream>>>(Wk, Wv, Wqs, Wf1, Wf2, intent_q, Wqi, bqi, bqs,
                                  cls_embed, wkT, wvT, wqsT, wf1T, wf2T,
                                  qint2, qnb, clsn);
    kvf_k<<<256, 512, 0, stream>>>(tokens, wkT, wvT, bk, bv, kT, vT);
    slotq_k<<<1024, 256, 0, stream>>>(noise, slot_mu, slot_sigma, wqsT, qint2,
                                      slots, qsT);

    for (int it = 0; it < 3; it++) {
        attn_k<<<256, 512, 0, stream>>>(qsT, kT, vT, Opart, psum4);
        mlp_k<<<1024, 256, 0, stream>>>(Opart, psum4, slots,
                                        ln1g, ln1b, ln2g, ln2b,
                                        wf1T, bf1, wf2T, bf2,
                                        wqsT, qint2, qsT,
                                        qnb, clsn, alphap, tempp, out, it);
    }
}